// Round 21
// baseline (1836.205 us; speedup 1.0000x reference)
//
#include <hip/hip_runtime.h>
#include <hip/hip_bf16.h>
#include <math.h>

typedef __hip_bfloat16 bf;
typedef __attribute__((ext_vector_type(8))) short bf8v;   // 8 bf16 = 4 VGPR
typedef __attribute__((ext_vector_type(4))) float f4v;

__device__ __forceinline__ float bf2f(bf v) { return __bfloat162float(v); }
__device__ __forceinline__ bf f2bf(float v) { return __float2bfloat16(v); }
__device__ __forceinline__ unsigned packbf(float a, float b) {
    __hip_bfloat16_raw ra = (__hip_bfloat16_raw)__float2bfloat16(a);
    __hip_bfloat16_raw rb = (__hip_bfloat16_raw)__float2bfloat16(b);
    return (unsigned)ra.x | ((unsigned)rb.x << 16);
}

// ===========================================================================
// Tiled direct 3x3 conv, stride 2 (d2,d3,d4). 16x16 out tile.
// ===========================================================================
template <typename TIN, int STRIDE>
__global__ __launch_bounds__(256)
void conv_tiled(const TIN* __restrict__ inA, const TIN* __restrict__ inB,
                int CiA, int Ci,
                const float* __restrict__ Wt, const float* __restrict__ Bias,
                bf* __restrict__ out,
                int N, int Hi, int Wi, int Co, int Ho, int Wo, int tilesX)
{
    constexpr int TS = 16;
    constexpr int IH = (TS - 1) * STRIDE + 3;
    constexpr int IWP = (IH % 2 == 0) ? IH + 1 : IH;
    constexpr int CHUNK = 8;

    __shared__ TIN  sIn[CHUNK * IH * IWP];
    __shared__ __align__(16) float sW[CHUNK * 144];

    int tile = blockIdx.x;
    int tx0 = (tile % tilesX) * TS, ty0 = (tile / tilesX) * TS;
    int n = blockIdx.y;
    int cog0 = blockIdx.z * 16;
    int t = threadIdx.x;
    int tx = t & 15, ty = t >> 4;
    int CiB = Ci - CiA;

    float acc[16];
    #pragma unroll
    for (int c = 0; c < 16; ++c) acc[c] = Bias[cog0 + c];

    for (int cb = 0; cb < Ci; cb += CHUNK) {
        int cn = (Ci - cb < CHUNK) ? (Ci - cb) : CHUNK;
        for (int e = t; e < cn * IH * IH; e += 256) {
            int ci = e / (IH * IH);
            int rem = e % (IH * IH);
            int py = rem / IH, px = rem % IH;
            int iy = ty0 * STRIDE - 1 + py;
            int ix = tx0 * STRIDE - 1 + px;
            int gci = cb + ci;
            const TIN* src = (gci < CiA)
                ? inA + (size_t)(n * CiA + gci) * Hi * Wi
                : inB + (size_t)(n * CiB + gci - CiA) * Hi * Wi;
            float v = ((unsigned)iy < (unsigned)Hi && (unsigned)ix < (unsigned)Wi)
                      ? (float)src[(size_t)iy * Wi + ix] : 0.f;
            sIn[ci * IH * IWP + py * IWP + px] = (TIN)v;
        }
        for (int e = t; e < cn * 144; e += 256) {
            int ci = e / 144, rem = e % 144;
            int t9 = rem / 16, co = rem % 16;
            sW[ci * 144 + t9 * 16 + co] =
                Wt[(size_t)(cog0 + co) * Ci * 9 + (cb + ci) * 9 + t9];
        }
        __syncthreads();
        for (int ci = 0; ci < cn; ++ci) {
            #pragma unroll
            for (int t9 = 0; t9 < 9; ++t9) {
                int ky = t9 / 3, kx = t9 % 3;
                float v = (float)sIn[ci * IH * IWP + (ty * STRIDE + ky) * IWP
                                     + (tx * STRIDE + kx)];
                const float* wp = &sW[ci * 144 + t9 * 16];
                #pragma unroll
                for (int co = 0; co < 16; ++co)
                    acc[co] = fmaf(v, wp[co], acc[co]);
            }
        }
        __syncthreads();
    }

    int oy = ty0 + ty, ox = tx0 + tx;
    #pragma unroll
    for (int co = 0; co < 16; ++co)
        out[(size_t)(n * Co + cog0 + co) * Ho * Wo + (size_t)oy * Wo + ox]
            = f2bf(fmaxf(acc[co], 0.f));
}

// ===========================================================================
// Stride-1 conv (d1 only, Ci=1). 32x32 tile, 2x2 px/thread.
// ===========================================================================
template <typename TIN>
__global__ __launch_bounds__(256)
void conv32(const TIN* __restrict__ inA, const TIN* __restrict__ inB,
            int CiA, int Ci,
            const float* __restrict__ Wt, const float* __restrict__ Bias,
            bf* __restrict__ out, int N)
{
    constexpr int CHUNK = 4;
    __shared__ float sIn[CHUNK][34][35];
    __shared__ __align__(16) float sW[CHUNK][9][16];

    int tile = blockIdx.x;
    int X0 = (tile & 7) * 32, Y0 = (tile >> 3) * 32;
    int n = blockIdx.y;
    int t = threadIdx.x, tx = t & 15, ty = t >> 4;
    int CiB = Ci - CiA;

    float acc[4][16];
    #pragma unroll
    for (int p = 0; p < 4; ++p)
        #pragma unroll
        for (int c = 0; c < 16; ++c) acc[p][c] = 0.f;

    for (int cb = 0; cb < Ci; cb += CHUNK) {
        int cn = (Ci - cb < CHUNK) ? Ci - cb : CHUNK;
        for (int e = t; e < cn * 1156; e += 256) {
            int ci = e / 1156, rem = e % 1156;
            int py = rem / 34, px = rem % 34;
            int iy = Y0 - 1 + py, ix = X0 - 1 + px;
            int gci = cb + ci;
            const TIN* src = (gci < CiA)
                ? inA + ((size_t)(n * CiA + gci) << 16)
                : inB + ((size_t)(n * CiB + gci - CiA) << 16);
            sIn[ci][py][px] = ((unsigned)iy < 256u && (unsigned)ix < 256u)
                              ? (float)src[(iy << 8) + ix] : 0.f;
        }
        for (int e = t; e < cn * 144; e += 256) {
            int ci = e / 144, rem = e % 144;
            int t9 = rem / 16, co = rem % 16;
            sW[ci][t9][co] = Wt[(size_t)co * Ci * 9 + (cb + ci) * 9 + t9];
        }
        __syncthreads();
        for (int ci = 0; ci < cn; ++ci) {
            float rin[4][4];
            #pragma unroll
            for (int a = 0; a < 4; ++a)
                #pragma unroll
                for (int b = 0; b < 4; ++b)
                    rin[a][b] = sIn[ci][2 * ty + a][2 * tx + b];
            #pragma unroll
            for (int t9 = 0; t9 < 9; ++t9) {
                const int ky = t9 / 3, kx = t9 % 3;
                float w[16];
                #pragma unroll
                for (int q = 0; q < 4; ++q)
                    *(float4*)&w[q * 4] = *(const float4*)&sW[ci][t9][q * 4];
                #pragma unroll
                for (int ry = 0; ry < 2; ++ry)
                    #pragma unroll
                    for (int rx = 0; rx < 2; ++rx) {
                        float v = rin[ry + ky][rx + kx];
                        #pragma unroll
                        for (int co = 0; co < 16; ++co)
                            acc[ry * 2 + rx][co] = fmaf(v, w[co], acc[ry * 2 + rx][co]);
                    }
            }
        }
        __syncthreads();
    }

    #pragma unroll
    for (int co = 0; co < 16; ++co) {
        float bs = Bias[co];
        bf* dst = out + ((size_t)(n * 16 + co) << 16);
        #pragma unroll
        for (int ry = 0; ry < 2; ++ry) {
            unsigned pk = packbf(fmaxf(acc[ry * 2 + 0][co] + bs, 0.f),
                                 fmaxf(acc[ry * 2 + 1][co] + bs, 0.f));
            *(unsigned*)(dst + ((Y0 + 2 * ty + ry) << 8) + X0 + 2 * tx) = pk;
        }
    }
}

// ===========================================================================
// MFMA implicit-GEMM stride-1 conv: Co=16, Ci template (16 or 32), 256x256.
// (verified correct in round 13)
// ===========================================================================
template <int CI, int KPAD>
__global__ __launch_bounds__(256)
void conv_mfma(const bf* __restrict__ inA, const bf* __restrict__ inB,
               int CiA,
               const float* __restrict__ Wt, const float* __restrict__ Bias,
               bf* __restrict__ out, int N)
{
    constexpr int K = CI * 9;
    constexpr int NM = KPAD / 32;
    __shared__ bf sIn[CI][18][19];
    __shared__ __align__(16) bf sWt[16][KPAD];

    int tile = blockIdx.x;
    int X0 = (tile & 15) * 16, Y0 = (tile >> 4) * 16;
    int n = blockIdx.y;
    int t = threadIdx.x;
    int lane = t & 63, wave = t >> 6;
    int q = lane >> 4, mcol = lane & 15;
    int CiB = CI - CiA;

    for (int e = t; e < 16 * KPAD; e += 256) {
        int co = e / KPAD, k = e % KPAD;
        sWt[co][k] = (k < K) ? f2bf(Wt[(size_t)co * K + k]) : f2bf(0.f);
    }
    for (int e = t; e < CI * 324; e += 256) {
        int ci = e / 324, rem = e % 324;
        int py = rem / 18, px = rem % 18;
        int iy = Y0 - 1 + py, ix = X0 - 1 + px;
        const bf* src = (ci < CiA)
            ? inA + ((size_t)(n * CiA + ci) << 16)
            : inB + ((size_t)(n * CiB + ci - CiA) << 16);
        bf v;
        if ((unsigned)iy < 256u && (unsigned)ix < 256u) v = src[(iy << 8) + ix];
        else v = f2bf(0.f);
        sIn[ci][py][px] = v;
    }
    __syncthreads();

    bf8v wfrag[NM];
    #pragma unroll
    for (int s = 0; s < NM; ++s)
        wfrag[s] = *(const bf8v*)&sWt[mcol][s * 32 + q * 8];

    f4v acc[4];
    #pragma unroll
    for (int g = 0; g < 4; ++g) acc[g] = (f4v){0.f, 0.f, 0.f, 0.f};

    const bf* flat = (const bf*)sIn;
    int prow0 = wave * 4;
    #pragma unroll
    for (int s = 0; s < NM; ++s) {
        int toff[8];
        #pragma unroll
        for (int j = 0; j < 8; ++j) {
            int k = s * 32 + q * 8 + j;
            int ci = (k * 57) >> 9;
            int rem = k - ci * 9;
            int ky = (rem * 11) >> 5;
            int kx = rem - ky * 3;
            toff[j] = (k < K) ? (ci * 342 + ky * 19 + kx) : 0;
        }
        #pragma unroll
        for (int g = 0; g < 4; ++g) {
            int base = (prow0 + g) * 19 + mcol;
            unsigned short v[8];
            #pragma unroll
            for (int j = 0; j < 8; ++j) {
                int k = s * 32 + q * 8 + j;
                bf raw = flat[toff[j] + base];
                __hip_bfloat16_raw r = (__hip_bfloat16_raw)raw;
                v[j] = (k < K) ? r.x : (unsigned short)0;
            }
            bf8v afrag;
            #pragma unroll
            for (int j = 0; j < 8; ++j) afrag[j] = (short)v[j];
            acc[g] = __builtin_amdgcn_mfma_f32_16x16x32_bf16(afrag, wfrag[s], acc[g], 0, 0, 0);
        }
    }

    float bs = Bias[mcol];
    bf* dst = out + ((size_t)(n * 16 + mcol) << 16);
    #pragma unroll
    for (int g = 0; g < 4; ++g) {
        int oy = Y0 + prow0 + g, ox = X0 + q * 4;
        uint2 pk;
        pk.x = packbf(fmaxf(acc[g][0] + bs, 0.f), fmaxf(acc[g][1] + bs, 0.f));
        pk.y = packbf(fmaxf(acc[g][2] + bs, 0.f), fmaxf(acc[g][3] + bs, 0.f));
        *(uint2*)(dst + (oy << 8) + ox) = pk;
    }
}

// ===========================================================================
// MFMA phase-decomposed transposed conv (k=3,s=2,p=1,op=1): u1,u2,u3.
// Round-15-verified structure, PHASE-SPLIT across two instantiations (PP):
// PP=0 -> phases 0,1 (even output rows); PP=1 -> phases 2,3 (odd rows).
// Halves accumulator AGPRs (64->32) to lift the register-capped occupancy.
// ===========================================================================
#define CVT_PHASE(PH, KBASE, NCHAIN, L2NT, L2NTX)                              \
    _Pragma("unroll")                                                          \
    for (int s = 0; s < NCHAIN; ++s) {                                         \
        bf8v wf = *(const bf8v*)&sWt[mcol][(KBASE) + s * 32 + q * 8];          \
        int toff[8];                                                           \
        _Pragma("unroll")                                                      \
        for (int j = 0; j < 8; ++j) {                                          \
            int k = s * 32 + q * 8 + j;                                        \
            int cic = k >> (L2NT);                                             \
            int tap = k & ((1 << (L2NT)) - 1);                                 \
            int ay = tap >> (L2NTX);                                           \
            int ax = tap & ((1 << (L2NTX)) - 1);                               \
            toff[j] = cic * 306 + ay * 18 + ax;                                \
        }                                                                      \
        _Pragma("unroll")                                                      \
        for (int g = 0; g < 4; ++g) {                                          \
            int base = (prow0 + g) * 18 + mcol;                                \
            bf8v af;                                                           \
            _Pragma("unroll")                                                  \
            for (int j = 0; j < 8; ++j) {                                      \
                __hip_bfloat16_raw r = (__hip_bfloat16_raw)flat[toff[j] + base];\
                af[j] = (short)r.x;                                            \
            }                                                                  \
            acc[PH][g] = __builtin_amdgcn_mfma_f32_16x16x32_bf16(af, wf,       \
                                                      acc[PH][g], 0, 0, 0);    \
        }                                                                      \
    }

template <int CITOT, int CIA, int PP>
__global__ __launch_bounds__(256)
void convt_mfma(const bf* __restrict__ inA, const bf* __restrict__ inB,
                const float* __restrict__ Wt, const float* __restrict__ Bias,
                bf* __restrict__ out,
                int N, int Hi, int Wi, int Cotot, int Ho, int Wo, int tilesX)
{
    constexpr int NCH = CITOT / 32;
    __shared__ bf sIn[32][17][18];                // 306 elems per ci
    __shared__ __align__(16) bf sWt[16][328];     // phase bases 0,40,112,184

    int tile = blockIdx.x;
    int J0 = (tile % tilesX) * 16, I0 = (tile / tilesX) * 16;
    int n = blockIdx.y;
    int cog0 = blockIdx.z * 16;
    int t = threadIdx.x;
    int lane = t & 63, wave = t >> 6;
    int q = lane >> 4, mcol = lane & 15;
    int prow0 = wave * 4;

    f4v acc[2][4];
    #pragma unroll
    for (int p = 0; p < 2; ++p)
        #pragma unroll
        for (int g = 0; g < 4; ++g) acc[p][g] = (f4v){0.f, 0.f, 0.f, 0.f};

    const bf* flat = (const bf*)sIn;

    for (int cb = 0; cb < NCH; ++cb) {
        if (cb) __syncthreads();                  // drain reads before restage
        for (int e = t; e < 32 * 306; e += 256) {
            int ci = e / 306, rem = e % 306;
            int py = rem / 18, px = rem % 18;
            int iy = I0 + py, ix = J0 + px;
            int gci = cb * 32 + ci;
            const bf* src = (gci < CIA)
                ? inA + (size_t)(n * CIA + gci) * Hi * Wi
                : inB + (size_t)(n * (CITOT - CIA) + gci - CIA) * Hi * Wi;
            sIn[ci][py][px] = (py < 17 && iy < Hi && px < 17 && ix < Wi)
                              ? src[(size_t)iy * Wi + ix] : f2bf(0.f);
        }
        for (int e = t; e < 16 * 288; e += 256) {
            int co = e / 288, rem = e % 288;
            int cic = rem / 9, t9 = rem % 9;
            int ky = t9 / 3, kx = t9 % 3;
            int ry = (ky == 1) ? 0 : 1;
            int rx = (kx == 1) ? 0 : 1;
            int ty = (ky == 1) ? 0 : (ky >> 1);
            int txi = (kx == 1) ? 0 : (kx >> 1);
            int ntx = 1 + rx;
            int ntaps = (1 + ry) * (1 + rx);
            int ph = ry * 2 + rx;
            const int base4[4] = {0, 40, 112, 184};
            int kl = cic * ntaps + ty * ntx + txi;
            sWt[co][base4[ph] + kl] =
                f2bf(Wt[(size_t)(cog0 + co) * CITOT * 9
                        + (size_t)(cb * 32 + cic) * 9 + t9]);
        }
        __syncthreads();

        if (PP == 0) {
            CVT_PHASE(0,   0, 1, 0, 0)    // phase 0 (ry0,rx0) 1 tap,  K=32
            CVT_PHASE(1,  40, 2, 1, 1)    // phase 1 (ry0,rx1) 2 taps, K=64
        } else {
            CVT_PHASE(0, 112, 2, 1, 0)    // phase 2 (ry1,rx0) 2 taps, K=64
            CVT_PHASE(1, 184, 4, 2, 1)    // phase 3 (ry1,rx1) 4 taps, K=128
        }
    }

    float bs = Bias[cog0 + mcol];
    bf* dst = out + (size_t)(n * Cotot + cog0 + mcol) * Ho * Wo;
    #pragma unroll
    for (int lp = 0; lp < 2; ++lp) {
        const int ph = PP * 2 + lp;
        const int ry = ph >> 1, rx = ph & 1;
        #pragma unroll
        for (int g = 0; g < 4; ++g) {
            int oy = 2 * (I0 + prow0 + g) + ry;
            #pragma unroll
            for (int jj = 0; jj < 4; ++jj) {
                int ox = 2 * (J0 + q * 4 + jj) + rx;
                dst[(size_t)oy * Wo + ox] = f2bf(fmaxf(acc[lp][g][jj] + bs, 0.f));
            }
        }
    }
}

// ===========================================================================
// MFMA Gram partials (verified round 20).
// ===========================================================================
__global__ __launch_bounds__(256)
void sim_partial(const bf* __restrict__ f, float* __restrict__ part, int KTOT)
{
    __shared__ __align__(16) bf tile[32][264];
    int c = blockIdx.x;
    int t = threadIdx.x;
    int k0 = c << 8;

    for (int e = t; e < 1024; e += 256) {
        int row = e >> 5, col8 = (e & 31) * 8;
        uint4 v = *(const uint4*)&f[(size_t)row * KTOT + k0 + col8];
        *(uint4*)&tile[row][col8] = v;
    }
    __syncthreads();

    int lane = t & 63, wave = t >> 6;
    int q = lane >> 4, mcol = lane & 15;
    int qr = wave >> 1, qc = wave & 1;

    f4v acc = (f4v){0.f, 0.f, 0.f, 0.f};
    #pragma unroll
    for (int ks = 0; ks < 8; ++ks) {
        bf8v a = *(const bf8v*)&tile[qr * 16 + mcol][ks * 32 + q * 8];
        bf8v b = *(const bf8v*)&tile[qc * 16 + mcol][ks * 32 + q * 8];
        acc = __builtin_amdgcn_mfma_f32_16x16x32_bf16(a, b, acc, 0, 0, 0);
    }

    float* dst = part + (size_t)c * 1024;
    #pragma unroll
    for (int jj = 0; jj < 4; ++jj) {
        int i = qr * 16 + q * 4 + jj;
        int j = qc * 16 + mcol;
        dst[i * 32 + j] = acc[jj];
    }
}

__global__ __launch_bounds__(256)
void sim_reduce(const float* __restrict__ part, float* __restrict__ sim, int nchunks)
{
    __shared__ float red[256];
    int pair = blockIdx.x;
    int t = threadIdx.x;
    float s = 0.f;
    for (int k = t; k < nchunks; k += 256)
        s += part[(size_t)k * 1024 + pair];
    red[t] = s;
    __syncthreads();
    #pragma unroll
    for (int off = 128; off > 0; off >>= 1) {
        if (t < off) red[t] += red[t + off];
        __syncthreads();
    }
    if (t == 0) sim[pair] = red[0];
}

// ===========================================================================
// Cosine sim + group mask + top-3 (strict >, lowest index wins ties).
// ===========================================================================
__global__ void topk_kernel(const float* __restrict__ sim, const int* __restrict__ prange,
                            int* __restrict__ idx, int N)
{
    int i = threadIdx.x;
    if (i >= N) return;
    float nm_i = fmaxf(sqrtf(sim[i * N + i]), 1e-8f);
    int p0 = prange[0], p1 = prange[1];
    int gi = (i >= p0) + (i >= p1);
    float vals[32];
    for (int j = 0; j < N; ++j) {
        int gj = (j >= p0) + (j >= p1);
        if (j == i || gj != gi) { vals[j] = -1e30f; continue; }
        float nm_j = fmaxf(sqrtf(sim[j * N + j]), 1e-8f);
        vals[j] = sim[i * N + j] / (nm_i * nm_j);
    }
    for (int k = 0; k < 3; ++k) {
        float best = -2e30f; int bj = 0;
        for (int j = 0; j < N; ++j)
            if (vals[j] > best) { best = vals[j]; bj = j; }
        idx[i * 3 + k] = bj;
        vals[bj] = -1e30f;
    }
}

// ===========================================================================
// Gather-mean: agg[n] = (ga[i0] + ga[i1] + ga[i2]) / 3.
// ===========================================================================
__global__ __launch_bounds__(256)
void gather_mean(const bf* __restrict__ ga, const int* __restrict__ idx,
                 bf* __restrict__ agg)
{
    int n = blockIdx.y;
    int v = blockIdx.x * 256 + threadIdx.x;
    int i0 = idx[n * 3 + 0], i1 = idx[n * 3 + 1], i2 = idx[n * 3 + 2];
    const size_t stride = (size_t)16 << 16;
    const uint4* p0 = (const uint4*)(ga + stride * i0) + v;
    const uint4* p1 = (const uint4*)(ga + stride * i1) + v;
    const uint4* p2 = (const uint4*)(ga + stride * i2) + v;
    uint4 a = *p0, b = *p1, c = *p2;
    uint4 r;
    unsigned* ap = (unsigned*)&a; unsigned* bp = (unsigned*)&b;
    unsigned* cp = (unsigned*)&c; unsigned* rp = (unsigned*)&r;
    #pragma unroll
    for (int w = 0; w < 4; ++w) {
        float fa0 = __bfloat162float((__hip_bfloat16_raw){(unsigned short)(ap[w] & 0xffff)});
        float fb0 = __bfloat162float((__hip_bfloat16_raw){(unsigned short)(bp[w] & 0xffff)});
        float fc0 = __bfloat162float((__hip_bfloat16_raw){(unsigned short)(cp[w] & 0xffff)});
        float fa1 = __bfloat162float((__hip_bfloat16_raw){(unsigned short)(ap[w] >> 16)});
        float fb1 = __bfloat162float((__hip_bfloat16_raw){(unsigned short)(bp[w] >> 16)});
        float fc1 = __bfloat162float((__hip_bfloat16_raw){(unsigned short)(cp[w] >> 16)});
        rp[w] = packbf((fa0 + fb0 + fc0) * (1.f / 3.f),
                       (fa1 + fb1 + fc1) * (1.f / 3.f));
    }
    *((uint4*)(agg + stride * n) + v) = r;
}

// ===========================================================================
// Light head: gnn (bf16) + d1 recompute + dense 32->2 + softmax.
// ===========================================================================
__global__ __launch_bounds__(256)
void head_tiled(const float* __restrict__ cts, const bf* __restrict__ gnn,
                const float* __restrict__ w_d1, const float* __restrict__ b_d1,
                const float* __restrict__ w_de, const float* __restrict__ b_de,
                float* __restrict__ out, int N)
{
    __shared__ float sCts[18][19];
    __shared__ float sWd1[144];
    __shared__ float sB1[16];
    __shared__ float sDe[64];

    int tile = blockIdx.x;
    int X0 = (tile & 15) * 16, Y0 = (tile >> 4) * 16;
    int n = blockIdx.y;
    int t = threadIdx.x, tx = t & 15, ty = t >> 4;

    for (int e = t; e < 18 * 18; e += 256) {
        int py = e / 18, px = e % 18;
        int iy = Y0 - 1 + py, ix = X0 - 1 + px;
        sCts[py][px] = ((unsigned)iy < 256u && (unsigned)ix < 256u)
                       ? cts[((size_t)n << 16) + (iy << 8) + ix] : 0.f;
    }
    if (t < 144) sWd1[t] = w_d1[t];
    else if (t < 160) sB1[t - 144] = b_d1[t - 144];
    else if (t >= 192 && t < 256) sDe[t - 192] = w_de[t - 192];
    __syncthreads();

    int pix = ((Y0 + ty) << 8) + X0 + tx;
    float l0 = b_de[0], l1 = b_de[1];

    #pragma unroll
    for (int c = 0; c < 16; ++c) {
        float v = bf2f(gnn[((size_t)(n * 16 + c) << 16) + pix]);
        l0 = fmaf(v, sDe[c * 2 + 0], l0);
        l1 = fmaf(v, sDe[c * 2 + 1], l1);
    }

    float ct[3][3];
    #pragma unroll
    for (int a = 0; a < 3; ++a)
        #pragma unroll
        for (int b = 0; b < 3; ++b)
            ct[a][b] = sCts[ty + a][tx + b];
    #pragma unroll
    for (int c = 0; c < 16; ++c) {
        float a1 = sB1[c];
        #pragma unroll
        for (int t9 = 0; t9 < 9; ++t9)
            a1 = fmaf(ct[t9 / 3][t9 % 3], sWd1[c * 9 + t9], a1);
        float v = fmaxf(a1, 0.f);
        l0 = fmaf(v, sDe[(16 + c) * 2 + 0], l0);
        l1 = fmaf(v, sDe[(16 + c) * 2 + 1], l1);
    }

    float m = fmaxf(l0, l1);
    float e0 = expf(l0 - m), e1 = expf(l1 - m);
    float inv = 1.f / (e0 + e1);
    size_t base = ((size_t)n * 2) << 16;
    out[base + pix] = e0 * inv;
    out[base + 65536 + pix] = e1 * inv;
}

// ===========================================================================

extern "C" void kernel_launch(void* const* d_in, const int* in_sizes, int n_in,
                              void* d_out, int out_size, void* d_ws, size_t ws_size,
                              hipStream_t stream)
{
    const float* cts  = (const float*)d_in[0];
    const int*   prng = (const int*)d_in[1];
    const float* w_d1 = (const float*)d_in[2];  const float* b_d1 = (const float*)d_in[3];
    const float* w_d2 = (const float*)d_in[4];  const float* b_d2 = (const float*)d_in[5];
    const float* w_d3 = (const float*)d_in[6];  const float* b_d3 = (const float*)d_in[7];
    const float* w_d4 = (const float*)d_in[8];  const float* b_d4 = (const float*)d_in[9];
    const float* w_u1 = (const float*)d_in[10]; const float* b_u1 = (const float*)d_in[11];
    const float* w_u2 = (const float*)d_in[12]; const float* b_u2 = (const float*)d_in[13];
    const float* w_u3 = (const float*)d_in[14]; const float* b_u3 = (const float*)d_in[15];
    const float* w_ga = (const float*)d_in[16]; const float* b_ga = (const float*)d_in[17];
    const float* w_gu = (const float*)d_in[18]; const float* b_gu = (const float*)d_in[19];
    const float* w_de = (const float*)d_in[20]; const float* b_de = (const float*)d_in[21];

    const int H = 256, Wd = 256;
    const int N = in_sizes[0] / (H * Wd);   // 32

    // ---- workspace layout (192 MiB total), lifetime reuse ----
    char* wsb = (char*)d_ws;
    bf* u3 = (bf*)(wsb);
    bf* R1 = (bf*)(wsb + 67108864);

    bf* d1 = R1;
    bf* d2 = (bf*)(wsb + 134217728);
    bf* d3 = (bf*)(wsb + 134217728 + 33554432);
    bf* d4 = (bf*)(wsb + 134217728 + 50331648);
    bf* u1 = R1;
    bf* u2 = (bf*)(wsb + 67108864 + 16777216);
    bf* ga = R1;
    bf* gnn = R1;
    bf* agg = (bf*)(wsb + 134217728);
    float* simp = (float*)(wsb + 134217728);
    float* sim  = (float*)(wsb + 134217728 + 16777216);
    int*   idx  = (int*)d_out + (out_size - 96);

    const int KTOT = 16 * H * Wd;
    const int NCH  = KTOT / 256;            // 4096 chunks

    // encoder
    conv32<float><<<dim3(64, N), 256, 0, stream>>>(cts, cts, 1, 1, w_d1, b_d1, d1, N);
    conv_tiled<bf, 2><<<dim3(64, N, 2), 256, 0, stream>>>(
        d1, (const bf*)nullptr, 16, 16, w_d2, b_d2, d2, N, 256, 256, 32, 128, 128, 8);
    conv_tiled<bf, 2><<<dim3(16, N, 4), 256, 0, stream>>>(
        d2, (const bf*)nullptr, 32, 32, w_d3, b_d3, d3, N, 128, 128, 64, 64, 64, 4);
    conv_tiled<bf, 2><<<dim3(4, N, 8), 256, 0, stream>>>(
        d3, (const bf*)nullptr, 64, 64, w_d4, b_d4, d4, N, 64, 64, 128, 32, 32, 2);
    // decoder (MFMA transposed convs, phase-split for occupancy)
    convt_mfma<128, 128, 0><<<dim3(4, N, 4), 256, 0, stream>>>(
        d4, d4, w_u1, b_u1, u1, N, 32, 32, 64, 64, 64, 2);
    convt_mfma<128, 128, 1><<<dim3(4, N, 4), 256, 0, stream>>>(
        d4, d4, w_u1, b_u1, u1, N, 32, 32, 64, 64, 64, 2);
    convt_mfma<128, 64, 0><<<dim3(16, N, 2), 256, 0, stream>>>(
        u1, d3, w_u2, b_u2, u2, N, 64, 64, 32, 128, 128, 4);
    convt_mfma<128, 64, 1><<<dim3(16, N, 2), 256, 0, stream>>>(
        u1, d3, w_u2, b_u2, u2, N, 64, 64, 32, 128, 128, 4);
    convt_mfma<64, 32, 0><<<dim3(64, N, 1), 256, 0, stream>>>(
        u2, d2, w_u3, b_u3, u3, N, 128, 128, 16, 256, 256, 8);
    convt_mfma<64, 32, 1><<<dim3(64, N, 1), 256, 0, stream>>>(
        u2, d2, w_u3, b_u3, u3, N, 128, 128, 16, 256, 256, 8);
    // cosine similarity + top-3 (Gram via MFMA)
    sim_partial<<<NCH, 256, 0, stream>>>(u3, simp, KTOT);
    sim_reduce<<<dim3(N * N), 256, 0, stream>>>(simp, sim, NCH);
    topk_kernel<<<1, 64, 0, stream>>>(sim, prng, idx, N);
    // per-slice gnn-neighbor conv (MFMA), then gather-mean
    conv_mfma<16, 160><<<dim3(256, N), 256, 0, stream>>>(
        u3, u3, 16, w_ga, b_ga, ga, N);
    gather_mean<<<dim3(512, N), 256, 0, stream>>>(ga, idx, agg);
    // gnn conv (MFMA, 32ch from u3|agg) then light head
    conv_mfma<32, 288><<<dim3(256, N), 256, 0, stream>>>(
        u3, agg, 16, w_gu, b_gu, gnn, N);
    head_tiled<<<dim3(256, N), 256, 0, stream>>>(
        cts, gnn, w_d1, b_d1, w_de, b_de, (float*)d_out, N);
}

// Round 22
// 1583.993 us; speedup vs baseline: 1.1592x; 1.1592x over previous
//
#include <hip/hip_runtime.h>
#include <hip/hip_bf16.h>
#include <math.h>

typedef __hip_bfloat16 bf;
typedef __attribute__((ext_vector_type(8))) short bf8v;   // 8 bf16 = 4 VGPR
typedef __attribute__((ext_vector_type(4))) float f4v;

__device__ __forceinline__ float bf2f(bf v) { return __bfloat162float(v); }
__device__ __forceinline__ bf f2bf(float v) { return __float2bfloat16(v); }
__device__ __forceinline__ unsigned packbf(float a, float b) {
    __hip_bfloat16_raw ra = (__hip_bfloat16_raw)__float2bfloat16(a);
    __hip_bfloat16_raw rb = (__hip_bfloat16_raw)__float2bfloat16(b);
    return (unsigned)ra.x | ((unsigned)rb.x << 16);
}

// ===========================================================================
// Tiled direct 3x3 conv, stride 2 (d2,d3,d4). 16x16 out tile.
// ===========================================================================
template <typename TIN, int STRIDE>
__global__ __launch_bounds__(256)
void conv_tiled(const TIN* __restrict__ inA, const TIN* __restrict__ inB,
                int CiA, int Ci,
                const float* __restrict__ Wt, const float* __restrict__ Bias,
                bf* __restrict__ out,
                int N, int Hi, int Wi, int Co, int Ho, int Wo, int tilesX)
{
    constexpr int TS = 16;
    constexpr int IH = (TS - 1) * STRIDE + 3;
    constexpr int IWP = (IH % 2 == 0) ? IH + 1 : IH;
    constexpr int CHUNK = 8;

    __shared__ TIN  sIn[CHUNK * IH * IWP];
    __shared__ __align__(16) float sW[CHUNK * 144];

    int tile = blockIdx.x;
    int tx0 = (tile % tilesX) * TS, ty0 = (tile / tilesX) * TS;
    int n = blockIdx.y;
    int cog0 = blockIdx.z * 16;
    int t = threadIdx.x;
    int tx = t & 15, ty = t >> 4;
    int CiB = Ci - CiA;

    float acc[16];
    #pragma unroll
    for (int c = 0; c < 16; ++c) acc[c] = Bias[cog0 + c];

    for (int cb = 0; cb < Ci; cb += CHUNK) {
        int cn = (Ci - cb < CHUNK) ? (Ci - cb) : CHUNK;
        for (int e = t; e < cn * IH * IH; e += 256) {
            int ci = e / (IH * IH);
            int rem = e % (IH * IH);
            int py = rem / IH, px = rem % IH;
            int iy = ty0 * STRIDE - 1 + py;
            int ix = tx0 * STRIDE - 1 + px;
            int gci = cb + ci;
            const TIN* src = (gci < CiA)
                ? inA + (size_t)(n * CiA + gci) * Hi * Wi
                : inB + (size_t)(n * CiB + gci - CiA) * Hi * Wi;
            float v = ((unsigned)iy < (unsigned)Hi && (unsigned)ix < (unsigned)Wi)
                      ? (float)src[(size_t)iy * Wi + ix] : 0.f;
            sIn[ci * IH * IWP + py * IWP + px] = (TIN)v;
        }
        for (int e = t; e < cn * 144; e += 256) {
            int ci = e / 144, rem = e % 144;
            int t9 = rem / 16, co = rem % 16;
            sW[ci * 144 + t9 * 16 + co] =
                Wt[(size_t)(cog0 + co) * Ci * 9 + (cb + ci) * 9 + t9];
        }
        __syncthreads();
        for (int ci = 0; ci < cn; ++ci) {
            #pragma unroll
            for (int t9 = 0; t9 < 9; ++t9) {
                int ky = t9 / 3, kx = t9 % 3;
                float v = (float)sIn[ci * IH * IWP + (ty * STRIDE + ky) * IWP
                                     + (tx * STRIDE + kx)];
                const float* wp = &sW[ci * 144 + t9 * 16];
                #pragma unroll
                for (int co = 0; co < 16; ++co)
                    acc[co] = fmaf(v, wp[co], acc[co]);
            }
        }
        __syncthreads();
    }

    int oy = ty0 + ty, ox = tx0 + tx;
    #pragma unroll
    for (int co = 0; co < 16; ++co)
        out[(size_t)(n * Co + cog0 + co) * Ho * Wo + (size_t)oy * Wo + ox]
            = f2bf(fmaxf(acc[co], 0.f));
}

// ===========================================================================
// Stride-1 conv (d1 only, Ci=1). 32x32 tile, 2x2 px/thread.
// ===========================================================================
template <typename TIN>
__global__ __launch_bounds__(256)
void conv32(const TIN* __restrict__ inA, const TIN* __restrict__ inB,
            int CiA, int Ci,
            const float* __restrict__ Wt, const float* __restrict__ Bias,
            bf* __restrict__ out, int N)
{
    constexpr int CHUNK = 4;
    __shared__ float sIn[CHUNK][34][35];
    __shared__ __align__(16) float sW[CHUNK][9][16];

    int tile = blockIdx.x;
    int X0 = (tile & 7) * 32, Y0 = (tile >> 3) * 32;
    int n = blockIdx.y;
    int t = threadIdx.x, tx = t & 15, ty = t >> 4;
    int CiB = Ci - CiA;

    float acc[4][16];
    #pragma unroll
    for (int p = 0; p < 4; ++p)
        #pragma unroll
        for (int c = 0; c < 16; ++c) acc[p][c] = 0.f;

    for (int cb = 0; cb < Ci; cb += CHUNK) {
        int cn = (Ci - cb < CHUNK) ? Ci - cb : CHUNK;
        for (int e = t; e < cn * 1156; e += 256) {
            int ci = e / 1156, rem = e % 1156;
            int py = rem / 34, px = rem % 34;
            int iy = Y0 - 1 + py, ix = X0 - 1 + px;
            int gci = cb + ci;
            const TIN* src = (gci < CiA)
                ? inA + ((size_t)(n * CiA + gci) << 16)
                : inB + ((size_t)(n * CiB + gci - CiA) << 16);
            sIn[ci][py][px] = ((unsigned)iy < 256u && (unsigned)ix < 256u)
                              ? (float)src[(iy << 8) + ix] : 0.f;
        }
        for (int e = t; e < cn * 144; e += 256) {
            int ci = e / 144, rem = e % 144;
            int t9 = rem / 16, co = rem % 16;
            sW[ci][t9][co] = Wt[(size_t)co * Ci * 9 + (cb + ci) * 9 + t9];
        }
        __syncthreads();
        for (int ci = 0; ci < cn; ++ci) {
            float rin[4][4];
            #pragma unroll
            for (int a = 0; a < 4; ++a)
                #pragma unroll
                for (int b = 0; b < 4; ++b)
                    rin[a][b] = sIn[ci][2 * ty + a][2 * tx + b];
            #pragma unroll
            for (int t9 = 0; t9 < 9; ++t9) {
                const int ky = t9 / 3, kx = t9 % 3;
                float w[16];
                #pragma unroll
                for (int q = 0; q < 4; ++q)
                    *(float4*)&w[q * 4] = *(const float4*)&sW[ci][t9][q * 4];
                #pragma unroll
                for (int ry = 0; ry < 2; ++ry)
                    #pragma unroll
                    for (int rx = 0; rx < 2; ++rx) {
                        float v = rin[ry + ky][rx + kx];
                        #pragma unroll
                        for (int co = 0; co < 16; ++co)
                            acc[ry * 2 + rx][co] = fmaf(v, w[co], acc[ry * 2 + rx][co]);
                    }
            }
        }
        __syncthreads();
    }

    #pragma unroll
    for (int co = 0; co < 16; ++co) {
        float bs = Bias[co];
        bf* dst = out + ((size_t)(n * 16 + co) << 16);
        #pragma unroll
        for (int ry = 0; ry < 2; ++ry) {
            unsigned pk = packbf(fmaxf(acc[ry * 2 + 0][co] + bs, 0.f),
                                 fmaxf(acc[ry * 2 + 1][co] + bs, 0.f));
            *(unsigned*)(dst + ((Y0 + 2 * ty + ry) << 8) + X0 + 2 * tx) = pk;
        }
    }
}

// ===========================================================================
// MFMA implicit-GEMM stride-1 conv: Co=16, Ci template (16 or 32), 256x256.
// (verified correct in round 13)
// ===========================================================================
template <int CI, int KPAD>
__global__ __launch_bounds__(256)
void conv_mfma(const bf* __restrict__ inA, const bf* __restrict__ inB,
               int CiA,
               const float* __restrict__ Wt, const float* __restrict__ Bias,
               bf* __restrict__ out, int N)
{
    constexpr int K = CI * 9;
    constexpr int NM = KPAD / 32;
    __shared__ bf sIn[CI][18][19];
    __shared__ __align__(16) bf sWt[16][KPAD];

    int tile = blockIdx.x;
    int X0 = (tile & 15) * 16, Y0 = (tile >> 4) * 16;
    int n = blockIdx.y;
    int t = threadIdx.x;
    int lane = t & 63, wave = t >> 6;
    int q = lane >> 4, mcol = lane & 15;
    int CiB = CI - CiA;

    for (int e = t; e < 16 * KPAD; e += 256) {
        int co = e / KPAD, k = e % KPAD;
        sWt[co][k] = (k < K) ? f2bf(Wt[(size_t)co * K + k]) : f2bf(0.f);
    }
    for (int e = t; e < CI * 324; e += 256) {
        int ci = e / 324, rem = e % 324;
        int py = rem / 18, px = rem % 18;
        int iy = Y0 - 1 + py, ix = X0 - 1 + px;
        const bf* src = (ci < CiA)
            ? inA + ((size_t)(n * CiA + ci) << 16)
            : inB + ((size_t)(n * CiB + ci - CiA) << 16);
        bf v;
        if ((unsigned)iy < 256u && (unsigned)ix < 256u) v = src[(iy << 8) + ix];
        else v = f2bf(0.f);
        sIn[ci][py][px] = v;
    }
    __syncthreads();

    bf8v wfrag[NM];
    #pragma unroll
    for (int s = 0; s < NM; ++s)
        wfrag[s] = *(const bf8v*)&sWt[mcol][s * 32 + q * 8];

    f4v acc[4];
    #pragma unroll
    for (int g = 0; g < 4; ++g) acc[g] = (f4v){0.f, 0.f, 0.f, 0.f};

    const bf* flat = (const bf*)sIn;
    int prow0 = wave * 4;
    #pragma unroll
    for (int s = 0; s < NM; ++s) {
        int toff[8];
        #pragma unroll
        for (int j = 0; j < 8; ++j) {
            int k = s * 32 + q * 8 + j;
            int ci = (k * 57) >> 9;
            int rem = k - ci * 9;
            int ky = (rem * 11) >> 5;
            int kx = rem - ky * 3;
            toff[j] = (k < K) ? (ci * 342 + ky * 19 + kx) : 0;
        }
        #pragma unroll
        for (int g = 0; g < 4; ++g) {
            int base = (prow0 + g) * 19 + mcol;
            unsigned short v[8];
            #pragma unroll
            for (int j = 0; j < 8; ++j) {
                int k = s * 32 + q * 8 + j;
                bf raw = flat[toff[j] + base];
                __hip_bfloat16_raw r = (__hip_bfloat16_raw)raw;
                v[j] = (k < K) ? r.x : (unsigned short)0;
            }
            bf8v afrag;
            #pragma unroll
            for (int j = 0; j < 8; ++j) afrag[j] = (short)v[j];
            acc[g] = __builtin_amdgcn_mfma_f32_16x16x32_bf16(afrag, wfrag[s], acc[g], 0, 0, 0);
        }
    }

    float bs = Bias[mcol];
    bf* dst = out + ((size_t)(n * 16 + mcol) << 16);
    #pragma unroll
    for (int g = 0; g < 4; ++g) {
        int oy = Y0 + prow0 + g, ox = X0 + q * 4;
        uint2 pk;
        pk.x = packbf(fmaxf(acc[g][0] + bs, 0.f), fmaxf(acc[g][1] + bs, 0.f));
        pk.y = packbf(fmaxf(acc[g][2] + bs, 0.f), fmaxf(acc[g][3] + bs, 0.f));
        *(uint2*)(dst + (oy << 8) + ox) = pk;
    }
}

// ===========================================================================
// MFMA phase-decomposed transposed conv (k=3,s=2,p=1,op=1): u1,u2,u3.
// (verified correct in round 15; 32-ci chunk form)
// ===========================================================================
#define CVT_PHASE(PH, KBASE, NCHAIN, L2NT, L2NTX)                              \
    _Pragma("unroll")                                                          \
    for (int s = 0; s < NCHAIN; ++s) {                                         \
        bf8v wf = *(const bf8v*)&sWt[mcol][(KBASE) + s * 32 + q * 8];          \
        int toff[8];                                                           \
        _Pragma("unroll")                                                      \
        for (int j = 0; j < 8; ++j) {                                          \
            int k = s * 32 + q * 8 + j;                                        \
            int cic = k >> (L2NT);                                             \
            int tap = k & ((1 << (L2NT)) - 1);                                 \
            int ay = tap >> (L2NTX);                                           \
            int ax = tap & ((1 << (L2NTX)) - 1);                               \
            toff[j] = cic * 306 + ay * 18 + ax;                                \
        }                                                                      \
        _Pragma("unroll")                                                      \
        for (int g = 0; g < 4; ++g) {                                          \
            int base = (prow0 + g) * 18 + mcol;                                \
            bf8v af;                                                           \
            _Pragma("unroll")                                                  \
            for (int j = 0; j < 8; ++j) {                                      \
                __hip_bfloat16_raw r = (__hip_bfloat16_raw)flat[toff[j] + base];\
                af[j] = (short)r.x;                                            \
            }                                                                  \
            acc[PH][g] = __builtin_amdgcn_mfma_f32_16x16x32_bf16(af, wf,       \
                                                      acc[PH][g], 0, 0, 0);    \
        }                                                                      \
    }

template <int CITOT, int CIA>
__global__ __launch_bounds__(256)
void convt_mfma(const bf* __restrict__ inA, const bf* __restrict__ inB,
                const float* __restrict__ Wt, const float* __restrict__ Bias,
                bf* __restrict__ out,
                int N, int Hi, int Wi, int Cotot, int Ho, int Wo, int tilesX)
{
    constexpr int NCH = CITOT / 32;
    __shared__ bf sIn[32][17][18];                // 306 elems per ci
    __shared__ __align__(16) bf sWt[16][328];     // phase bases 0,40,112,184

    int tile = blockIdx.x;
    int J0 = (tile % tilesX) * 16, I0 = (tile / tilesX) * 16;
    int n = blockIdx.y;
    int cog0 = blockIdx.z * 16;
    int t = threadIdx.x;
    int lane = t & 63, wave = t >> 6;
    int q = lane >> 4, mcol = lane & 15;
    int prow0 = wave * 4;

    f4v acc[4][4];
    #pragma unroll
    for (int p = 0; p < 4; ++p)
        #pragma unroll
        for (int g = 0; g < 4; ++g) acc[p][g] = (f4v){0.f, 0.f, 0.f, 0.f};

    const bf* flat = (const bf*)sIn;

    for (int cb = 0; cb < NCH; ++cb) {
        if (cb) __syncthreads();                  // drain reads before restage
        for (int e = t; e < 32 * 306; e += 256) {
            int ci = e / 306, rem = e % 306;
            int py = rem / 18, px = rem % 18;
            int iy = I0 + py, ix = J0 + px;
            int gci = cb * 32 + ci;
            const bf* src = (gci < CIA)
                ? inA + (size_t)(n * CIA + gci) * Hi * Wi
                : inB + (size_t)(n * (CITOT - CIA) + gci - CIA) * Hi * Wi;
            sIn[ci][py][px] = (py < 17 && iy < Hi && px < 17 && ix < Wi)
                              ? src[(size_t)iy * Wi + ix] : f2bf(0.f);
        }
        for (int e = t; e < 16 * 288; e += 256) {
            int co = e / 288, rem = e % 288;
            int cic = rem / 9, t9 = rem % 9;
            int ky = t9 / 3, kx = t9 % 3;
            int ry = (ky == 1) ? 0 : 1;
            int rx = (kx == 1) ? 0 : 1;
            int ty = (ky == 1) ? 0 : (ky >> 1);
            int txi = (kx == 1) ? 0 : (kx >> 1);
            int ntx = 1 + rx;
            int ntaps = (1 + ry) * (1 + rx);
            int ph = ry * 2 + rx;
            const int base4[4] = {0, 40, 112, 184};
            int kl = cic * ntaps + ty * ntx + txi;
            sWt[co][base4[ph] + kl] =
                f2bf(Wt[(size_t)(cog0 + co) * CITOT * 9
                        + (size_t)(cb * 32 + cic) * 9 + t9]);
        }
        __syncthreads();

        CVT_PHASE(0,   0, 1, 0, 0)    // (ry0,rx0) 1 tap,  K=32
        CVT_PHASE(1,  40, 2, 1, 1)    // (ry0,rx1) 2 taps, K=64
        CVT_PHASE(2, 112, 2, 1, 0)    // (ry1,rx0) 2 taps, K=64
        CVT_PHASE(3, 184, 4, 2, 1)    // (ry1,rx1) 4 taps, K=128
    }

    float bs = Bias[cog0 + mcol];
    bf* dst = out + (size_t)(n * Cotot + cog0 + mcol) * Ho * Wo;
    #pragma unroll
    for (int ph = 0; ph < 4; ++ph) {
        const int ry = ph >> 1, rx = ph & 1;
        #pragma unroll
        for (int g = 0; g < 4; ++g) {
            int oy = 2 * (I0 + prow0 + g) + ry;
            #pragma unroll
            for (int jj = 0; jj < 4; ++jj) {
                int ox = 2 * (J0 + q * 4 + jj) + rx;
                dst[(size_t)oy * Wo + ox] = f2bf(fmaxf(acc[ph][g][jj] + bs, 0.f));
            }
        }
    }
}

// ===========================================================================
// MFMA Gram partials (verified round 20).
// ===========================================================================
__global__ __launch_bounds__(256)
void sim_partial(const bf* __restrict__ f, float* __restrict__ part, int KTOT)
{
    __shared__ __align__(16) bf tile[32][264];
    int c = blockIdx.x;
    int t = threadIdx.x;
    int k0 = c << 8;

    for (int e = t; e < 1024; e += 256) {
        int row = e >> 5, col8 = (e & 31) * 8;
        uint4 v = *(const uint4*)&f[(size_t)row * KTOT + k0 + col8];
        *(uint4*)&tile[row][col8] = v;
    }
    __syncthreads();

    int lane = t & 63, wave = t >> 6;
    int q = lane >> 4, mcol = lane & 15;
    int qr = wave >> 1, qc = wave & 1;

    f4v acc = (f4v){0.f, 0.f, 0.f, 0.f};
    #pragma unroll
    for (int ks = 0; ks < 8; ++ks) {
        bf8v a = *(const bf8v*)&tile[qr * 16 + mcol][ks * 32 + q * 8];
        bf8v b = *(const bf8v*)&tile[qc * 16 + mcol][ks * 32 + q * 8];
        acc = __builtin_amdgcn_mfma_f32_16x16x32_bf16(a, b, acc, 0, 0, 0);
    }

    float* dst = part + (size_t)c * 1024;
    #pragma unroll
    for (int jj = 0; jj < 4; ++jj) {
        int i = qr * 16 + q * 4 + jj;
        int j = qc * 16 + mcol;
        dst[i * 32 + j] = acc[jj];
    }
}

__global__ __launch_bounds__(256)
void sim_reduce(const float* __restrict__ part, float* __restrict__ sim, int nchunks)
{
    __shared__ float red[256];
    int pair = blockIdx.x;
    int t = threadIdx.x;
    float s = 0.f;
    for (int k = t; k < nchunks; k += 256)
        s += part[(size_t)k * 1024 + pair];
    red[t] = s;
    __syncthreads();
    #pragma unroll
    for (int off = 128; off > 0; off >>= 1) {
        if (t < off) red[t] += red[t + off];
        __syncthreads();
    }
    if (t == 0) sim[pair] = red[0];
}

// ===========================================================================
// Cosine sim + group mask + top-3 (strict >, lowest index wins ties).
// ===========================================================================
__global__ void topk_kernel(const float* __restrict__ sim, const int* __restrict__ prange,
                            int* __restrict__ idx, int N)
{
    int i = threadIdx.x;
    if (i >= N) return;
    float nm_i = fmaxf(sqrtf(sim[i * N + i]), 1e-8f);
    int p0 = prange[0], p1 = prange[1];
    int gi = (i >= p0) + (i >= p1);
    float vals[32];
    for (int j = 0; j < N; ++j) {
        int gj = (j >= p0) + (j >= p1);
        if (j == i || gj != gi) { vals[j] = -1e30f; continue; }
        float nm_j = fmaxf(sqrtf(sim[j * N + j]), 1e-8f);
        vals[j] = sim[i * N + j] / (nm_i * nm_j);
    }
    for (int k = 0; k < 3; ++k) {
        float best = -2e30f; int bj = 0;
        for (int j = 0; j < N; ++j)
            if (vals[j] > best) { best = vals[j]; bj = j; }
        idx[i * 3 + k] = bj;
        vals[bj] = -1e30f;
    }
}

// ===========================================================================
// Gather-mean: agg[n] = (ga[i0] + ga[i1] + ga[i2]) / 3.
// ===========================================================================
__global__ __launch_bounds__(256)
void gather_mean(const bf* __restrict__ ga, const int* __restrict__ idx,
                 bf* __restrict__ agg)
{
    int n = blockIdx.y;
    int v = blockIdx.x * 256 + threadIdx.x;
    int i0 = idx[n * 3 + 0], i1 = idx[n * 3 + 1], i2 = idx[n * 3 + 2];
    const size_t stride = (size_t)16 << 16;
    const uint4* p0 = (const uint4*)(ga + stride * i0) + v;
    const uint4* p1 = (const uint4*)(ga + stride * i1) + v;
    const uint4* p2 = (const uint4*)(ga + stride * i2) + v;
    uint4 a = *p0, b = *p1, c = *p2;
    uint4 r;
    unsigned* ap = (unsigned*)&a; unsigned* bp = (unsigned*)&b;
    unsigned* cp = (unsigned*)&c; unsigned* rp = (unsigned*)&r;
    #pragma unroll
    for (int w = 0; w < 4; ++w) {
        float fa0 = __bfloat162float((__hip_bfloat16_raw){(unsigned short)(ap[w] & 0xffff)});
        float fb0 = __bfloat162float((__hip_bfloat16_raw){(unsigned short)(bp[w] & 0xffff)});
        float fc0 = __bfloat162float((__hip_bfloat16_raw){(unsigned short)(cp[w] & 0xffff)});
        float fa1 = __bfloat162float((__hip_bfloat16_raw){(unsigned short)(ap[w] >> 16)});
        float fb1 = __bfloat162float((__hip_bfloat16_raw){(unsigned short)(bp[w] >> 16)});
        float fc1 = __bfloat162float((__hip_bfloat16_raw){(unsigned short)(cp[w] >> 16)});
        rp[w] = packbf((fa0 + fb0 + fc0) * (1.f / 3.f),
                       (fa1 + fb1 + fc1) * (1.f / 3.f));
    }
    *((uint4*)(agg + stride * n) + v) = r;
}

// ===========================================================================
// Light head: gnn (bf16) + d1 recompute + dense 32->2 + softmax.
// ===========================================================================
__global__ __launch_bounds__(256)
void head_tiled(const float* __restrict__ cts, const bf* __restrict__ gnn,
                const float* __restrict__ w_d1, const float* __restrict__ b_d1,
                const float* __restrict__ w_de, const float* __restrict__ b_de,
                float* __restrict__ out, int N)
{
    __shared__ float sCts[18][19];
    __shared__ float sWd1[144];
    __shared__ float sB1[16];
    __shared__ float sDe[64];

    int tile = blockIdx.x;
    int X0 = (tile & 15) * 16, Y0 = (tile >> 4) * 16;
    int n = blockIdx.y;
    int t = threadIdx.x, tx = t & 15, ty = t >> 4;

    for (int e = t; e < 18 * 18; e += 256) {
        int py = e / 18, px = e % 18;
        int iy = Y0 - 1 + py, ix = X0 - 1 + px;
        sCts[py][px] = ((unsigned)iy < 256u && (unsigned)ix < 256u)
                       ? cts[((size_t)n << 16) + (iy << 8) + ix] : 0.f;
    }
    if (t < 144) sWd1[t] = w_d1[t];
    else if (t < 160) sB1[t - 144] = b_d1[t - 144];
    else if (t >= 192 && t < 256) sDe[t - 192] = w_de[t - 192];
    __syncthreads();

    int pix = ((Y0 + ty) << 8) + X0 + tx;
    float l0 = b_de[0], l1 = b_de[1];

    #pragma unroll
    for (int c = 0; c < 16; ++c) {
        float v = bf2f(gnn[((size_t)(n * 16 + c) << 16) + pix]);
        l0 = fmaf(v, sDe[c * 2 + 0], l0);
        l1 = fmaf(v, sDe[c * 2 + 1], l1);
    }

    float ct[3][3];
    #pragma unroll
    for (int a = 0; a < 3; ++a)
        #pragma unroll
        for (int b = 0; b < 3; ++b)
            ct[a][b] = sCts[ty + a][tx + b];
    #pragma unroll
    for (int c = 0; c < 16; ++c) {
        float a1 = sB1[c];
        #pragma unroll
        for (int t9 = 0; t9 < 9; ++t9)
            a1 = fmaf(ct[t9 / 3][t9 % 3], sWd1[c * 9 + t9], a1);
        float v = fmaxf(a1, 0.f);
        l0 = fmaf(v, sDe[(16 + c) * 2 + 0], l0);
        l1 = fmaf(v, sDe[(16 + c) * 2 + 1], l1);
    }

    float m = fmaxf(l0, l1);
    float e0 = expf(l0 - m), e1 = expf(l1 - m);
    float inv = 1.f / (e0 + e1);
    size_t base = ((size_t)n * 2) << 16;
    out[base + pix] = e0 * inv;
    out[base + 65536 + pix] = e1 * inv;
}

// ===========================================================================

extern "C" void kernel_launch(void* const* d_in, const int* in_sizes, int n_in,
                              void* d_out, int out_size, void* d_ws, size_t ws_size,
                              hipStream_t stream)
{
    const float* cts  = (const float*)d_in[0];
    const int*   prng = (const int*)d_in[1];
    const float* w_d1 = (const float*)d_in[2];  const float* b_d1 = (const float*)d_in[3];
    const float* w_d2 = (const float*)d_in[4];  const float* b_d2 = (const float*)d_in[5];
    const float* w_d3 = (const float*)d_in[6];  const float* b_d3 = (const float*)d_in[7];
    const float* w_d4 = (const float*)d_in[8];  const float* b_d4 = (const float*)d_in[9];
    const float* w_u1 = (const float*)d_in[10]; const float* b_u1 = (const float*)d_in[11];
    const float* w_u2 = (const float*)d_in[12]; const float* b_u2 = (const float*)d_in[13];
    const float* w_u3 = (const float*)d_in[14]; const float* b_u3 = (const float*)d_in[15];
    const float* w_ga = (const float*)d_in[16]; const float* b_ga = (const float*)d_in[17];
    const float* w_gu = (const float*)d_in[18]; const float* b_gu = (const float*)d_in[19];
    const float* w_de = (const float*)d_in[20]; const float* b_de = (const float*)d_in[21];

    const int H = 256, Wd = 256;
    const int N = in_sizes[0] / (H * Wd);   // 32

    // ---- workspace layout (192 MiB total), lifetime reuse ----
    char* wsb = (char*)d_ws;
    bf* u3 = (bf*)(wsb);
    bf* R1 = (bf*)(wsb + 67108864);

    bf* d1 = R1;
    bf* d2 = (bf*)(wsb + 134217728);
    bf* d3 = (bf*)(wsb + 134217728 + 33554432);
    bf* d4 = (bf*)(wsb + 134217728 + 50331648);
    bf* u1 = R1;
    bf* u2 = (bf*)(wsb + 67108864 + 16777216);
    bf* ga = R1;
    bf* gnn = R1;
    bf* agg = (bf*)(wsb + 134217728);
    float* simp = (float*)(wsb + 134217728);
    float* sim  = (float*)(wsb + 134217728 + 16777216);
    int*   idx  = (int*)d_out + (out_size - 96);

    const int KTOT = 16 * H * Wd;
    const int NCH  = KTOT / 256;            // 4096 chunks

    // encoder
    conv32<float><<<dim3(64, N), 256, 0, stream>>>(cts, cts, 1, 1, w_d1, b_d1, d1, N);
    conv_tiled<bf, 2><<<dim3(64, N, 2), 256, 0, stream>>>(
        d1, (const bf*)nullptr, 16, 16, w_d2, b_d2, d2, N, 256, 256, 32, 128, 128, 8);
    conv_tiled<bf, 2><<<dim3(16, N, 4), 256, 0, stream>>>(
        d2, (const bf*)nullptr, 32, 32, w_d3, b_d3, d3, N, 128, 128, 64, 64, 64, 4);
    conv_tiled<bf, 2><<<dim3(4, N, 8), 256, 0, stream>>>(
        d3, (const bf*)nullptr, 64, 64, w_d4, b_d4, d4, N, 64, 64, 128, 32, 32, 2);
    // decoder (all transposed convs via MFMA)
    convt_mfma<128, 128><<<dim3(4, N, 4), 256, 0, stream>>>(
        d4, d4, w_u1, b_u1, u1, N, 32, 32, 64, 64, 64, 2);
    convt_mfma<128, 64><<<dim3(16, N, 2), 256, 0, stream>>>(
        u1, d3, w_u2, b_u2, u2, N, 64, 64, 32, 128, 128, 4);
    convt_mfma<64, 32><<<dim3(64, N, 1), 256, 0, stream>>>(
        u2, d2, w_u3, b_u3, u3, N, 128, 128, 16, 256, 256, 8);
    // cosine similarity + top-3 (Gram via MFMA)
    sim_partial<<<NCH, 256, 0, stream>>>(u3, simp, KTOT);
    sim_reduce<<<dim3(N * N), 256, 0, stream>>>(simp, sim, NCH);
    topk_kernel<<<1, 64, 0, stream>>>(sim, prng, idx, N);
    // per-slice gnn-neighbor conv (MFMA), then gather-mean
    conv_mfma<16, 160><<<dim3(256, N), 256, 0, stream>>>(
        u3, u3, 16, w_ga, b_ga, ga, N);
    gather_mean<<<dim3(512, N), 256, 0, stream>>>(ga, idx, agg);
    // gnn conv (MFMA, 32ch from u3|agg) then light head
    conv_mfma<32, 288><<<dim3(256, N), 256, 0, stream>>>(
        u3, agg, 16, w_gu, b_gu, gnn, N);
    head_tiled<<<dim3(256, N), 256, 0, stream>>>(
        cts, gnn, w_d1, b_d1, w_de, b_de, (float*)d_out, N);
}

// Round 23
// 1401.364 us; speedup vs baseline: 1.3103x; 1.1303x over previous
//
#include <hip/hip_runtime.h>
#include <hip/hip_bf16.h>
#include <math.h>

typedef __hip_bfloat16 bf;
typedef __attribute__((ext_vector_type(8))) short bf8v;   // 8 bf16 = 4 VGPR
typedef __attribute__((ext_vector_type(4))) float f4v;

__device__ __forceinline__ float bf2f(bf v) { return __bfloat162float(v); }
__device__ __forceinline__ bf f2bf(float v) { return __float2bfloat16(v); }
__device__ __forceinline__ unsigned packbf(float a, float b) {
    __hip_bfloat16_raw ra = (__hip_bfloat16_raw)__float2bfloat16(a);
    __hip_bfloat16_raw rb = (__hip_bfloat16_raw)__float2bfloat16(b);
    return (unsigned)ra.x | ((unsigned)rb.x << 16);
}

// ===========================================================================
// Tiled direct 3x3 conv, stride 2 (d2,d3,d4). 16x16 out tile.
// ===========================================================================
template <typename TIN, int STRIDE>
__global__ __launch_bounds__(256)
void conv_tiled(const TIN* __restrict__ inA, const TIN* __restrict__ inB,
                int CiA, int Ci,
                const float* __restrict__ Wt, const float* __restrict__ Bias,
                bf* __restrict__ out,
                int N, int Hi, int Wi, int Co, int Ho, int Wo, int tilesX)
{
    constexpr int TS = 16;
    constexpr int IH = (TS - 1) * STRIDE + 3;
    constexpr int IWP = (IH % 2 == 0) ? IH + 1 : IH;
    constexpr int CHUNK = 8;

    __shared__ TIN  sIn[CHUNK * IH * IWP];
    __shared__ __align__(16) float sW[CHUNK * 144];

    int tile = blockIdx.x;
    int tx0 = (tile % tilesX) * TS, ty0 = (tile / tilesX) * TS;
    int n = blockIdx.y;
    int cog0 = blockIdx.z * 16;
    int t = threadIdx.x;
    int tx = t & 15, ty = t >> 4;
    int CiB = Ci - CiA;

    float acc[16];
    #pragma unroll
    for (int c = 0; c < 16; ++c) acc[c] = Bias[cog0 + c];

    for (int cb = 0; cb < Ci; cb += CHUNK) {
        int cn = (Ci - cb < CHUNK) ? (Ci - cb) : CHUNK;
        for (int e = t; e < cn * IH * IH; e += 256) {
            int ci = e / (IH * IH);
            int rem = e % (IH * IH);
            int py = rem / IH, px = rem % IH;
            int iy = ty0 * STRIDE - 1 + py;
            int ix = tx0 * STRIDE - 1 + px;
            int gci = cb + ci;
            const TIN* src = (gci < CiA)
                ? inA + (size_t)(n * CiA + gci) * Hi * Wi
                : inB + (size_t)(n * CiB + gci - CiA) * Hi * Wi;
            float v = ((unsigned)iy < (unsigned)Hi && (unsigned)ix < (unsigned)Wi)
                      ? (float)src[(size_t)iy * Wi + ix] : 0.f;
            sIn[ci * IH * IWP + py * IWP + px] = (TIN)v;
        }
        for (int e = t; e < cn * 144; e += 256) {
            int ci = e / 144, rem = e % 144;
            int t9 = rem / 16, co = rem % 16;
            sW[ci * 144 + t9 * 16 + co] =
                Wt[(size_t)(cog0 + co) * Ci * 9 + (cb + ci) * 9 + t9];
        }
        __syncthreads();
        for (int ci = 0; ci < cn; ++ci) {
            #pragma unroll
            for (int t9 = 0; t9 < 9; ++t9) {
                int ky = t9 / 3, kx = t9 % 3;
                float v = (float)sIn[ci * IH * IWP + (ty * STRIDE + ky) * IWP
                                     + (tx * STRIDE + kx)];
                const float* wp = &sW[ci * 144 + t9 * 16];
                #pragma unroll
                for (int co = 0; co < 16; ++co)
                    acc[co] = fmaf(v, wp[co], acc[co]);
            }
        }
        __syncthreads();
    }

    int oy = ty0 + ty, ox = tx0 + tx;
    #pragma unroll
    for (int co = 0; co < 16; ++co)
        out[(size_t)(n * Co + cog0 + co) * Ho * Wo + (size_t)oy * Wo + ox]
            = f2bf(fmaxf(acc[co], 0.f));
}

// ===========================================================================
// Stride-1 conv (d1 only, Ci=1). 32x32 tile, 2x2 px/thread.
// ===========================================================================
template <typename TIN>
__global__ __launch_bounds__(256)
void conv32(const TIN* __restrict__ inA, const TIN* __restrict__ inB,
            int CiA, int Ci,
            const float* __restrict__ Wt, const float* __restrict__ Bias,
            bf* __restrict__ out, int N)
{
    constexpr int CHUNK = 4;
    __shared__ float sIn[CHUNK][34][35];
    __shared__ __align__(16) float sW[CHUNK][9][16];

    int tile = blockIdx.x;
    int X0 = (tile & 7) * 32, Y0 = (tile >> 3) * 32;
    int n = blockIdx.y;
    int t = threadIdx.x, tx = t & 15, ty = t >> 4;
    int CiB = Ci - CiA;

    float acc[4][16];
    #pragma unroll
    for (int p = 0; p < 4; ++p)
        #pragma unroll
        for (int c = 0; c < 16; ++c) acc[p][c] = 0.f;

    for (int cb = 0; cb < Ci; cb += CHUNK) {
        int cn = (Ci - cb < CHUNK) ? Ci - cb : CHUNK;
        for (int e = t; e < cn * 1156; e += 256) {
            int ci = e / 1156, rem = e % 1156;
            int py = rem / 34, px = rem % 34;
            int iy = Y0 - 1 + py, ix = X0 - 1 + px;
            int gci = cb + ci;
            const TIN* src = (gci < CiA)
                ? inA + ((size_t)(n * CiA + gci) << 16)
                : inB + ((size_t)(n * CiB + gci - CiA) << 16);
            sIn[ci][py][px] = ((unsigned)iy < 256u && (unsigned)ix < 256u)
                              ? (float)src[(iy << 8) + ix] : 0.f;
        }
        for (int e = t; e < cn * 144; e += 256) {
            int ci = e / 144, rem = e % 144;
            int t9 = rem / 16, co = rem % 16;
            sW[ci][t9][co] = Wt[(size_t)co * Ci * 9 + (cb + ci) * 9 + t9];
        }
        __syncthreads();
        for (int ci = 0; ci < cn; ++ci) {
            float rin[4][4];
            #pragma unroll
            for (int a = 0; a < 4; ++a)
                #pragma unroll
                for (int b = 0; b < 4; ++b)
                    rin[a][b] = sIn[ci][2 * ty + a][2 * tx + b];
            #pragma unroll
            for (int t9 = 0; t9 < 9; ++t9) {
                const int ky = t9 / 3, kx = t9 % 3;
                float w[16];
                #pragma unroll
                for (int q = 0; q < 4; ++q)
                    *(float4*)&w[q * 4] = *(const float4*)&sW[ci][t9][q * 4];
                #pragma unroll
                for (int ry = 0; ry < 2; ++ry)
                    #pragma unroll
                    for (int rx = 0; rx < 2; ++rx) {
                        float v = rin[ry + ky][rx + kx];
                        #pragma unroll
                        for (int co = 0; co < 16; ++co)
                            acc[ry * 2 + rx][co] = fmaf(v, w[co], acc[ry * 2 + rx][co]);
                    }
            }
        }
        __syncthreads();
    }

    #pragma unroll
    for (int co = 0; co < 16; ++co) {
        float bs = Bias[co];
        bf* dst = out + ((size_t)(n * 16 + co) << 16);
        #pragma unroll
        for (int ry = 0; ry < 2; ++ry) {
            unsigned pk = packbf(fmaxf(acc[ry * 2 + 0][co] + bs, 0.f),
                                 fmaxf(acc[ry * 2 + 1][co] + bs, 0.f));
            *(unsigned*)(dst + ((Y0 + 2 * ty + ry) << 8) + X0 + 2 * tx) = pk;
        }
    }
}

// ===========================================================================
// MFMA implicit-GEMM stride-1 conv: Co=16, Ci template (16 or 32), 256x256.
// (verified correct in round 13)
// ===========================================================================
template <int CI, int KPAD>
__global__ __launch_bounds__(256)
void conv_mfma(const bf* __restrict__ inA, const bf* __restrict__ inB,
               int CiA,
               const float* __restrict__ Wt, const float* __restrict__ Bias,
               bf* __restrict__ out, int N)
{
    constexpr int K = CI * 9;
    constexpr int NM = KPAD / 32;
    __shared__ bf sIn[CI][18][19];
    __shared__ __align__(16) bf sWt[16][KPAD];

    int tile = blockIdx.x;
    int X0 = (tile & 15) * 16, Y0 = (tile >> 4) * 16;
    int n = blockIdx.y;
    int t = threadIdx.x;
    int lane = t & 63, wave = t >> 6;
    int q = lane >> 4, mcol = lane & 15;
    int CiB = CI - CiA;

    for (int e = t; e < 16 * KPAD; e += 256) {
        int co = e / KPAD, k = e % KPAD;
        sWt[co][k] = (k < K) ? f2bf(Wt[(size_t)co * K + k]) : f2bf(0.f);
    }
    for (int e = t; e < CI * 324; e += 256) {
        int ci = e / 324, rem = e % 324;
        int py = rem / 18, px = rem % 18;
        int iy = Y0 - 1 + py, ix = X0 - 1 + px;
        const bf* src = (ci < CiA)
            ? inA + ((size_t)(n * CiA + ci) << 16)
            : inB + ((size_t)(n * CiB + ci - CiA) << 16);
        bf v;
        if ((unsigned)iy < 256u && (unsigned)ix < 256u) v = src[(iy << 8) + ix];
        else v = f2bf(0.f);
        sIn[ci][py][px] = v;
    }
    __syncthreads();

    bf8v wfrag[NM];
    #pragma unroll
    for (int s = 0; s < NM; ++s)
        wfrag[s] = *(const bf8v*)&sWt[mcol][s * 32 + q * 8];

    f4v acc[4];
    #pragma unroll
    for (int g = 0; g < 4; ++g) acc[g] = (f4v){0.f, 0.f, 0.f, 0.f};

    const bf* flat = (const bf*)sIn;
    int prow0 = wave * 4;
    #pragma unroll
    for (int s = 0; s < NM; ++s) {
        int toff[8];
        #pragma unroll
        for (int j = 0; j < 8; ++j) {
            int k = s * 32 + q * 8 + j;
            int ci = (k * 57) >> 9;
            int rem = k - ci * 9;
            int ky = (rem * 11) >> 5;
            int kx = rem - ky * 3;
            toff[j] = (k < K) ? (ci * 342 + ky * 19 + kx) : 0;
        }
        #pragma unroll
        for (int g = 0; g < 4; ++g) {
            int base = (prow0 + g) * 19 + mcol;
            unsigned short v[8];
            #pragma unroll
            for (int j = 0; j < 8; ++j) {
                int k = s * 32 + q * 8 + j;
                bf raw = flat[toff[j] + base];
                __hip_bfloat16_raw r = (__hip_bfloat16_raw)raw;
                v[j] = (k < K) ? r.x : (unsigned short)0;
            }
            bf8v afrag;
            #pragma unroll
            for (int j = 0; j < 8; ++j) afrag[j] = (short)v[j];
            acc[g] = __builtin_amdgcn_mfma_f32_16x16x32_bf16(afrag, wfrag[s], acc[g], 0, 0, 0);
        }
    }

    float bs = Bias[mcol];
    bf* dst = out + ((size_t)(n * 16 + mcol) << 16);
    #pragma unroll
    for (int g = 0; g < 4; ++g) {
        int oy = Y0 + prow0 + g, ox = X0 + q * 4;
        uint2 pk;
        pk.x = packbf(fmaxf(acc[g][0] + bs, 0.f), fmaxf(acc[g][1] + bs, 0.f));
        pk.y = packbf(fmaxf(acc[g][2] + bs, 0.f), fmaxf(acc[g][3] + bs, 0.f));
        *(uint2*)(dst + (oy << 8) + ox) = pk;
    }
}

// ===========================================================================
// MFMA phase-decomposed transposed conv (k=3,s=2,p=1,op=1): u1,u2,u3.
// Round-15-verified phase structure, with k reordered CIC-MINOR per tap:
// each chain = one fixed spatial tap (AY,AX) over 32 contiguous channels, so
// the A-fragment is a single contiguous ds_read_b128 from channel-minor
// sIn2[py][px][ci] (ci padded 32->40 so rows are 80B, 16B-aligned).
// Weights: kl = tap_local*32 + cic (phase bases unchanged: 0,40,112,184).
// ===========================================================================
#define CVT_CHAIN(PH, KOFF, AY, AX)                                           \
    {                                                                          \
        bf8v wf = *(const bf8v*)&sWt[mcol][(KOFF) + q * 8];                    \
        _Pragma("unroll")                                                      \
        for (int g = 0; g < 4; ++g) {                                          \
            bf8v af = *(const bf8v*)&sIn2[prow0 + g + (AY)][mcol + (AX)][q * 8];\
            acc[PH][g] = __builtin_amdgcn_mfma_f32_16x16x32_bf16(af, wf,       \
                                                      acc[PH][g], 0, 0, 0);    \
        }                                                                      \
    }

template <int CITOT, int CIA>
__global__ __launch_bounds__(256)
void convt_mfma(const bf* __restrict__ inA, const bf* __restrict__ inB,
                const float* __restrict__ Wt, const float* __restrict__ Bias,
                bf* __restrict__ out,
                int N, int Hi, int Wi, int Cotot, int Ho, int Wo, int tilesX)
{
    constexpr int NCH = CITOT / 32;
    __shared__ __align__(16) bf sIn2[17][18][40];  // [py][px][ci pad40] 24.5KB
    __shared__ __align__(16) bf sWt[16][328];      // phase bases 0,40,112,184

    int tile = blockIdx.x;
    int J0 = (tile % tilesX) * 16, I0 = (tile / tilesX) * 16;
    int n = blockIdx.y;
    int cog0 = blockIdx.z * 16;
    int t = threadIdx.x;
    int lane = t & 63, wave = t >> 6;
    int q = lane >> 4, mcol = lane & 15;
    int prow0 = wave * 4;

    f4v acc[4][4];
    #pragma unroll
    for (int p = 0; p < 4; ++p)
        #pragma unroll
        for (int g = 0; g < 4; ++g) acc[p][g] = (f4v){0.f, 0.f, 0.f, 0.f};

    for (int cb = 0; cb < NCH; ++cb) {
        if (cb) __syncthreads();                  // drain reads before restage
        for (int e = t; e < 32 * 306; e += 256) {
            int ci = e / 306, rem = e % 306;
            int py = rem / 18, px = rem % 18;
            int iy = I0 + py, ix = J0 + px;
            int gci = cb * 32 + ci;
            const bf* src = (gci < CIA)
                ? inA + (size_t)(n * CIA + gci) * Hi * Wi
                : inB + (size_t)(n * (CITOT - CIA) + gci - CIA) * Hi * Wi;
            sIn2[py][px][ci] = (iy < Hi && px < 17 && ix < Wi)
                               ? src[(size_t)iy * Wi + ix] : f2bf(0.f);
        }
        for (int e = t; e < 16 * 288; e += 256) {
            int co = e / 288, rem = e % 288;
            int cic = rem / 9, t9 = rem % 9;
            int ky = t9 / 3, kx = t9 % 3;
            int ry = (ky == 1) ? 0 : 1;
            int rx = (kx == 1) ? 0 : 1;
            int ty = (ky == 1) ? 0 : (ky >> 1);
            int txi = (kx == 1) ? 0 : (kx >> 1);
            int ntx = 1 + rx;
            int ph = ry * 2 + rx;
            const int base4[4] = {0, 40, 112, 184};
            int kl = (ty * ntx + txi) * 32 + cic;      // cic-minor k order
            sWt[co][base4[ph] + kl] =
                f2bf(Wt[(size_t)(cog0 + co) * CITOT * 9
                        + (size_t)(cb * 32 + cic) * 9 + t9]);
        }
        __syncthreads();

        //        PH  KOFF AY AX      (chain = one tap over 32 channels)
        CVT_CHAIN(0,   0, 0, 0)    // phase (ry0,rx0): tap (1,1)
        CVT_CHAIN(1,  40, 0, 0)    // phase (ry0,rx1): tap kx=0
        CVT_CHAIN(1,  72, 0, 1)    //                  tap kx=2
        CVT_CHAIN(2, 112, 0, 0)    // phase (ry1,rx0): tap ky=0
        CVT_CHAIN(2, 144, 1, 0)    //                  tap ky=2
        CVT_CHAIN(3, 184, 0, 0)    // phase (ry1,rx1): tap (0,0)
        CVT_CHAIN(3, 216, 0, 1)    //                  tap (0,2)
        CVT_CHAIN(3, 248, 1, 0)    //                  tap (2,0)
        CVT_CHAIN(3, 280, 1, 1)    //                  tap (2,2)
    }

    float bs = Bias[cog0 + mcol];
    bf* dst = out + (size_t)(n * Cotot + cog0 + mcol) * Ho * Wo;
    #pragma unroll
    for (int ph = 0; ph < 4; ++ph) {
        const int ry = ph >> 1, rx = ph & 1;
        #pragma unroll
        for (int g = 0; g < 4; ++g) {
            int oy = 2 * (I0 + prow0 + g) + ry;
            #pragma unroll
            for (int jj = 0; jj < 4; ++jj) {
                int ox = 2 * (J0 + q * 4 + jj) + rx;
                dst[(size_t)oy * Wo + ox] = f2bf(fmaxf(acc[ph][g][jj] + bs, 0.f));
            }
        }
    }
}

// ===========================================================================
// MFMA Gram partials (verified round 20).
// ===========================================================================
__global__ __launch_bounds__(256)
void sim_partial(const bf* __restrict__ f, float* __restrict__ part, int KTOT)
{
    __shared__ __align__(16) bf tile[32][264];
    int c = blockIdx.x;
    int t = threadIdx.x;
    int k0 = c << 8;

    for (int e = t; e < 1024; e += 256) {
        int row = e >> 5, col8 = (e & 31) * 8;
        uint4 v = *(const uint4*)&f[(size_t)row * KTOT + k0 + col8];
        *(uint4*)&tile[row][col8] = v;
    }
    __syncthreads();

    int lane = t & 63, wave = t >> 6;
    int q = lane >> 4, mcol = lane & 15;
    int qr = wave >> 1, qc = wave & 1;

    f4v acc = (f4v){0.f, 0.f, 0.f, 0.f};
    #pragma unroll
    for (int ks = 0; ks < 8; ++ks) {
        bf8v a = *(const bf8v*)&tile[qr * 16 + mcol][ks * 32 + q * 8];
        bf8v b = *(const bf8v*)&tile[qc * 16 + mcol][ks * 32 + q * 8];
        acc = __builtin_amdgcn_mfma_f32_16x16x32_bf16(a, b, acc, 0, 0, 0);
    }

    float* dst = part + (size_t)c * 1024;
    #pragma unroll
    for (int jj = 0; jj < 4; ++jj) {
        int i = qr * 16 + q * 4 + jj;
        int j = qc * 16 + mcol;
        dst[i * 32 + j] = acc[jj];
    }
}

__global__ __launch_bounds__(256)
void sim_reduce(const float* __restrict__ part, float* __restrict__ sim, int nchunks)
{
    __shared__ float red[256];
    int pair = blockIdx.x;
    int t = threadIdx.x;
    float s = 0.f;
    for (int k = t; k < nchunks; k += 256)
        s += part[(size_t)k * 1024 + pair];
    red[t] = s;
    __syncthreads();
    #pragma unroll
    for (int off = 128; off > 0; off >>= 1) {
        if (t < off) red[t] += red[t + off];
        __syncthreads();
    }
    if (t == 0) sim[pair] = red[0];
}

// ===========================================================================
// Cosine sim + group mask + top-3 (strict >, lowest index wins ties).
// ===========================================================================
__global__ void topk_kernel(const float* __restrict__ sim, const int* __restrict__ prange,
                            int* __restrict__ idx, int N)
{
    int i = threadIdx.x;
    if (i >= N) return;
    float nm_i = fmaxf(sqrtf(sim[i * N + i]), 1e-8f);
    int p0 = prange[0], p1 = prange[1];
    int gi = (i >= p0) + (i >= p1);
    float vals[32];
    for (int j = 0; j < N; ++j) {
        int gj = (j >= p0) + (j >= p1);
        if (j == i || gj != gi) { vals[j] = -1e30f; continue; }
        float nm_j = fmaxf(sqrtf(sim[j * N + j]), 1e-8f);
        vals[j] = sim[i * N + j] / (nm_i * nm_j);
    }
    for (int k = 0; k < 3; ++k) {
        float best = -2e30f; int bj = 0;
        for (int j = 0; j < N; ++j)
            if (vals[j] > best) { best = vals[j]; bj = j; }
        idx[i * 3 + k] = bj;
        vals[bj] = -1e30f;
    }
}

// ===========================================================================
// Gather-mean: agg[n] = (ga[i0] + ga[i1] + ga[i2]) / 3.
// ===========================================================================
__global__ __launch_bounds__(256)
void gather_mean(const bf* __restrict__ ga, const int* __restrict__ idx,
                 bf* __restrict__ agg)
{
    int n = blockIdx.y;
    int v = blockIdx.x * 256 + threadIdx.x;
    int i0 = idx[n * 3 + 0], i1 = idx[n * 3 + 1], i2 = idx[n * 3 + 2];
    const size_t stride = (size_t)16 << 16;
    const uint4* p0 = (const uint4*)(ga + stride * i0) + v;
    const uint4* p1 = (const uint4*)(ga + stride * i1) + v;
    const uint4* p2 = (const uint4*)(ga + stride * i2) + v;
    uint4 a = *p0, b = *p1, c = *p2;
    uint4 r;
    unsigned* ap = (unsigned*)&a; unsigned* bp = (unsigned*)&b;
    unsigned* cp = (unsigned*)&c; unsigned* rp = (unsigned*)&r;
    #pragma unroll
    for (int w = 0; w < 4; ++w) {
        float fa0 = __bfloat162float((__hip_bfloat16_raw){(unsigned short)(ap[w] & 0xffff)});
        float fb0 = __bfloat162float((__hip_bfloat16_raw){(unsigned short)(bp[w] & 0xffff)});
        float fc0 = __bfloat162float((__hip_bfloat16_raw){(unsigned short)(cp[w] & 0xffff)});
        float fa1 = __bfloat162float((__hip_bfloat16_raw){(unsigned short)(ap[w] >> 16)});
        float fb1 = __bfloat162float((__hip_bfloat16_raw){(unsigned short)(bp[w] >> 16)});
        float fc1 = __bfloat162float((__hip_bfloat16_raw){(unsigned short)(cp[w] >> 16)});
        rp[w] = packbf((fa0 + fb0 + fc0) * (1.f / 3.f),
                       (fa1 + fb1 + fc1) * (1.f / 3.f));
    }
    *((uint4*)(agg + stride * n) + v) = r;
}

// ===========================================================================
// Light head: gnn (bf16) + d1 recompute + dense 32->2 + softmax.
// ===========================================================================
__global__ __launch_bounds__(256)
void head_tiled(const float* __restrict__ cts, const bf* __restrict__ gnn,
                const float* __restrict__ w_d1, const float* __restrict__ b_d1,
                const float* __restrict__ w_de, const float* __restrict__ b_de,
                float* __restrict__ out, int N)
{
    __shared__ float sCts[18][19];
    __shared__ float sWd1[144];
    __shared__ float sB1[16];
    __shared__ float sDe[64];

    int tile = blockIdx.x;
    int X0 = (tile & 15) * 16, Y0 = (tile >> 4) * 16;
    int n = blockIdx.y;
    int t = threadIdx.x, tx = t & 15, ty = t >> 4;

    for (int e = t; e < 18 * 18; e += 256) {
        int py = e / 18, px = e % 18;
        int iy = Y0 - 1 + py, ix = X0 - 1 + px;
        sCts[py][px] = ((unsigned)iy < 256u && (unsigned)ix < 256u)
                       ? cts[((size_t)n << 16) + (iy << 8) + ix] : 0.f;
    }
    if (t < 144) sWd1[t] = w_d1[t];
    else if (t < 160) sB1[t - 144] = b_d1[t - 144];
    else if (t >= 192 && t < 256) sDe[t - 192] = w_de[t - 192];
    __syncthreads();

    int pix = ((Y0 + ty) << 8) + X0 + tx;
    float l0 = b_de[0], l1 = b_de[1];

    #pragma unroll
    for (int c = 0; c < 16; ++c) {
        float v = bf2f(gnn[((size_t)(n * 16 + c) << 16) + pix]);
        l0 = fmaf(v, sDe[c * 2 + 0], l0);
        l1 = fmaf(v, sDe[c * 2 + 1], l1);
    }

    float ct[3][3];
    #pragma unroll
    for (int a = 0; a < 3; ++a)
        #pragma unroll
        for (int b = 0; b < 3; ++b)
            ct[a][b] = sCts[ty + a][tx + b];
    #pragma unroll
    for (int c = 0; c < 16; ++c) {
        float a1 = sB1[c];
        #pragma unroll
        for (int t9 = 0; t9 < 9; ++t9)
            a1 = fmaf(ct[t9 / 3][t9 % 3], sWd1[c * 9 + t9], a1);
        float v = fmaxf(a1, 0.f);
        l0 = fmaf(v, sDe[(16 + c) * 2 + 0], l0);
        l1 = fmaf(v, sDe[(16 + c) * 2 + 1], l1);
    }

    float m = fmaxf(l0, l1);
    float e0 = expf(l0 - m), e1 = expf(l1 - m);
    float inv = 1.f / (e0 + e1);
    size_t base = ((size_t)n * 2) << 16;
    out[base + pix] = e0 * inv;
    out[base + 65536 + pix] = e1 * inv;
}

// ===========================================================================

extern "C" void kernel_launch(void* const* d_in, const int* in_sizes, int n_in,
                              void* d_out, int out_size, void* d_ws, size_t ws_size,
                              hipStream_t stream)
{
    const float* cts  = (const float*)d_in[0];
    const int*   prng = (const int*)d_in[1];
    const float* w_d1 = (const float*)d_in[2];  const float* b_d1 = (const float*)d_in[3];
    const float* w_d2 = (const float*)d_in[4];  const float* b_d2 = (const float*)d_in[5];
    const float* w_d3 = (const float*)d_in[6];  const float* b_d3 = (const float*)d_in[7];
    const float* w_d4 = (const float*)d_in[8];  const float* b_d4 = (const float*)d_in[9];
    const float* w_u1 = (const float*)d_in[10]; const float* b_u1 = (const float*)d_in[11];
    const float* w_u2 = (const float*)d_in[12]; const float* b_u2 = (const float*)d_in[13];
    const float* w_u3 = (const float*)d_in[14]; const float* b_u3 = (const float*)d_in[15];
    const float* w_ga = (const float*)d_in[16]; const float* b_ga = (const float*)d_in[17];
    const float* w_gu = (const float*)d_in[18]; const float* b_gu = (const float*)d_in[19];
    const float* w_de = (const float*)d_in[20]; const float* b_de = (const float*)d_in[21];

    const int H = 256, Wd = 256;
    const int N = in_sizes[0] / (H * Wd);   // 32

    // ---- workspace layout (192 MiB total), lifetime reuse ----
    char* wsb = (char*)d_ws;
    bf* u3 = (bf*)(wsb);
    bf* R1 = (bf*)(wsb + 67108864);

    bf* d1 = R1;
    bf* d2 = (bf*)(wsb + 134217728);
    bf* d3 = (bf*)(wsb + 134217728 + 33554432);
    bf* d4 = (bf*)(wsb + 134217728 + 50331648);
    bf* u1 = R1;
    bf* u2 = (bf*)(wsb + 67108864 + 16777216);
    bf* ga = R1;
    bf* gnn = R1;
    bf* agg = (bf*)(wsb + 134217728);
    float* simp = (float*)(wsb + 134217728);
    float* sim  = (float*)(wsb + 134217728 + 16777216);
    int*   idx  = (int*)d_out + (out_size - 96);

    const int KTOT = 16 * H * Wd;
    const int NCH  = KTOT / 256;            // 4096 chunks

    // encoder
    conv32<float><<<dim3(64, N), 256, 0, stream>>>(cts, cts, 1, 1, w_d1, b_d1, d1, N);
    conv_tiled<bf, 2><<<dim3(64, N, 2), 256, 0, stream>>>(
        d1, (const bf*)nullptr, 16, 16, w_d2, b_d2, d2, N, 256, 256, 32, 128, 128, 8);
    conv_tiled<bf, 2><<<dim3(16, N, 4), 256, 0, stream>>>(
        d2, (const bf*)nullptr, 32, 32, w_d3, b_d3, d3, N, 128, 128, 64, 64, 64, 4);
    conv_tiled<bf, 2><<<dim3(4, N, 8), 256, 0, stream>>>(
        d3, (const bf*)nullptr, 64, 64, w_d4, b_d4, d4, N, 64, 64, 128, 32, 32, 2);
    // decoder (all transposed convs via MFMA)
    convt_mfma<128, 128><<<dim3(4, N, 4), 256, 0, stream>>>(
        d4, d4, w_u1, b_u1, u1, N, 32, 32, 64, 64, 64, 2);
    convt_mfma<128, 64><<<dim3(16, N, 2), 256, 0, stream>>>(
        u1, d3, w_u2, b_u2, u2, N, 64, 64, 32, 128, 128, 4);
    convt_mfma<64, 32><<<dim3(64, N, 1), 256, 0, stream>>>(
        u2, d2, w_u3, b_u3, u3, N, 128, 128, 16, 256, 256, 8);
    // cosine similarity + top-3 (Gram via MFMA)
    sim_partial<<<NCH, 256, 0, stream>>>(u3, simp, KTOT);
    sim_reduce<<<dim3(N * N), 256, 0, stream>>>(simp, sim, NCH);
    topk_kernel<<<1, 64, 0, stream>>>(sim, prng, idx, N);
    // per-slice gnn-neighbor conv (MFMA), then gather-mean
    conv_mfma<16, 160><<<dim3(256, N), 256, 0, stream>>>(
        u3, u3, 16, w_ga, b_ga, ga, N);
    gather_mean<<<dim3(512, N), 256, 0, stream>>>(ga, idx, agg);
    // gnn conv (MFMA, 32ch from u3|agg) then light head
    conv_mfma<32, 288><<<dim3(256, N), 256, 0, stream>>>(
        u3, agg, 16, w_gu, b_gu, gnn, N);
    head_tiled<<<dim3(256, N), 256, 0, stream>>>(
        cts, gnn, w_d1, b_d1, w_de, b_de, (float*)d_out, N);
}

// Round 24
// 1384.961 us; speedup vs baseline: 1.3258x; 1.0118x over previous
//
#include <hip/hip_runtime.h>
#include <hip/hip_bf16.h>
#include <math.h>

typedef __hip_bfloat16 bf;
typedef __attribute__((ext_vector_type(8))) short bf8v;   // 8 bf16 = 4 VGPR
typedef __attribute__((ext_vector_type(4))) float f4v;

__device__ __forceinline__ float bf2f(bf v) { return __bfloat162float(v); }
__device__ __forceinline__ bf f2bf(float v) { return __float2bfloat16(v); }
__device__ __forceinline__ unsigned packbf(float a, float b) {
    __hip_bfloat16_raw ra = (__hip_bfloat16_raw)__float2bfloat16(a);
    __hip_bfloat16_raw rb = (__hip_bfloat16_raw)__float2bfloat16(b);
    return (unsigned)ra.x | ((unsigned)rb.x << 16);
}

// ===========================================================================
// Tiled direct 3x3 conv, stride 2 (d2,d3,d4). 16x16 out tile.
// ===========================================================================
template <typename TIN, int STRIDE>
__global__ __launch_bounds__(256)
void conv_tiled(const TIN* __restrict__ inA, const TIN* __restrict__ inB,
                int CiA, int Ci,
                const float* __restrict__ Wt, const float* __restrict__ Bias,
                bf* __restrict__ out,
                int N, int Hi, int Wi, int Co, int Ho, int Wo, int tilesX)
{
    constexpr int TS = 16;
    constexpr int IH = (TS - 1) * STRIDE + 3;
    constexpr int IWP = (IH % 2 == 0) ? IH + 1 : IH;
    constexpr int CHUNK = 8;

    __shared__ TIN  sIn[CHUNK * IH * IWP];
    __shared__ __align__(16) float sW[CHUNK * 144];

    int tile = blockIdx.x;
    int tx0 = (tile % tilesX) * TS, ty0 = (tile / tilesX) * TS;
    int n = blockIdx.y;
    int cog0 = blockIdx.z * 16;
    int t = threadIdx.x;
    int tx = t & 15, ty = t >> 4;
    int CiB = Ci - CiA;

    float acc[16];
    #pragma unroll
    for (int c = 0; c < 16; ++c) acc[c] = Bias[cog0 + c];

    for (int cb = 0; cb < Ci; cb += CHUNK) {
        int cn = (Ci - cb < CHUNK) ? (Ci - cb) : CHUNK;
        for (int e = t; e < cn * IH * IH; e += 256) {
            int ci = e / (IH * IH);
            int rem = e % (IH * IH);
            int py = rem / IH, px = rem % IH;
            int iy = ty0 * STRIDE - 1 + py;
            int ix = tx0 * STRIDE - 1 + px;
            int gci = cb + ci;
            const TIN* src = (gci < CiA)
                ? inA + (size_t)(n * CiA + gci) * Hi * Wi
                : inB + (size_t)(n * CiB + gci - CiA) * Hi * Wi;
            float v = ((unsigned)iy < (unsigned)Hi && (unsigned)ix < (unsigned)Wi)
                      ? (float)src[(size_t)iy * Wi + ix] : 0.f;
            sIn[ci * IH * IWP + py * IWP + px] = (TIN)v;
        }
        for (int e = t; e < cn * 144; e += 256) {
            int ci = e / 144, rem = e % 144;
            int t9 = rem / 16, co = rem % 16;
            sW[ci * 144 + t9 * 16 + co] =
                Wt[(size_t)(cog0 + co) * Ci * 9 + (cb + ci) * 9 + t9];
        }
        __syncthreads();
        for (int ci = 0; ci < cn; ++ci) {
            #pragma unroll
            for (int t9 = 0; t9 < 9; ++t9) {
                int ky = t9 / 3, kx = t9 % 3;
                float v = (float)sIn[ci * IH * IWP + (ty * STRIDE + ky) * IWP
                                     + (tx * STRIDE + kx)];
                const float* wp = &sW[ci * 144 + t9 * 16];
                #pragma unroll
                for (int co = 0; co < 16; ++co)
                    acc[co] = fmaf(v, wp[co], acc[co]);
            }
        }
        __syncthreads();
    }

    int oy = ty0 + ty, ox = tx0 + tx;
    #pragma unroll
    for (int co = 0; co < 16; ++co)
        out[(size_t)(n * Co + cog0 + co) * Ho * Wo + (size_t)oy * Wo + ox]
            = f2bf(fmaxf(acc[co], 0.f));
}

// ===========================================================================
// Stride-1 conv (d1 only, Ci=1). 32x32 tile, 2x2 px/thread.
// ===========================================================================
template <typename TIN>
__global__ __launch_bounds__(256)
void conv32(const TIN* __restrict__ inA, const TIN* __restrict__ inB,
            int CiA, int Ci,
            const float* __restrict__ Wt, const float* __restrict__ Bias,
            bf* __restrict__ out, int N)
{
    constexpr int CHUNK = 4;
    __shared__ float sIn[CHUNK][34][35];
    __shared__ __align__(16) float sW[CHUNK][9][16];

    int tile = blockIdx.x;
    int X0 = (tile & 7) * 32, Y0 = (tile >> 3) * 32;
    int n = blockIdx.y;
    int t = threadIdx.x, tx = t & 15, ty = t >> 4;
    int CiB = Ci - CiA;

    float acc[4][16];
    #pragma unroll
    for (int p = 0; p < 4; ++p)
        #pragma unroll
        for (int c = 0; c < 16; ++c) acc[p][c] = 0.f;

    for (int cb = 0; cb < Ci; cb += CHUNK) {
        int cn = (Ci - cb < CHUNK) ? Ci - cb : CHUNK;
        for (int e = t; e < cn * 1156; e += 256) {
            int ci = e / 1156, rem = e % 1156;
            int py = rem / 34, px = rem % 34;
            int iy = Y0 - 1 + py, ix = X0 - 1 + px;
            int gci = cb + ci;
            const TIN* src = (gci < CiA)
                ? inA + ((size_t)(n * CiA + gci) << 16)
                : inB + ((size_t)(n * CiB + gci - CiA) << 16);
            sIn[ci][py][px] = ((unsigned)iy < 256u && (unsigned)ix < 256u)
                              ? (float)src[(iy << 8) + ix] : 0.f;
        }
        for (int e = t; e < cn * 144; e += 256) {
            int ci = e / 144, rem = e % 144;
            int t9 = rem / 16, co = rem % 16;
            sW[ci][t9][co] = Wt[(size_t)co * Ci * 9 + (cb + ci) * 9 + t9];
        }
        __syncthreads();
        for (int ci = 0; ci < cn; ++ci) {
            float rin[4][4];
            #pragma unroll
            for (int a = 0; a < 4; ++a)
                #pragma unroll
                for (int b = 0; b < 4; ++b)
                    rin[a][b] = sIn[ci][2 * ty + a][2 * tx + b];
            #pragma unroll
            for (int t9 = 0; t9 < 9; ++t9) {
                const int ky = t9 / 3, kx = t9 % 3;
                float w[16];
                #pragma unroll
                for (int q = 0; q < 4; ++q)
                    *(float4*)&w[q * 4] = *(const float4*)&sW[ci][t9][q * 4];
                #pragma unroll
                for (int ry = 0; ry < 2; ++ry)
                    #pragma unroll
                    for (int rx = 0; rx < 2; ++rx) {
                        float v = rin[ry + ky][rx + kx];
                        #pragma unroll
                        for (int co = 0; co < 16; ++co)
                            acc[ry * 2 + rx][co] = fmaf(v, w[co], acc[ry * 2 + rx][co]);
                    }
            }
        }
        __syncthreads();
    }

    #pragma unroll
    for (int co = 0; co < 16; ++co) {
        float bs = Bias[co];
        bf* dst = out + ((size_t)(n * 16 + co) << 16);
        #pragma unroll
        for (int ry = 0; ry < 2; ++ry) {
            unsigned pk = packbf(fmaxf(acc[ry * 2 + 0][co] + bs, 0.f),
                                 fmaxf(acc[ry * 2 + 1][co] + bs, 0.f));
            *(unsigned*)(dst + ((Y0 + 2 * ty + ry) << 8) + X0 + 2 * tx) = pk;
        }
    }
}

// ===========================================================================
// MFMA implicit-GEMM stride-1 conv, CONTIGUOUS A-reads (r23 transform):
// channel-minor input sIn2[18][19][CIP], tap-major weights kl = tap*CI + ci.
// CI=32 (KPAD=288): 9 chains, tap = s (compile-time), ciofs = q*8.
// CI=16 (KPAD=160): 5 chains, tap = 2s+(q>>1) clamped to 8 (kl>=144 weights
// are zero so the clamped duplicate contributes 0), ciofs = (q&1)*8.
// Fragment/epilogue layouts identical to the round-13-verified conv_mfma.
// ===========================================================================
template <int CI, int CIP, int KPAD>
__global__ __launch_bounds__(256)
void conv_mfma(const bf* __restrict__ inA, const bf* __restrict__ inB,
               int CiA,
               const float* __restrict__ Wt, const float* __restrict__ Bias,
               bf* __restrict__ out, int N)
{
    constexpr int K = CI * 9;
    constexpr int NM = KPAD / 32;
    __shared__ __align__(16) bf sIn2[18][19][CIP];
    __shared__ __align__(16) bf sWt[16][KPAD];

    int tile = blockIdx.x;
    int X0 = (tile & 15) * 16, Y0 = (tile >> 4) * 16;
    int n = blockIdx.y;
    int t = threadIdx.x;
    int lane = t & 63, wave = t >> 6;
    int q = lane >> 4, mcol = lane & 15;
    int CiB = CI - CiA;

    // weights: kl = tap*CI + ci  ->  Wt[co][ci][tap]
    for (int e = t; e < 16 * KPAD; e += 256) {
        int co = e / KPAD, k = e % KPAD;
        int tap = k / CI, ci = k % CI;
        sWt[co][k] = (k < K) ? f2bf(Wt[(size_t)co * K + ci * 9 + tap]) : f2bf(0.f);
    }
    // input: channel-minor [py][px][ci], 18x18 valid
    for (int e = t; e < CI * 324; e += 256) {
        int ci = e / 324, rem = e % 324;
        int py = rem / 18, px = rem % 18;
        int iy = Y0 - 1 + py, ix = X0 - 1 + px;
        const bf* src = (ci < CiA)
            ? inA + ((size_t)(n * CiA + ci) << 16)
            : inB + ((size_t)(n * CiB + ci - CiA) << 16);
        bf v;
        if ((unsigned)iy < 256u && (unsigned)ix < 256u) v = src[(iy << 8) + ix];
        else v = f2bf(0.f);
        sIn2[py][px][ci] = v;
    }
    __syncthreads();

    f4v acc[4];
    #pragma unroll
    for (int g = 0; g < 4; ++g) acc[g] = (f4v){0.f, 0.f, 0.f, 0.f};

    int prow0 = wave * 4;
    #pragma unroll
    for (int s = 0; s < NM; ++s) {
        bf8v wf = *(const bf8v*)&sWt[mcol][s * 32 + q * 8];
        int tap, ciofs;
        if (CI == 32) { tap = s;               ciofs = q * 8; }
        else          { tap = 2 * s + (q >> 1); if (tap > 8) tap = 8;
                        ciofs = (q & 1) * 8; }
        int ay = tap / 3, ax = tap - ay * 3;
        #pragma unroll
        for (int g = 0; g < 4; ++g) {
            bf8v af = *(const bf8v*)&sIn2[prow0 + g + ay][mcol + ax][ciofs];
            acc[g] = __builtin_amdgcn_mfma_f32_16x16x32_bf16(af, wf, acc[g], 0, 0, 0);
        }
    }

    float bs = Bias[mcol];
    bf* dst = out + ((size_t)(n * 16 + mcol) << 16);
    #pragma unroll
    for (int g = 0; g < 4; ++g) {
        int oy = Y0 + prow0 + g, ox = X0 + q * 4;
        uint2 pk;
        pk.x = packbf(fmaxf(acc[g][0] + bs, 0.f), fmaxf(acc[g][1] + bs, 0.f));
        pk.y = packbf(fmaxf(acc[g][2] + bs, 0.f), fmaxf(acc[g][3] + bs, 0.f));
        *(uint2*)(dst + (oy << 8) + ox) = pk;
    }
}

// ===========================================================================
// MFMA phase-decomposed transposed conv (k=3,s=2,p=1,op=1): u1,u2,u3.
// (round-23-verified cic-minor contiguous form)
// ===========================================================================
#define CVT_CHAIN(PH, KOFF, AY, AX)                                           \
    {                                                                          \
        bf8v wf = *(const bf8v*)&sWt[mcol][(KOFF) + q * 8];                    \
        _Pragma("unroll")                                                      \
        for (int g = 0; g < 4; ++g) {                                          \
            bf8v af = *(const bf8v*)&sIn2[prow0 + g + (AY)][mcol + (AX)][q * 8];\
            acc[PH][g] = __builtin_amdgcn_mfma_f32_16x16x32_bf16(af, wf,       \
                                                      acc[PH][g], 0, 0, 0);    \
        }                                                                      \
    }

template <int CITOT, int CIA>
__global__ __launch_bounds__(256)
void convt_mfma(const bf* __restrict__ inA, const bf* __restrict__ inB,
                const float* __restrict__ Wt, const float* __restrict__ Bias,
                bf* __restrict__ out,
                int N, int Hi, int Wi, int Cotot, int Ho, int Wo, int tilesX)
{
    constexpr int NCH = CITOT / 32;
    __shared__ __align__(16) bf sIn2[17][18][40];  // [py][px][ci pad40] 24.5KB
    __shared__ __align__(16) bf sWt[16][328];      // phase bases 0,40,112,184

    int tile = blockIdx.x;
    int J0 = (tile % tilesX) * 16, I0 = (tile / tilesX) * 16;
    int n = blockIdx.y;
    int cog0 = blockIdx.z * 16;
    int t = threadIdx.x;
    int lane = t & 63, wave = t >> 6;
    int q = lane >> 4, mcol = lane & 15;
    int prow0 = wave * 4;

    f4v acc[4][4];
    #pragma unroll
    for (int p = 0; p < 4; ++p)
        #pragma unroll
        for (int g = 0; g < 4; ++g) acc[p][g] = (f4v){0.f, 0.f, 0.f, 0.f};

    for (int cb = 0; cb < NCH; ++cb) {
        if (cb) __syncthreads();                  // drain reads before restage
        for (int e = t; e < 32 * 306; e += 256) {
            int ci = e / 306, rem = e % 306;
            int py = rem / 18, px = rem % 18;
            int iy = I0 + py, ix = J0 + px;
            int gci = cb * 32 + ci;
            const bf* src = (gci < CIA)
                ? inA + (size_t)(n * CIA + gci) * Hi * Wi
                : inB + (size_t)(n * (CITOT - CIA) + gci - CIA) * Hi * Wi;
            sIn2[py][px][ci] = (iy < Hi && px < 17 && ix < Wi)
                               ? src[(size_t)iy * Wi + ix] : f2bf(0.f);
        }
        for (int e = t; e < 16 * 288; e += 256) {
            int co = e / 288, rem = e % 288;
            int cic = rem / 9, t9 = rem % 9;
            int ky = t9 / 3, kx = t9 % 3;
            int ry = (ky == 1) ? 0 : 1;
            int rx = (kx == 1) ? 0 : 1;
            int ty = (ky == 1) ? 0 : (ky >> 1);
            int txi = (kx == 1) ? 0 : (kx >> 1);
            int ntx = 1 + rx;
            int ph = ry * 2 + rx;
            const int base4[4] = {0, 40, 112, 184};
            int kl = (ty * ntx + txi) * 32 + cic;      // cic-minor k order
            sWt[co][base4[ph] + kl] =
                f2bf(Wt[(size_t)(cog0 + co) * CITOT * 9
                        + (size_t)(cb * 32 + cic) * 9 + t9]);
        }
        __syncthreads();

        //        PH  KOFF AY AX      (chain = one tap over 32 channels)
        CVT_CHAIN(0,   0, 0, 0)    // phase (ry0,rx0): tap (1,1)
        CVT_CHAIN(1,  40, 0, 0)    // phase (ry0,rx1): tap kx=0
        CVT_CHAIN(1,  72, 0, 1)    //                  tap kx=2
        CVT_CHAIN(2, 112, 0, 0)    // phase (ry1,rx0): tap ky=0
        CVT_CHAIN(2, 144, 1, 0)    //                  tap ky=2
        CVT_CHAIN(3, 184, 0, 0)    // phase (ry1,rx1): tap (0,0)
        CVT_CHAIN(3, 216, 0, 1)    //                  tap (0,2)
        CVT_CHAIN(3, 248, 1, 0)    //                  tap (2,0)
        CVT_CHAIN(3, 280, 1, 1)    //                  tap (2,2)
    }

    float bs = Bias[cog0 + mcol];
    bf* dst = out + (size_t)(n * Cotot + cog0 + mcol) * Ho * Wo;
    #pragma unroll
    for (int ph = 0; ph < 4; ++ph) {
        const int ry = ph >> 1, rx = ph & 1;
        #pragma unroll
        for (int g = 0; g < 4; ++g) {
            int oy = 2 * (I0 + prow0 + g) + ry;
            #pragma unroll
            for (int jj = 0; jj < 4; ++jj) {
                int ox = 2 * (J0 + q * 4 + jj) + rx;
                dst[(size_t)oy * Wo + ox] = f2bf(fmaxf(acc[ph][g][jj] + bs, 0.f));
            }
        }
    }
}

// ===========================================================================
// MFMA Gram partials (verified round 20).
// ===========================================================================
__global__ __launch_bounds__(256)
void sim_partial(const bf* __restrict__ f, float* __restrict__ part, int KTOT)
{
    __shared__ __align__(16) bf tile[32][264];
    int c = blockIdx.x;
    int t = threadIdx.x;
    int k0 = c << 8;

    for (int e = t; e < 1024; e += 256) {
        int row = e >> 5, col8 = (e & 31) * 8;
        uint4 v = *(const uint4*)&f[(size_t)row * KTOT + k0 + col8];
        *(uint4*)&tile[row][col8] = v;
    }
    __syncthreads();

    int lane = t & 63, wave = t >> 6;
    int q = lane >> 4, mcol = lane & 15;
    int qr = wave >> 1, qc = wave & 1;

    f4v acc = (f4v){0.f, 0.f, 0.f, 0.f};
    #pragma unroll
    for (int ks = 0; ks < 8; ++ks) {
        bf8v a = *(const bf8v*)&tile[qr * 16 + mcol][ks * 32 + q * 8];
        bf8v b = *(const bf8v*)&tile[qc * 16 + mcol][ks * 32 + q * 8];
        acc = __builtin_amdgcn_mfma_f32_16x16x32_bf16(a, b, acc, 0, 0, 0);
    }

    float* dst = part + (size_t)c * 1024;
    #pragma unroll
    for (int jj = 0; jj < 4; ++jj) {
        int i = qr * 16 + q * 4 + jj;
        int j = qc * 16 + mcol;
        dst[i * 32 + j] = acc[jj];
    }
}

__global__ __launch_bounds__(256)
void sim_reduce(const float* __restrict__ part, float* __restrict__ sim, int nchunks)
{
    __shared__ float red[256];
    int pair = blockIdx.x;
    int t = threadIdx.x;
    float s = 0.f;
    for (int k = t; k < nchunks; k += 256)
        s += part[(size_t)k * 1024 + pair];
    red[t] = s;
    __syncthreads();
    #pragma unroll
    for (int off = 128; off > 0; off >>= 1) {
        if (t < off) red[t] += red[t + off];
        __syncthreads();
    }
    if (t == 0) sim[pair] = red[0];
}

// ===========================================================================
// Cosine sim + group mask + top-3 (strict >, lowest index wins ties).
// ===========================================================================
__global__ void topk_kernel(const float* __restrict__ sim, const int* __restrict__ prange,
                            int* __restrict__ idx, int N)
{
    int i = threadIdx.x;
    if (i >= N) return;
    float nm_i = fmaxf(sqrtf(sim[i * N + i]), 1e-8f);
    int p0 = prange[0], p1 = prange[1];
    int gi = (i >= p0) + (i >= p1);
    float vals[32];
    for (int j = 0; j < N; ++j) {
        int gj = (j >= p0) + (j >= p1);
        if (j == i || gj != gi) { vals[j] = -1e30f; continue; }
        float nm_j = fmaxf(sqrtf(sim[j * N + j]), 1e-8f);
        vals[j] = sim[i * N + j] / (nm_i * nm_j);
    }
    for (int k = 0; k < 3; ++k) {
        float best = -2e30f; int bj = 0;
        for (int j = 0; j < N; ++j)
            if (vals[j] > best) { best = vals[j]; bj = j; }
        idx[i * 3 + k] = bj;
        vals[bj] = -1e30f;
    }
}

// ===========================================================================
// Gather-mean: agg[n] = (ga[i0] + ga[i1] + ga[i2]) / 3.
// ===========================================================================
__global__ __launch_bounds__(256)
void gather_mean(const bf* __restrict__ ga, const int* __restrict__ idx,
                 bf* __restrict__ agg)
{
    int n = blockIdx.y;
    int v = blockIdx.x * 256 + threadIdx.x;
    int i0 = idx[n * 3 + 0], i1 = idx[n * 3 + 1], i2 = idx[n * 3 + 2];
    const size_t stride = (size_t)16 << 16;
    const uint4* p0 = (const uint4*)(ga + stride * i0) + v;
    const uint4* p1 = (const uint4*)(ga + stride * i1) + v;
    const uint4* p2 = (const uint4*)(ga + stride * i2) + v;
    uint4 a = *p0, b = *p1, c = *p2;
    uint4 r;
    unsigned* ap = (unsigned*)&a; unsigned* bp = (unsigned*)&b;
    unsigned* cp = (unsigned*)&c; unsigned* rp = (unsigned*)&r;
    #pragma unroll
    for (int w = 0; w < 4; ++w) {
        float fa0 = __bfloat162float((__hip_bfloat16_raw){(unsigned short)(ap[w] & 0xffff)});
        float fb0 = __bfloat162float((__hip_bfloat16_raw){(unsigned short)(bp[w] & 0xffff)});
        float fc0 = __bfloat162float((__hip_bfloat16_raw){(unsigned short)(cp[w] & 0xffff)});
        float fa1 = __bfloat162float((__hip_bfloat16_raw){(unsigned short)(ap[w] >> 16)});
        float fb1 = __bfloat162float((__hip_bfloat16_raw){(unsigned short)(bp[w] >> 16)});
        float fc1 = __bfloat162float((__hip_bfloat16_raw){(unsigned short)(cp[w] >> 16)});
        rp[w] = packbf((fa0 + fb0 + fc0) * (1.f / 3.f),
                       (fa1 + fb1 + fc1) * (1.f / 3.f));
    }
    *((uint4*)(agg + stride * n) + v) = r;
}

// ===========================================================================
// Light head: gnn (bf16) + d1 recompute + dense 32->2 + softmax.
// ===========================================================================
__global__ __launch_bounds__(256)
void head_tiled(const float* __restrict__ cts, const bf* __restrict__ gnn,
                const float* __restrict__ w_d1, const float* __restrict__ b_d1,
                const float* __restrict__ w_de, const float* __restrict__ b_de,
                float* __restrict__ out, int N)
{
    __shared__ float sCts[18][19];
    __shared__ float sWd1[144];
    __shared__ float sB1[16];
    __shared__ float sDe[64];

    int tile = blockIdx.x;
    int X0 = (tile & 15) * 16, Y0 = (tile >> 4) * 16;
    int n = blockIdx.y;
    int t = threadIdx.x, tx = t & 15, ty = t >> 4;

    for (int e = t; e < 18 * 18; e += 256) {
        int py = e / 18, px = e % 18;
        int iy = Y0 - 1 + py, ix = X0 - 1 + px;
        sCts[py][px] = ((unsigned)iy < 256u && (unsigned)ix < 256u)
                       ? cts[((size_t)n << 16) + (iy << 8) + ix] : 0.f;
    }
    if (t < 144) sWd1[t] = w_d1[t];
    else if (t < 160) sB1[t - 144] = b_d1[t - 144];
    else if (t >= 192 && t < 256) sDe[t - 192] = w_de[t - 192];
    __syncthreads();

    int pix = ((Y0 + ty) << 8) + X0 + tx;
    float l0 = b_de[0], l1 = b_de[1];

    #pragma unroll
    for (int c = 0; c < 16; ++c) {
        float v = bf2f(gnn[((size_t)(n * 16 + c) << 16) + pix]);
        l0 = fmaf(v, sDe[c * 2 + 0], l0);
        l1 = fmaf(v, sDe[c * 2 + 1], l1);
    }

    float ct[3][3];
    #pragma unroll
    for (int a = 0; a < 3; ++a)
        #pragma unroll
        for (int b = 0; b < 3; ++b)
            ct[a][b] = sCts[ty + a][tx + b];
    #pragma unroll
    for (int c = 0; c < 16; ++c) {
        float a1 = sB1[c];
        #pragma unroll
        for (int t9 = 0; t9 < 9; ++t9)
            a1 = fmaf(ct[t9 / 3][t9 % 3], sWd1[c * 9 + t9], a1);
        float v = fmaxf(a1, 0.f);
        l0 = fmaf(v, sDe[(16 + c) * 2 + 0], l0);
        l1 = fmaf(v, sDe[(16 + c) * 2 + 1], l1);
    }

    float m = fmaxf(l0, l1);
    float e0 = expf(l0 - m), e1 = expf(l1 - m);
    float inv = 1.f / (e0 + e1);
    size_t base = ((size_t)n * 2) << 16;
    out[base + pix] = e0 * inv;
    out[base + 65536 + pix] = e1 * inv;
}

// ===========================================================================

extern "C" void kernel_launch(void* const* d_in, const int* in_sizes, int n_in,
                              void* d_out, int out_size, void* d_ws, size_t ws_size,
                              hipStream_t stream)
{
    const float* cts  = (const float*)d_in[0];
    const int*   prng = (const int*)d_in[1];
    const float* w_d1 = (const float*)d_in[2];  const float* b_d1 = (const float*)d_in[3];
    const float* w_d2 = (const float*)d_in[4];  const float* b_d2 = (const float*)d_in[5];
    const float* w_d3 = (const float*)d_in[6];  const float* b_d3 = (const float*)d_in[7];
    const float* w_d4 = (const float*)d_in[8];  const float* b_d4 = (const float*)d_in[9];
    const float* w_u1 = (const float*)d_in[10]; const float* b_u1 = (const float*)d_in[11];
    const float* w_u2 = (const float*)d_in[12]; const float* b_u2 = (const float*)d_in[13];
    const float* w_u3 = (const float*)d_in[14]; const float* b_u3 = (const float*)d_in[15];
    const float* w_ga = (const float*)d_in[16]; const float* b_ga = (const float*)d_in[17];
    const float* w_gu = (const float*)d_in[18]; const float* b_gu = (const float*)d_in[19];
    const float* w_de = (const float*)d_in[20]; const float* b_de = (const float*)d_in[21];

    const int H = 256, Wd = 256;
    const int N = in_sizes[0] / (H * Wd);   // 32

    // ---- workspace layout (192 MiB total), lifetime reuse ----
    char* wsb = (char*)d_ws;
    bf* u3 = (bf*)(wsb);
    bf* R1 = (bf*)(wsb + 67108864);

    bf* d1 = R1;
    bf* d2 = (bf*)(wsb + 134217728);
    bf* d3 = (bf*)(wsb + 134217728 + 33554432);
    bf* d4 = (bf*)(wsb + 134217728 + 50331648);
    bf* u1 = R1;
    bf* u2 = (bf*)(wsb + 67108864 + 16777216);
    bf* ga = R1;
    bf* gnn = R1;
    bf* agg = (bf*)(wsb + 134217728);
    float* simp = (float*)(wsb + 134217728);
    float* sim  = (float*)(wsb + 134217728 + 16777216);
    int*   idx  = (int*)d_out + (out_size - 96);

    const int KTOT = 16 * H * Wd;
    const int NCH  = KTOT / 256;            // 4096 chunks

    // encoder
    conv32<float><<<dim3(64, N), 256, 0, stream>>>(cts, cts, 1, 1, w_d1, b_d1, d1, N);
    conv_tiled<bf, 2><<<dim3(64, N, 2), 256, 0, stream>>>(
        d1, (const bf*)nullptr, 16, 16, w_d2, b_d2, d2, N, 256, 256, 32, 128, 128, 8);
    conv_tiled<bf, 2><<<dim3(16, N, 4), 256, 0, stream>>>(
        d2, (const bf*)nullptr, 32, 32, w_d3, b_d3, d3, N, 128, 128, 64, 64, 64, 4);
    conv_tiled<bf, 2><<<dim3(4, N, 8), 256, 0, stream>>>(
        d3, (const bf*)nullptr, 64, 64, w_d4, b_d4, d4, N, 64, 64, 128, 32, 32, 2);
    // decoder (all transposed convs via MFMA)
    convt_mfma<128, 128><<<dim3(4, N, 4), 256, 0, stream>>>(
        d4, d4, w_u1, b_u1, u1, N, 32, 32, 64, 64, 64, 2);
    convt_mfma<128, 64><<<dim3(16, N, 2), 256, 0, stream>>>(
        u1, d3, w_u2, b_u2, u2, N, 64, 64, 32, 128, 128, 4);
    convt_mfma<64, 32><<<dim3(64, N, 1), 256, 0, stream>>>(
        u2, d2, w_u3, b_u3, u3, N, 128, 128, 16, 256, 256, 8);
    // cosine similarity + top-3 (Gram via MFMA)
    sim_partial<<<NCH, 256, 0, stream>>>(u3, simp, KTOT);
    sim_reduce<<<dim3(N * N), 256, 0, stream>>>(simp, sim, NCH);
    topk_kernel<<<1, 64, 0, stream>>>(sim, prng, idx, N);
    // per-slice gnn-neighbor conv (MFMA, contiguous A-reads), then gather-mean
    conv_mfma<16, 20, 160><<<dim3(256, N), 256, 0, stream>>>(
        u3, u3, 16, w_ga, b_ga, ga, N);
    gather_mean<<<dim3(512, N), 256, 0, stream>>>(ga, idx, agg);
    // gnn conv (MFMA, 32ch from u3|agg, contiguous A-reads) then light head
    conv_mfma<32, 40, 288><<<dim3(256, N), 256, 0, stream>>>(
        u3, agg, 16, w_gu, b_gu, gnn, N);
    head_tiled<<<dim3(256, N), 256, 0, stream>>>(
        cts, gnn, w_d1, b_d1, w_de, b_de, (float*)d_out, N);
}

// Round 25
// 1237.375 us; speedup vs baseline: 1.4840x; 1.1193x over previous
//
#include <hip/hip_runtime.h>
#include <hip/hip_bf16.h>
#include <math.h>

typedef __hip_bfloat16 bf;
typedef __attribute__((ext_vector_type(8))) short bf8v;   // 8 bf16 = 4 VGPR
typedef __attribute__((ext_vector_type(4))) float f4v;

__device__ __forceinline__ float bf2f(bf v) { return __bfloat162float(v); }
__device__ __forceinline__ bf f2bf(float v) { return __float2bfloat16(v); }
__device__ __forceinline__ unsigned packbf(float a, float b) {
    __hip_bfloat16_raw ra = (__hip_bfloat16_raw)__float2bfloat16(a);
    __hip_bfloat16_raw rb = (__hip_bfloat16_raw)__float2bfloat16(b);
    return (unsigned)ra.x | ((unsigned)rb.x << 16);
}

// ===========================================================================
// Tiled direct 3x3 conv, stride 2 (d2,d3,d4). 16x16 out tile.
// ===========================================================================
template <typename TIN, int STRIDE>
__global__ __launch_bounds__(256)
void conv_tiled(const TIN* __restrict__ inA, const TIN* __restrict__ inB,
                int CiA, int Ci,
                const float* __restrict__ Wt, const float* __restrict__ Bias,
                bf* __restrict__ out,
                int N, int Hi, int Wi, int Co, int Ho, int Wo, int tilesX)
{
    constexpr int TS = 16;
    constexpr int IH = (TS - 1) * STRIDE + 3;
    constexpr int IWP = (IH % 2 == 0) ? IH + 1 : IH;
    constexpr int CHUNK = 8;

    __shared__ TIN  sIn[CHUNK * IH * IWP];
    __shared__ __align__(16) float sW[CHUNK * 144];

    int tile = blockIdx.x;
    int tx0 = (tile % tilesX) * TS, ty0 = (tile / tilesX) * TS;
    int n = blockIdx.y;
    int cog0 = blockIdx.z * 16;
    int t = threadIdx.x;
    int tx = t & 15, ty = t >> 4;
    int CiB = Ci - CiA;

    float acc[16];
    #pragma unroll
    for (int c = 0; c < 16; ++c) acc[c] = Bias[cog0 + c];

    for (int cb = 0; cb < Ci; cb += CHUNK) {
        int cn = (Ci - cb < CHUNK) ? (Ci - cb) : CHUNK;
        for (int e = t; e < cn * IH * IH; e += 256) {
            int ci = e / (IH * IH);
            int rem = e % (IH * IH);
            int py = rem / IH, px = rem % IH;
            int iy = ty0 * STRIDE - 1 + py;
            int ix = tx0 * STRIDE - 1 + px;
            int gci = cb + ci;
            const TIN* src = (gci < CiA)
                ? inA + (size_t)(n * CiA + gci) * Hi * Wi
                : inB + (size_t)(n * CiB + gci - CiA) * Hi * Wi;
            float v = ((unsigned)iy < (unsigned)Hi && (unsigned)ix < (unsigned)Wi)
                      ? (float)src[(size_t)iy * Wi + ix] : 0.f;
            sIn[ci * IH * IWP + py * IWP + px] = (TIN)v;
        }
        for (int e = t; e < cn * 144; e += 256) {
            int ci = e / 144, rem = e % 144;
            int t9 = rem / 16, co = rem % 16;
            sW[ci * 144 + t9 * 16 + co] =
                Wt[(size_t)(cog0 + co) * Ci * 9 + (cb + ci) * 9 + t9];
        }
        __syncthreads();
        for (int ci = 0; ci < cn; ++ci) {
            #pragma unroll
            for (int t9 = 0; t9 < 9; ++t9) {
                int ky = t9 / 3, kx = t9 % 3;
                float v = (float)sIn[ci * IH * IWP + (ty * STRIDE + ky) * IWP
                                     + (tx * STRIDE + kx)];
                const float* wp = &sW[ci * 144 + t9 * 16];
                #pragma unroll
                for (int co = 0; co < 16; ++co)
                    acc[co] = fmaf(v, wp[co], acc[co]);
            }
        }
        __syncthreads();
    }

    int oy = ty0 + ty, ox = tx0 + tx;
    #pragma unroll
    for (int co = 0; co < 16; ++co)
        out[(size_t)(n * Co + cog0 + co) * Ho * Wo + (size_t)oy * Wo + ox]
            = f2bf(fmaxf(acc[co], 0.f));
}

// ===========================================================================
// Stride-1 conv (d1 only, Ci=1). 32x32 tile, 2x2 px/thread.
// ===========================================================================
template <typename TIN>
__global__ __launch_bounds__(256)
void conv32(const TIN* __restrict__ inA, const TIN* __restrict__ inB,
            int CiA, int Ci,
            const float* __restrict__ Wt, const float* __restrict__ Bias,
            bf* __restrict__ out, int N)
{
    constexpr int CHUNK = 4;
    __shared__ float sIn[CHUNK][34][35];
    __shared__ __align__(16) float sW[CHUNK][9][16];

    int tile = blockIdx.x;
    int X0 = (tile & 7) * 32, Y0 = (tile >> 3) * 32;
    int n = blockIdx.y;
    int t = threadIdx.x, tx = t & 15, ty = t >> 4;
    int CiB = Ci - CiA;

    float acc[4][16];
    #pragma unroll
    for (int p = 0; p < 4; ++p)
        #pragma unroll
        for (int c = 0; c < 16; ++c) acc[p][c] = 0.f;

    for (int cb = 0; cb < Ci; cb += CHUNK) {
        int cn = (Ci - cb < CHUNK) ? Ci - cb : CHUNK;
        for (int e = t; e < cn * 1156; e += 256) {
            int ci = e / 1156, rem = e % 1156;
            int py = rem / 34, px = rem % 34;
            int iy = Y0 - 1 + py, ix = X0 - 1 + px;
            int gci = cb + ci;
            const TIN* src = (gci < CiA)
                ? inA + ((size_t)(n * CiA + gci) << 16)
                : inB + ((size_t)(n * CiB + gci - CiA) << 16);
            sIn[ci][py][px] = ((unsigned)iy < 256u && (unsigned)ix < 256u)
                              ? (float)src[(iy << 8) + ix] : 0.f;
        }
        for (int e = t; e < cn * 144; e += 256) {
            int ci = e / 144, rem = e % 144;
            int t9 = rem / 16, co = rem % 16;
            sW[ci][t9][co] = Wt[(size_t)co * Ci * 9 + (cb + ci) * 9 + t9];
        }
        __syncthreads();
        for (int ci = 0; ci < cn; ++ci) {
            float rin[4][4];
            #pragma unroll
            for (int a = 0; a < 4; ++a)
                #pragma unroll
                for (int b = 0; b < 4; ++b)
                    rin[a][b] = sIn[ci][2 * ty + a][2 * tx + b];
            #pragma unroll
            for (int t9 = 0; t9 < 9; ++t9) {
                const int ky = t9 / 3, kx = t9 % 3;
                float w[16];
                #pragma unroll
                for (int q = 0; q < 4; ++q)
                    *(float4*)&w[q * 4] = *(const float4*)&sW[ci][t9][q * 4];
                #pragma unroll
                for (int ry = 0; ry < 2; ++ry)
                    #pragma unroll
                    for (int rx = 0; rx < 2; ++rx) {
                        float v = rin[ry + ky][rx + kx];
                        #pragma unroll
                        for (int co = 0; co < 16; ++co)
                            acc[ry * 2 + rx][co] = fmaf(v, w[co], acc[ry * 2 + rx][co]);
                    }
            }
        }
        __syncthreads();
    }

    #pragma unroll
    for (int co = 0; co < 16; ++co) {
        float bs = Bias[co];
        bf* dst = out + ((size_t)(n * 16 + co) << 16);
        #pragma unroll
        for (int ry = 0; ry < 2; ++ry) {
            unsigned pk = packbf(fmaxf(acc[ry * 2 + 0][co] + bs, 0.f),
                                 fmaxf(acc[ry * 2 + 1][co] + bs, 0.f));
            *(unsigned*)(dst + ((Y0 + 2 * ty + ry) << 8) + X0 + 2 * tx) = pk;
        }
    }
}

// ===========================================================================
// MFMA implicit-GEMM stride-1 conv, contiguous A-reads (r23) + VECTORIZED
// global staging (r24): rows split {px0 scalar | px1-8 vec | px9-16 vec |
// px17 scalar}; vec segments are 16B-aligned (X0 mult-16, halo -1).
// ===========================================================================
template <int CI, int CIP, int KPAD>
__global__ __launch_bounds__(256)
void conv_mfma(const bf* __restrict__ inA, const bf* __restrict__ inB,
               int CiA,
               const float* __restrict__ Wt, const float* __restrict__ Bias,
               bf* __restrict__ out, int N)
{
    constexpr int K = CI * 9;
    constexpr int NM = KPAD / 32;
    __shared__ __align__(16) bf sIn2[18][19][CIP];
    __shared__ __align__(16) bf sWt[16][KPAD];

    int tile = blockIdx.x;
    int X0 = (tile & 15) * 16, Y0 = (tile >> 4) * 16;
    int n = blockIdx.y;
    int t = threadIdx.x;
    int lane = t & 63, wave = t >> 6;
    int q = lane >> 4, mcol = lane & 15;
    int CiB = CI - CiA;

    // weights: kl = tap*CI + ci  ->  Wt[co][ci][tap]
    for (int e = t; e < 16 * KPAD; e += 256) {
        int co = e / KPAD, k = e % KPAD;
        int tap = k / CI, ci = k % CI;
        sWt[co][k] = (k < K) ? f2bf(Wt[(size_t)co * K + ci * 9 + tap]) : f2bf(0.f);
    }
    // input: channel-minor [py][px][ci]; vectorized global reads
    for (int e = t; e < CI * 72; e += 256) {       // 18 rows x 4 slots
        int ci = e / 72, rem = e % 72;
        int py = rem / 4, slot = rem % 4;
        const bf* src = (ci < CiA)
            ? inA + ((size_t)(n * CiA + ci) << 16)
            : inB + ((size_t)(n * CiB + ci - CiA) << 16);
        int iy = Y0 - 1 + py;
        bool rowok = ((unsigned)iy < 256u);
        if (slot == 0) {
            int ix = X0 - 1;
            sIn2[py][0][ci] = (rowok && ix >= 0) ? src[(iy << 8) + ix] : f2bf(0.f);
        } else if (slot == 3) {
            int ix = X0 + 16;
            sIn2[py][17][ci] = (rowok && ix < 256) ? src[(iy << 8) + ix] : f2bf(0.f);
        } else {
            int px0 = (slot == 1) ? 1 : 9;
            if (rowok) {
                uint4 v = *(const uint4*)&src[(iy << 8) + X0 - 1 + px0];
                const bf* pv = (const bf*)&v;
                #pragma unroll
                for (int j = 0; j < 8; ++j) sIn2[py][px0 + j][ci] = pv[j];
            } else {
                #pragma unroll
                for (int j = 0; j < 8; ++j) sIn2[py][px0 + j][ci] = f2bf(0.f);
            }
        }
    }
    __syncthreads();

    f4v acc[4];
    #pragma unroll
    for (int g = 0; g < 4; ++g) acc[g] = (f4v){0.f, 0.f, 0.f, 0.f};

    int prow0 = wave * 4;
    #pragma unroll
    for (int s = 0; s < NM; ++s) {
        bf8v wf = *(const bf8v*)&sWt[mcol][s * 32 + q * 8];
        int tap, ciofs;
        if (CI == 32) { tap = s;               ciofs = q * 8; }
        else          { tap = 2 * s + (q >> 1); if (tap > 8) tap = 8;
                        ciofs = (q & 1) * 8; }
        int ay = tap / 3, ax = tap - ay * 3;
        #pragma unroll
        for (int g = 0; g < 4; ++g) {
            bf8v af = *(const bf8v*)&sIn2[prow0 + g + ay][mcol + ax][ciofs];
            acc[g] = __builtin_amdgcn_mfma_f32_16x16x32_bf16(af, wf, acc[g], 0, 0, 0);
        }
    }

    float bs = Bias[mcol];
    bf* dst = out + ((size_t)(n * 16 + mcol) << 16);
    #pragma unroll
    for (int g = 0; g < 4; ++g) {
        int oy = Y0 + prow0 + g, ox = X0 + q * 4;
        uint2 pk;
        pk.x = packbf(fmaxf(acc[g][0] + bs, 0.f), fmaxf(acc[g][1] + bs, 0.f));
        pk.y = packbf(fmaxf(acc[g][2] + bs, 0.f), fmaxf(acc[g][3] + bs, 0.f));
        *(uint2*)(dst + (oy << 8) + ox) = pk;
    }
}

// ===========================================================================
// MFMA phase-decomposed transposed conv (k=3,s=2,p=1,op=1): u1,u2,u3.
// r23 cic-minor contiguous form + VECTORIZED global staging (r24):
// rows split {px0-7 vec | px8-15 vec | px16/17 scalar}; vec segments are
// always in-bounds in x (J0 mult-16, no left halo) and 16B-aligned.
// ===========================================================================
#define CVT_CHAIN(PH, KOFF, AY, AX)                                           \
    {                                                                          \
        bf8v wf = *(const bf8v*)&sWt[mcol][(KOFF) + q * 8];                    \
        _Pragma("unroll")                                                      \
        for (int g = 0; g < 4; ++g) {                                          \
            bf8v af = *(const bf8v*)&sIn2[prow0 + g + (AY)][mcol + (AX)][q * 8];\
            acc[PH][g] = __builtin_amdgcn_mfma_f32_16x16x32_bf16(af, wf,       \
                                                      acc[PH][g], 0, 0, 0);    \
        }                                                                      \
    }

template <int CITOT, int CIA>
__global__ __launch_bounds__(256)
void convt_mfma(const bf* __restrict__ inA, const bf* __restrict__ inB,
                const float* __restrict__ Wt, const float* __restrict__ Bias,
                bf* __restrict__ out,
                int N, int Hi, int Wi, int Cotot, int Ho, int Wo, int tilesX)
{
    constexpr int NCH = CITOT / 32;
    __shared__ __align__(16) bf sIn2[17][18][40];  // [py][px][ci pad40] 24.5KB
    __shared__ __align__(16) bf sWt[16][328];      // phase bases 0,40,112,184

    int tile = blockIdx.x;
    int J0 = (tile % tilesX) * 16, I0 = (tile / tilesX) * 16;
    int n = blockIdx.y;
    int cog0 = blockIdx.z * 16;
    int t = threadIdx.x;
    int lane = t & 63, wave = t >> 6;
    int q = lane >> 4, mcol = lane & 15;
    int prow0 = wave * 4;

    f4v acc[4][4];
    #pragma unroll
    for (int p = 0; p < 4; ++p)
        #pragma unroll
        for (int g = 0; g < 4; ++g) acc[p][g] = (f4v){0.f, 0.f, 0.f, 0.f};

    for (int cb = 0; cb < NCH; ++cb) {
        if (cb) __syncthreads();                  // drain reads before restage
        // input chunk staging: 32 ch x 17 rows x 3 segments, vectorized
        for (int e = t; e < 32 * 51; e += 256) {  // 51 = 17 rows * 3 segs
            int ci = e / 51, rem = e % 51;
            int py = rem / 3, seg = rem % 3;
            int gci = cb * 32 + ci;
            const bf* src = (gci < CIA)
                ? inA + (size_t)(n * CIA + gci) * Hi * Wi
                : inB + (size_t)(n * (CITOT - CIA) + gci - CIA) * Hi * Wi;
            int iy = I0 + py;
            if (seg < 2) {
                int px0 = seg * 8;                // px 0-7 or 8-15, in-bounds
                if (iy < Hi) {
                    uint4 v = *(const uint4*)&src[(size_t)iy * Wi + J0 + px0];
                    const bf* pv = (const bf*)&v;
                    #pragma unroll
                    for (int j = 0; j < 8; ++j) sIn2[py][px0 + j][ci] = pv[j];
                } else {
                    #pragma unroll
                    for (int j = 0; j < 8; ++j) sIn2[py][px0 + j][ci] = f2bf(0.f);
                }
            } else {
                int ix = J0 + 16;
                sIn2[py][16][ci] = (iy < Hi && ix < Wi)
                                   ? src[(size_t)iy * Wi + ix] : f2bf(0.f);
                sIn2[py][17][ci] = f2bf(0.f);
            }
        }
        for (int e = t; e < 16 * 288; e += 256) {
            int co = e / 288, rem = e % 288;
            int cic = rem / 9, t9 = rem % 9;
            int ky = t9 / 3, kx = t9 % 3;
            int ry = (ky == 1) ? 0 : 1;
            int rx = (kx == 1) ? 0 : 1;
            int ty = (ky == 1) ? 0 : (ky >> 1);
            int txi = (kx == 1) ? 0 : (kx >> 1);
            int ntx = 1 + rx;
            int ph = ry * 2 + rx;
            const int base4[4] = {0, 40, 112, 184};
            int kl = (ty * ntx + txi) * 32 + cic;      // cic-minor k order
            sWt[co][base4[ph] + kl] =
                f2bf(Wt[(size_t)(cog0 + co) * CITOT * 9
                        + (size_t)(cb * 32 + cic) * 9 + t9]);
        }
        __syncthreads();

        //        PH  KOFF AY AX      (chain = one tap over 32 channels)
        CVT_CHAIN(0,   0, 0, 0)    // phase (ry0,rx0): tap (1,1)
        CVT_CHAIN(1,  40, 0, 0)    // phase (ry0,rx1): tap kx=0
        CVT_CHAIN(1,  72, 0, 1)    //                  tap kx=2
        CVT_CHAIN(2, 112, 0, 0)    // phase (ry1,rx0): tap ky=0
        CVT_CHAIN(2, 144, 1, 0)    //                  tap ky=2
        CVT_CHAIN(3, 184, 0, 0)    // phase (ry1,rx1): tap (0,0)
        CVT_CHAIN(3, 216, 0, 1)    //                  tap (0,2)
        CVT_CHAIN(3, 248, 1, 0)    //                  tap (2,0)
        CVT_CHAIN(3, 280, 1, 1)    //                  tap (2,2)
    }

    float bs = Bias[cog0 + mcol];
    bf* dst = out + (size_t)(n * Cotot + cog0 + mcol) * Ho * Wo;
    #pragma unroll
    for (int ph = 0; ph < 4; ++ph) {
        const int ry = ph >> 1, rx = ph & 1;
        #pragma unroll
        for (int g = 0; g < 4; ++g) {
            int oy = 2 * (I0 + prow0 + g) + ry;
            #pragma unroll
            for (int jj = 0; jj < 4; ++jj) {
                int ox = 2 * (J0 + q * 4 + jj) + rx;
                dst[(size_t)oy * Wo + ox] = f2bf(fmaxf(acc[ph][g][jj] + bs, 0.f));
            }
        }
    }
}

// ===========================================================================
// MFMA Gram partials (verified round 20).
// ===========================================================================
__global__ __launch_bounds__(256)
void sim_partial(const bf* __restrict__ f, float* __restrict__ part, int KTOT)
{
    __shared__ __align__(16) bf tile[32][264];
    int c = blockIdx.x;
    int t = threadIdx.x;
    int k0 = c << 8;

    for (int e = t; e < 1024; e += 256) {
        int row = e >> 5, col8 = (e & 31) * 8;
        uint4 v = *(const uint4*)&f[(size_t)row * KTOT + k0 + col8];
        *(uint4*)&tile[row][col8] = v;
    }
    __syncthreads();

    int lane = t & 63, wave = t >> 6;
    int q = lane >> 4, mcol = lane & 15;
    int qr = wave >> 1, qc = wave & 1;

    f4v acc = (f4v){0.f, 0.f, 0.f, 0.f};
    #pragma unroll
    for (int ks = 0; ks < 8; ++ks) {
        bf8v a = *(const bf8v*)&tile[qr * 16 + mcol][ks * 32 + q * 8];
        bf8v b = *(const bf8v*)&tile[qc * 16 + mcol][ks * 32 + q * 8];
        acc = __builtin_amdgcn_mfma_f32_16x16x32_bf16(a, b, acc, 0, 0, 0);
    }

    float* dst = part + (size_t)c * 1024;
    #pragma unroll
    for (int jj = 0; jj < 4; ++jj) {
        int i = qr * 16 + q * 4 + jj;
        int j = qc * 16 + mcol;
        dst[i * 32 + j] = acc[jj];
    }
}

__global__ __launch_bounds__(256)
void sim_reduce(const float* __restrict__ part, float* __restrict__ sim, int nchunks)
{
    __shared__ float red[256];
    int pair = blockIdx.x;
    int t = threadIdx.x;
    float s = 0.f;
    for (int k = t; k < nchunks; k += 256)
        s += part[(size_t)k * 1024 + pair];
    red[t] = s;
    __syncthreads();
    #pragma unroll
    for (int off = 128; off > 0; off >>= 1) {
        if (t < off) red[t] += red[t + off];
        __syncthreads();
    }
    if (t == 0) sim[pair] = red[0];
}

// ===========================================================================
// Cosine sim + group mask + top-3 (strict >, lowest index wins ties).
// ===========================================================================
__global__ void topk_kernel(const float* __restrict__ sim, const int* __restrict__ prange,
                            int* __restrict__ idx, int N)
{
    int i = threadIdx.x;
    if (i >= N) return;
    float nm_i = fmaxf(sqrtf(sim[i * N + i]), 1e-8f);
    int p0 = prange[0], p1 = prange[1];
    int gi = (i >= p0) + (i >= p1);
    float vals[32];
    for (int j = 0; j < N; ++j) {
        int gj = (j >= p0) + (j >= p1);
        if (j == i || gj != gi) { vals[j] = -1e30f; continue; }
        float nm_j = fmaxf(sqrtf(sim[j * N + j]), 1e-8f);
        vals[j] = sim[i * N + j] / (nm_i * nm_j);
    }
    for (int k = 0; k < 3; ++k) {
        float best = -2e30f; int bj = 0;
        for (int j = 0; j < N; ++j)
            if (vals[j] > best) { best = vals[j]; bj = j; }
        idx[i * 3 + k] = bj;
        vals[bj] = -1e30f;
    }
}

// ===========================================================================
// Gather-mean: agg[n] = (ga[i0] + ga[i1] + ga[i2]) / 3.
// ===========================================================================
__global__ __launch_bounds__(256)
void gather_mean(const bf* __restrict__ ga, const int* __restrict__ idx,
                 bf* __restrict__ agg)
{
    int n = blockIdx.y;
    int v = blockIdx.x * 256 + threadIdx.x;
    int i0 = idx[n * 3 + 0], i1 = idx[n * 3 + 1], i2 = idx[n * 3 + 2];
    const size_t stride = (size_t)16 << 16;
    const uint4* p0 = (const uint4*)(ga + stride * i0) + v;
    const uint4* p1 = (const uint4*)(ga + stride * i1) + v;
    const uint4* p2 = (const uint4*)(ga + stride * i2) + v;
    uint4 a = *p0, b = *p1, c = *p2;
    uint4 r;
    unsigned* ap = (unsigned*)&a; unsigned* bp = (unsigned*)&b;
    unsigned* cp = (unsigned*)&c; unsigned* rp = (unsigned*)&r;
    #pragma unroll
    for (int w = 0; w < 4; ++w) {
        float fa0 = __bfloat162float((__hip_bfloat16_raw){(unsigned short)(ap[w] & 0xffff)});
        float fb0 = __bfloat162float((__hip_bfloat16_raw){(unsigned short)(bp[w] & 0xffff)});
        float fc0 = __bfloat162float((__hip_bfloat16_raw){(unsigned short)(cp[w] & 0xffff)});
        float fa1 = __bfloat162float((__hip_bfloat16_raw){(unsigned short)(ap[w] >> 16)});
        float fb1 = __bfloat162float((__hip_bfloat16_raw){(unsigned short)(bp[w] >> 16)});
        float fc1 = __bfloat162float((__hip_bfloat16_raw){(unsigned short)(cp[w] >> 16)});
        rp[w] = packbf((fa0 + fb0 + fc0) * (1.f / 3.f),
                       (fa1 + fb1 + fc1) * (1.f / 3.f));
    }
    *((uint4*)(agg + stride * n) + v) = r;
}

// ===========================================================================
// Light head: gnn (bf16) + d1 recompute + dense 32->2 + softmax.
// ===========================================================================
__global__ __launch_bounds__(256)
void head_tiled(const float* __restrict__ cts, const bf* __restrict__ gnn,
                const float* __restrict__ w_d1, const float* __restrict__ b_d1,
                const float* __restrict__ w_de, const float* __restrict__ b_de,
                float* __restrict__ out, int N)
{
    __shared__ float sCts[18][19];
    __shared__ float sWd1[144];
    __shared__ float sB1[16];
    __shared__ float sDe[64];

    int tile = blockIdx.x;
    int X0 = (tile & 15) * 16, Y0 = (tile >> 4) * 16;
    int n = blockIdx.y;
    int t = threadIdx.x, tx = t & 15, ty = t >> 4;

    for (int e = t; e < 18 * 18; e += 256) {
        int py = e / 18, px = e % 18;
        int iy = Y0 - 1 + py, ix = X0 - 1 + px;
        sCts[py][px] = ((unsigned)iy < 256u && (unsigned)ix < 256u)
                       ? cts[((size_t)n << 16) + (iy << 8) + ix] : 0.f;
    }
    if (t < 144) sWd1[t] = w_d1[t];
    else if (t < 160) sB1[t - 144] = b_d1[t - 144];
    else if (t >= 192 && t < 256) sDe[t - 192] = w_de[t - 192];
    __syncthreads();

    int pix = ((Y0 + ty) << 8) + X0 + tx;
    float l0 = b_de[0], l1 = b_de[1];

    #pragma unroll
    for (int c = 0; c < 16; ++c) {
        float v = bf2f(gnn[((size_t)(n * 16 + c) << 16) + pix]);
        l0 = fmaf(v, sDe[c * 2 + 0], l0);
        l1 = fmaf(v, sDe[c * 2 + 1], l1);
    }

    float ct[3][3];
    #pragma unroll
    for (int a = 0; a < 3; ++a)
        #pragma unroll
        for (int b = 0; b < 3; ++b)
            ct[a][b] = sCts[ty + a][tx + b];
    #pragma unroll
    for (int c = 0; c < 16; ++c) {
        float a1 = sB1[c];
        #pragma unroll
        for (int t9 = 0; t9 < 9; ++t9)
            a1 = fmaf(ct[t9 / 3][t9 % 3], sWd1[c * 9 + t9], a1);
        float v = fmaxf(a1, 0.f);
        l0 = fmaf(v, sDe[(16 + c) * 2 + 0], l0);
        l1 = fmaf(v, sDe[(16 + c) * 2 + 1], l1);
    }

    float m = fmaxf(l0, l1);
    float e0 = expf(l0 - m), e1 = expf(l1 - m);
    float inv = 1.f / (e0 + e1);
    size_t base = ((size_t)n * 2) << 16;
    out[base + pix] = e0 * inv;
    out[base + 65536 + pix] = e1 * inv;
}

// ===========================================================================

extern "C" void kernel_launch(void* const* d_in, const int* in_sizes, int n_in,
                              void* d_out, int out_size, void* d_ws, size_t ws_size,
                              hipStream_t stream)
{
    const float* cts  = (const float*)d_in[0];
    const int*   prng = (const int*)d_in[1];
    const float* w_d1 = (const float*)d_in[2];  const float* b_d1 = (const float*)d_in[3];
    const float* w_d2 = (const float*)d_in[4];  const float* b_d2 = (const float*)d_in[5];
    const float* w_d3 = (const float*)d_in[6];  const float* b_d3 = (const float*)d_in[7];
    const float* w_d4 = (const float*)d_in[8];  const float* b_d4 = (const float*)d_in[9];
    const float* w_u1 = (const float*)d_in[10]; const float* b_u1 = (const float*)d_in[11];
    const float* w_u2 = (const float*)d_in[12]; const float* b_u2 = (const float*)d_in[13];
    const float* w_u3 = (const float*)d_in[14]; const float* b_u3 = (const float*)d_in[15];
    const float* w_ga = (const float*)d_in[16]; const float* b_ga = (const float*)d_in[17];
    const float* w_gu = (const float*)d_in[18]; const float* b_gu = (const float*)d_in[19];
    const float* w_de = (const float*)d_in[20]; const float* b_de = (const float*)d_in[21];

    const int H = 256, Wd = 256;
    const int N = in_sizes[0] / (H * Wd);   // 32

    // ---- workspace layout (192 MiB total), lifetime reuse ----
    char* wsb = (char*)d_ws;
    bf* u3 = (bf*)(wsb);
    bf* R1 = (bf*)(wsb + 67108864);

    bf* d1 = R1;
    bf* d2 = (bf*)(wsb + 134217728);
    bf* d3 = (bf*)(wsb + 134217728 + 33554432);
    bf* d4 = (bf*)(wsb + 134217728 + 50331648);
    bf* u1 = R1;
    bf* u2 = (bf*)(wsb + 67108864 + 16777216);
    bf* ga = R1;
    bf* gnn = R1;
    bf* agg = (bf*)(wsb + 134217728);
    float* simp = (float*)(wsb + 134217728);
    float* sim  = (float*)(wsb + 134217728 + 16777216);
    int*   idx  = (int*)d_out + (out_size - 96);

    const int KTOT = 16 * H * Wd;
    const int NCH  = KTOT / 256;            // 4096 chunks

    // encoder
    conv32<float><<<dim3(64, N), 256, 0, stream>>>(cts, cts, 1, 1, w_d1, b_d1, d1, N);
    conv_tiled<bf, 2><<<dim3(64, N, 2), 256, 0, stream>>>(
        d1, (const bf*)nullptr, 16, 16, w_d2, b_d2, d2, N, 256, 256, 32, 128, 128, 8);
    conv_tiled<bf, 2><<<dim3(16, N, 4), 256, 0, stream>>>(
        d2, (const bf*)nullptr, 32, 32, w_d3, b_d3, d3, N, 128, 128, 64, 64, 64, 4);
    conv_tiled<bf, 2><<<dim3(4, N, 8), 256, 0, stream>>>(
        d3, (const bf*)nullptr, 64, 64, w_d4, b_d4, d4, N, 64, 64, 128, 32, 32, 2);
    // decoder (all transposed convs via MFMA)
    convt_mfma<128, 128><<<dim3(4, N, 4), 256, 0, stream>>>(
        d4, d4, w_u1, b_u1, u1, N, 32, 32, 64, 64, 64, 2);
    convt_mfma<128, 64><<<dim3(16, N, 2), 256, 0, stream>>>(
        u1, d3, w_u2, b_u2, u2, N, 64, 64, 32, 128, 128, 4);
    convt_mfma<64, 32><<<dim3(64, N, 1), 256, 0, stream>>>(
        u2, d2, w_u3, b_u3, u3, N, 128, 128, 16, 256, 256, 8);
    // cosine similarity + top-3 (Gram via MFMA)
    sim_partial<<<NCH, 256, 0, stream>>>(u3, simp, KTOT);
    sim_reduce<<<dim3(N * N), 256, 0, stream>>>(simp, sim, NCH);
    topk_kernel<<<1, 64, 0, stream>>>(sim, prng, idx, N);
    // per-slice gnn-neighbor conv (MFMA, contiguous A-reads), then gather-mean
    conv_mfma<16, 20, 160><<<dim3(256, N), 256, 0, stream>>>(
        u3, u3, 16, w_ga, b_ga, ga, N);
    gather_mean<<<dim3(512, N), 256, 0, stream>>>(ga, idx, agg);
    // gnn conv (MFMA, 32ch from u3|agg, contiguous A-reads) then light head
    conv_mfma<32, 40, 288><<<dim3(256, N), 256, 0, stream>>>(
        u3, agg, 16, w_gu, b_gu, gnn, N);
    head_tiled<<<dim3(256, N), 256, 0, stream>>>(
        cts, gnn, w_d1, b_d1, w_de, b_de, (float*)d_out, N);
}

// Round 26
// 1116.935 us; speedup vs baseline: 1.6440x; 1.1078x over previous
//
#include <hip/hip_runtime.h>
#include <hip/hip_bf16.h>
#include <math.h>

typedef __hip_bfloat16 bf;
typedef __attribute__((ext_vector_type(8))) short bf8v;   // 8 bf16 = 4 VGPR
typedef __attribute__((ext_vector_type(4))) float f4v;

__device__ __forceinline__ float bf2f(bf v) { return __bfloat162float(v); }
__device__ __forceinline__ bf f2bf(float v) { return __float2bfloat16(v); }
__device__ __forceinline__ unsigned packbf(float a, float b) {
    __hip_bfloat16_raw ra = (__hip_bfloat16_raw)__float2bfloat16(a);
    __hip_bfloat16_raw rb = (__hip_bfloat16_raw)__float2bfloat16(b);
    return (unsigned)ra.x | ((unsigned)rb.x << 16);
}

// ===========================================================================
// Tiled direct 3x3 conv, STRIDE 2, bf16 (d2,d3,d4). 16x16 out tile.
// r25: VECTORIZED global staging — rows split {px0 scalar | 4x 8-px vec};
// vec segments start at ix = 2*tx0 + 8s: always in-bounds, 16B-aligned.
// ===========================================================================
__global__ __launch_bounds__(256)
void conv_tiled(const bf* __restrict__ inA, const bf* __restrict__ inB,
                int CiA, int Ci,
                const float* __restrict__ Wt, const float* __restrict__ Bias,
                bf* __restrict__ out,
                int N, int Hi, int Wi, int Co, int Ho, int Wo, int tilesX)
{
    constexpr int IH = 33;
    constexpr int IWP = 33;
    constexpr int CHUNK = 8;

    __shared__ bf sIn[CHUNK * IH * IWP];
    __shared__ __align__(16) float sW[CHUNK * 144];

    int tile = blockIdx.x;
    int tx0 = (tile % tilesX) * 16, ty0 = (tile / tilesX) * 16;
    int n = blockIdx.y;
    int cog0 = blockIdx.z * 16;
    int t = threadIdx.x;
    int tx = t & 15, ty = t >> 4;
    int CiB = Ci - CiA;

    float acc[16];
    #pragma unroll
    for (int c = 0; c < 16; ++c) acc[c] = Bias[cog0 + c];

    for (int cb = 0; cb < Ci; cb += CHUNK) {
        int cn = (Ci - cb < CHUNK) ? (Ci - cb) : CHUNK;
        // staging: 33 rows x {1 scalar + 4 vec8} segments per channel
        for (int e = t; e < cn * 165; e += 256) {
            int ci = e / 165, rem = e % 165;
            int py = rem / 5, seg = rem % 5;
            int gci = cb + ci;
            const bf* src = (gci < CiA)
                ? inA + (size_t)(n * CiA + gci) * Hi * Wi
                : inB + (size_t)(n * CiB + gci - CiA) * Hi * Wi;
            int iy = ty0 * 2 - 1 + py;
            bool rowok = (iy >= 0);                // iy < Hi always holds
            bf* drow = &sIn[ci * IH * IWP + py * IWP];
            if (seg == 0) {
                int ix = tx0 * 2 - 1;
                drow[0] = (rowok && ix >= 0) ? src[(size_t)iy * Wi + ix]
                                             : f2bf(0.f);
            } else {
                int px0 = 1 + 8 * (seg - 1);       // 1, 9, 17, 25
                int ix0 = tx0 * 2 + 8 * (seg - 1); // in-bounds, 16B-aligned
                if (rowok) {
                    uint4 v = *(const uint4*)&src[(size_t)iy * Wi + ix0];
                    const bf* pv = (const bf*)&v;
                    #pragma unroll
                    for (int j = 0; j < 8; ++j) drow[px0 + j] = pv[j];
                } else {
                    #pragma unroll
                    for (int j = 0; j < 8; ++j) drow[px0 + j] = f2bf(0.f);
                }
            }
        }
        for (int e = t; e < cn * 144; e += 256) {
            int ci = e / 144, rem = e % 144;
            int t9 = rem / 16, co = rem % 16;
            sW[ci * 144 + t9 * 16 + co] =
                Wt[(size_t)(cog0 + co) * Ci * 9 + (cb + ci) * 9 + t9];
        }
        __syncthreads();
        for (int ci = 0; ci < cn; ++ci) {
            #pragma unroll
            for (int t9 = 0; t9 < 9; ++t9) {
                int ky = t9 / 3, kx = t9 % 3;
                float v = bf2f(sIn[ci * IH * IWP + (ty * 2 + ky) * IWP
                                   + (tx * 2 + kx)]);
                const float* wp = &sW[ci * 144 + t9 * 16];
                #pragma unroll
                for (int co = 0; co < 16; ++co)
                    acc[co] = fmaf(v, wp[co], acc[co]);
            }
        }
        __syncthreads();
    }

    int oy = ty0 + ty, ox = tx0 + tx;
    #pragma unroll
    for (int co = 0; co < 16; ++co)
        out[(size_t)(n * Co + cog0 + co) * Ho * Wo + (size_t)oy * Wo + ox]
            = f2bf(fmaxf(acc[co], 0.f));
}

// ===========================================================================
// Stride-1 conv (d1 only, Ci=1). 32x32 tile, 2x2 px/thread.
// ===========================================================================
template <typename TIN>
__global__ __launch_bounds__(256)
void conv32(const TIN* __restrict__ inA, const TIN* __restrict__ inB,
            int CiA, int Ci,
            const float* __restrict__ Wt, const float* __restrict__ Bias,
            bf* __restrict__ out, int N)
{
    constexpr int CHUNK = 4;
    __shared__ float sIn[CHUNK][34][35];
    __shared__ __align__(16) float sW[CHUNK][9][16];

    int tile = blockIdx.x;
    int X0 = (tile & 7) * 32, Y0 = (tile >> 3) * 32;
    int n = blockIdx.y;
    int t = threadIdx.x, tx = t & 15, ty = t >> 4;
    int CiB = Ci - CiA;

    float acc[4][16];
    #pragma unroll
    for (int p = 0; p < 4; ++p)
        #pragma unroll
        for (int c = 0; c < 16; ++c) acc[p][c] = 0.f;

    for (int cb = 0; cb < Ci; cb += CHUNK) {
        int cn = (Ci - cb < CHUNK) ? Ci - cb : CHUNK;
        for (int e = t; e < cn * 1156; e += 256) {
            int ci = e / 1156, rem = e % 1156;
            int py = rem / 34, px = rem % 34;
            int iy = Y0 - 1 + py, ix = X0 - 1 + px;
            int gci = cb + ci;
            const TIN* src = (gci < CiA)
                ? inA + ((size_t)(n * CiA + gci) << 16)
                : inB + ((size_t)(n * CiB + gci - CiA) << 16);
            sIn[ci][py][px] = ((unsigned)iy < 256u && (unsigned)ix < 256u)
                              ? (float)src[(iy << 8) + ix] : 0.f;
        }
        for (int e = t; e < cn * 144; e += 256) {
            int ci = e / 144, rem = e % 144;
            int t9 = rem / 16, co = rem % 16;
            sW[ci][t9][co] = Wt[(size_t)co * Ci * 9 + (cb + ci) * 9 + t9];
        }
        __syncthreads();
        for (int ci = 0; ci < cn; ++ci) {
            float rin[4][4];
            #pragma unroll
            for (int a = 0; a < 4; ++a)
                #pragma unroll
                for (int b = 0; b < 4; ++b)
                    rin[a][b] = sIn[ci][2 * ty + a][2 * tx + b];
            #pragma unroll
            for (int t9 = 0; t9 < 9; ++t9) {
                const int ky = t9 / 3, kx = t9 % 3;
                float w[16];
                #pragma unroll
                for (int q = 0; q < 4; ++q)
                    *(float4*)&w[q * 4] = *(const float4*)&sW[ci][t9][q * 4];
                #pragma unroll
                for (int ry = 0; ry < 2; ++ry)
                    #pragma unroll
                    for (int rx = 0; rx < 2; ++rx) {
                        float v = rin[ry + ky][rx + kx];
                        #pragma unroll
                        for (int co = 0; co < 16; ++co)
                            acc[ry * 2 + rx][co] = fmaf(v, w[co], acc[ry * 2 + rx][co]);
                    }
            }
        }
        __syncthreads();
    }

    #pragma unroll
    for (int co = 0; co < 16; ++co) {
        float bs = Bias[co];
        bf* dst = out + ((size_t)(n * 16 + co) << 16);
        #pragma unroll
        for (int ry = 0; ry < 2; ++ry) {
            unsigned pk = packbf(fmaxf(acc[ry * 2 + 0][co] + bs, 0.f),
                                 fmaxf(acc[ry * 2 + 1][co] + bs, 0.f));
            *(unsigned*)(dst + ((Y0 + 2 * ty + ry) << 8) + X0 + 2 * tx) = pk;
        }
    }
}

// ===========================================================================
// MFMA implicit-GEMM stride-1 conv, contiguous A-reads (r23) + vectorized
// global staging (r24).
// ===========================================================================
template <int CI, int CIP, int KPAD>
__global__ __launch_bounds__(256)
void conv_mfma(const bf* __restrict__ inA, const bf* __restrict__ inB,
               int CiA,
               const float* __restrict__ Wt, const float* __restrict__ Bias,
               bf* __restrict__ out, int N)
{
    constexpr int K = CI * 9;
    constexpr int NM = KPAD / 32;
    __shared__ __align__(16) bf sIn2[18][19][CIP];
    __shared__ __align__(16) bf sWt[16][KPAD];

    int tile = blockIdx.x;
    int X0 = (tile & 15) * 16, Y0 = (tile >> 4) * 16;
    int n = blockIdx.y;
    int t = threadIdx.x;
    int lane = t & 63, wave = t >> 6;
    int q = lane >> 4, mcol = lane & 15;
    int CiB = CI - CiA;

    for (int e = t; e < 16 * KPAD; e += 256) {
        int co = e / KPAD, k = e % KPAD;
        int tap = k / CI, ci = k % CI;
        sWt[co][k] = (k < K) ? f2bf(Wt[(size_t)co * K + ci * 9 + tap]) : f2bf(0.f);
    }
    for (int e = t; e < CI * 72; e += 256) {       // 18 rows x 4 slots
        int ci = e / 72, rem = e % 72;
        int py = rem / 4, slot = rem % 4;
        const bf* src = (ci < CiA)
            ? inA + ((size_t)(n * CiA + ci) << 16)
            : inB + ((size_t)(n * CiB + ci - CiA) << 16);
        int iy = Y0 - 1 + py;
        bool rowok = ((unsigned)iy < 256u);
        if (slot == 0) {
            int ix = X0 - 1;
            sIn2[py][0][ci] = (rowok && ix >= 0) ? src[(iy << 8) + ix] : f2bf(0.f);
        } else if (slot == 3) {
            int ix = X0 + 16;
            sIn2[py][17][ci] = (rowok && ix < 256) ? src[(iy << 8) + ix] : f2bf(0.f);
        } else {
            int px0 = (slot == 1) ? 1 : 9;
            if (rowok) {
                uint4 v = *(const uint4*)&src[(iy << 8) + X0 - 1 + px0];
                const bf* pv = (const bf*)&v;
                #pragma unroll
                for (int j = 0; j < 8; ++j) sIn2[py][px0 + j][ci] = pv[j];
            } else {
                #pragma unroll
                for (int j = 0; j < 8; ++j) sIn2[py][px0 + j][ci] = f2bf(0.f);
            }
        }
    }
    __syncthreads();

    f4v acc[4];
    #pragma unroll
    for (int g = 0; g < 4; ++g) acc[g] = (f4v){0.f, 0.f, 0.f, 0.f};

    int prow0 = wave * 4;
    #pragma unroll
    for (int s = 0; s < NM; ++s) {
        bf8v wf = *(const bf8v*)&sWt[mcol][s * 32 + q * 8];
        int tap, ciofs;
        if (CI == 32) { tap = s;               ciofs = q * 8; }
        else          { tap = 2 * s + (q >> 1); if (tap > 8) tap = 8;
                        ciofs = (q & 1) * 8; }
        int ay = tap / 3, ax = tap - ay * 3;
        #pragma unroll
        for (int g = 0; g < 4; ++g) {
            bf8v af = *(const bf8v*)&sIn2[prow0 + g + ay][mcol + ax][ciofs];
            acc[g] = __builtin_amdgcn_mfma_f32_16x16x32_bf16(af, wf, acc[g], 0, 0, 0);
        }
    }

    float bs = Bias[mcol];
    bf* dst = out + ((size_t)(n * 16 + mcol) << 16);
    #pragma unroll
    for (int g = 0; g < 4; ++g) {
        int oy = Y0 + prow0 + g, ox = X0 + q * 4;
        uint2 pk;
        pk.x = packbf(fmaxf(acc[g][0] + bs, 0.f), fmaxf(acc[g][1] + bs, 0.f));
        pk.y = packbf(fmaxf(acc[g][2] + bs, 0.f), fmaxf(acc[g][3] + bs, 0.f));
        *(uint2*)(dst + (oy << 8) + ox) = pk;
    }
}

// ===========================================================================
// MFMA phase-decomposed transposed conv (k=3,s=2,p=1,op=1): u1,u2,u3.
// r23 cic-minor contiguous form + r24 vectorized global staging.
// ===========================================================================
#define CVT_CHAIN(PH, KOFF, AY, AX)                                           \
    {                                                                          \
        bf8v wf = *(const bf8v*)&sWt[mcol][(KOFF) + q * 8];                    \
        _Pragma("unroll")                                                      \
        for (int g = 0; g < 4; ++g) {                                          \
            bf8v af = *(const bf8v*)&sIn2[prow0 + g + (AY)][mcol + (AX)][q * 8];\
            acc[PH][g] = __builtin_amdgcn_mfma_f32_16x16x32_bf16(af, wf,       \
                                                      acc[PH][g], 0, 0, 0);    \
        }                                                                      \
    }

template <int CITOT, int CIA>
__global__ __launch_bounds__(256)
void convt_mfma(const bf* __restrict__ inA, const bf* __restrict__ inB,
                const float* __restrict__ Wt, const float* __restrict__ Bias,
                bf* __restrict__ out,
                int N, int Hi, int Wi, int Cotot, int Ho, int Wo, int tilesX)
{
    constexpr int NCH = CITOT / 32;
    __shared__ __align__(16) bf sIn2[17][18][40];  // [py][px][ci pad40] 24.5KB
    __shared__ __align__(16) bf sWt[16][328];      // phase bases 0,40,112,184

    int tile = blockIdx.x;
    int J0 = (tile % tilesX) * 16, I0 = (tile / tilesX) * 16;
    int n = blockIdx.y;
    int cog0 = blockIdx.z * 16;
    int t = threadIdx.x;
    int lane = t & 63, wave = t >> 6;
    int q = lane >> 4, mcol = lane & 15;
    int prow0 = wave * 4;

    f4v acc[4][4];
    #pragma unroll
    for (int p = 0; p < 4; ++p)
        #pragma unroll
        for (int g = 0; g < 4; ++g) acc[p][g] = (f4v){0.f, 0.f, 0.f, 0.f};

    for (int cb = 0; cb < NCH; ++cb) {
        if (cb) __syncthreads();                  // drain reads before restage
        for (int e = t; e < 32 * 51; e += 256) {  // 51 = 17 rows * 3 segs
            int ci = e / 51, rem = e % 51;
            int py = rem / 3, seg = rem % 3;
            int gci = cb * 32 + ci;
            const bf* src = (gci < CIA)
                ? inA + (size_t)(n * CIA + gci) * Hi * Wi
                : inB + (size_t)(n * (CITOT - CIA) + gci - CIA) * Hi * Wi;
            int iy = I0 + py;
            if (seg < 2) {
                int px0 = seg * 8;
                if (iy < Hi) {
                    uint4 v = *(const uint4*)&src[(size_t)iy * Wi + J0 + px0];
                    const bf* pv = (const bf*)&v;
                    #pragma unroll
                    for (int j = 0; j < 8; ++j) sIn2[py][px0 + j][ci] = pv[j];
                } else {
                    #pragma unroll
                    for (int j = 0; j < 8; ++j) sIn2[py][px0 + j][ci] = f2bf(0.f);
                }
            } else {
                int ix = J0 + 16;
                sIn2[py][16][ci] = (iy < Hi && ix < Wi)
                                   ? src[(size_t)iy * Wi + ix] : f2bf(0.f);
                sIn2[py][17][ci] = f2bf(0.f);
            }
        }
        for (int e = t; e < 16 * 288; e += 256) {
            int co = e / 288, rem = e % 288;
            int cic = rem / 9, t9 = rem % 9;
            int ky = t9 / 3, kx = t9 % 3;
            int ry = (ky == 1) ? 0 : 1;
            int rx = (kx == 1) ? 0 : 1;
            int ty = (ky == 1) ? 0 : (ky >> 1);
            int txi = (kx == 1) ? 0 : (kx >> 1);
            int ntx = 1 + rx;
            int ph = ry * 2 + rx;
            const int base4[4] = {0, 40, 112, 184};
            int kl = (ty * ntx + txi) * 32 + cic;      // cic-minor k order
            sWt[co][base4[ph] + kl] =
                f2bf(Wt[(size_t)(cog0 + co) * CITOT * 9
                        + (size_t)(cb * 32 + cic) * 9 + t9]);
        }
        __syncthreads();

        //        PH  KOFF AY AX      (chain = one tap over 32 channels)
        CVT_CHAIN(0,   0, 0, 0)    // phase (ry0,rx0): tap (1,1)
        CVT_CHAIN(1,  40, 0, 0)    // phase (ry0,rx1): tap kx=0
        CVT_CHAIN(1,  72, 0, 1)    //                  tap kx=2
        CVT_CHAIN(2, 112, 0, 0)    // phase (ry1,rx0): tap ky=0
        CVT_CHAIN(2, 144, 1, 0)    //                  tap ky=2
        CVT_CHAIN(3, 184, 0, 0)    // phase (ry1,rx1): tap (0,0)
        CVT_CHAIN(3, 216, 0, 1)    //                  tap (0,2)
        CVT_CHAIN(3, 248, 1, 0)    //                  tap (2,0)
        CVT_CHAIN(3, 280, 1, 1)    //                  tap (2,2)
    }

    float bs = Bias[cog0 + mcol];
    bf* dst = out + (size_t)(n * Cotot + cog0 + mcol) * Ho * Wo;
    #pragma unroll
    for (int ph = 0; ph < 4; ++ph) {
        const int ry = ph >> 1, rx = ph & 1;
        #pragma unroll
        for (int g = 0; g < 4; ++g) {
            int oy = 2 * (I0 + prow0 + g) + ry;
            #pragma unroll
            for (int jj = 0; jj < 4; ++jj) {
                int ox = 2 * (J0 + q * 4 + jj) + rx;
                dst[(size_t)oy * Wo + ox] = f2bf(fmaxf(acc[ph][g][jj] + bs, 0.f));
            }
        }
    }
}

// ===========================================================================
// MFMA Gram partials (verified round 20).
// ===========================================================================
__global__ __launch_bounds__(256)
void sim_partial(const bf* __restrict__ f, float* __restrict__ part, int KTOT)
{
    __shared__ __align__(16) bf tile[32][264];
    int c = blockIdx.x;
    int t = threadIdx.x;
    int k0 = c << 8;

    for (int e = t; e < 1024; e += 256) {
        int row = e >> 5, col8 = (e & 31) * 8;
        uint4 v = *(const uint4*)&f[(size_t)row * KTOT + k0 + col8];
        *(uint4*)&tile[row][col8] = v;
    }
    __syncthreads();

    int lane = t & 63, wave = t >> 6;
    int q = lane >> 4, mcol = lane & 15;
    int qr = wave >> 1, qc = wave & 1;

    f4v acc = (f4v){0.f, 0.f, 0.f, 0.f};
    #pragma unroll
    for (int ks = 0; ks < 8; ++ks) {
        bf8v a = *(const bf8v*)&tile[qr * 16 + mcol][ks * 32 + q * 8];
        bf8v b = *(const bf8v*)&tile[qc * 16 + mcol][ks * 32 + q * 8];
        acc = __builtin_amdgcn_mfma_f32_16x16x32_bf16(a, b, acc, 0, 0, 0);
    }

    float* dst = part + (size_t)c * 1024;
    #pragma unroll
    for (int jj = 0; jj < 4; ++jj) {
        int i = qr * 16 + q * 4 + jj;
        int j = qc * 16 + mcol;
        dst[i * 32 + j] = acc[jj];
    }
}

__global__ __launch_bounds__(256)
void sim_reduce(const float* __restrict__ part, float* __restrict__ sim, int nchunks)
{
    __shared__ float red[256];
    int pair = blockIdx.x;
    int t = threadIdx.x;
    float s = 0.f;
    for (int k = t; k < nchunks; k += 256)
        s += part[(size_t)k * 1024 + pair];
    red[t] = s;
    __syncthreads();
    #pragma unroll
    for (int off = 128; off > 0; off >>= 1) {
        if (t < off) red[t] += red[t + off];
        __syncthreads();
    }
    if (t == 0) sim[pair] = red[0];
}

// ===========================================================================
// Cosine sim + group mask + top-3 (strict >, lowest index wins ties).
// ===========================================================================
__global__ void topk_kernel(const float* __restrict__ sim, const int* __restrict__ prange,
                            int* __restrict__ idx, int N)
{
    int i = threadIdx.x;
    if (i >= N) return;
    float nm_i = fmaxf(sqrtf(sim[i * N + i]), 1e-8f);
    int p0 = prange[0], p1 = prange[1];
    int gi = (i >= p0) + (i >= p1);
    float vals[32];
    for (int j = 0; j < N; ++j) {
        int gj = (j >= p0) + (j >= p1);
        if (j == i || gj != gi) { vals[j] = -1e30f; continue; }
        float nm_j = fmaxf(sqrtf(sim[j * N + j]), 1e-8f);
        vals[j] = sim[i * N + j] / (nm_i * nm_j);
    }
    for (int k = 0; k < 3; ++k) {
        float best = -2e30f; int bj = 0;
        for (int j = 0; j < N; ++j)
            if (vals[j] > best) { best = vals[j]; bj = j; }
        idx[i * 3 + k] = bj;
        vals[bj] = -1e30f;
    }
}

// ===========================================================================
// Gather-mean: agg[n] = (ga[i0] + ga[i1] + ga[i2]) / 3.
// ===========================================================================
__global__ __launch_bounds__(256)
void gather_mean(const bf* __restrict__ ga, const int* __restrict__ idx,
                 bf* __restrict__ agg)
{
    int n = blockIdx.y;
    int v = blockIdx.x * 256 + threadIdx.x;
    int i0 = idx[n * 3 + 0], i1 = idx[n * 3 + 1], i2 = idx[n * 3 + 2];
    const size_t stride = (size_t)16 << 16;
    const uint4* p0 = (const uint4*)(ga + stride * i0) + v;
    const uint4* p1 = (const uint4*)(ga + stride * i1) + v;
    const uint4* p2 = (const uint4*)(ga + stride * i2) + v;
    uint4 a = *p0, b = *p1, c = *p2;
    uint4 r;
    unsigned* ap = (unsigned*)&a; unsigned* bp = (unsigned*)&b;
    unsigned* cp = (unsigned*)&c; unsigned* rp = (unsigned*)&r;
    #pragma unroll
    for (int w = 0; w < 4; ++w) {
        float fa0 = __bfloat162float((__hip_bfloat16_raw){(unsigned short)(ap[w] & 0xffff)});
        float fb0 = __bfloat162float((__hip_bfloat16_raw){(unsigned short)(bp[w] & 0xffff)});
        float fc0 = __bfloat162float((__hip_bfloat16_raw){(unsigned short)(cp[w] & 0xffff)});
        float fa1 = __bfloat162float((__hip_bfloat16_raw){(unsigned short)(ap[w] >> 16)});
        float fb1 = __bfloat162float((__hip_bfloat16_raw){(unsigned short)(bp[w] >> 16)});
        float fc1 = __bfloat162float((__hip_bfloat16_raw){(unsigned short)(cp[w] >> 16)});
        rp[w] = packbf((fa0 + fb0 + fc0) * (1.f / 3.f),
                       (fa1 + fb1 + fc1) * (1.f / 3.f));
    }
    *((uint4*)(agg + stride * n) + v) = r;
}

// ===========================================================================
// Light head: gnn (bf16) + d1 recompute + dense 32->2 + softmax.
// ===========================================================================
__global__ __launch_bounds__(256)
void head_tiled(const float* __restrict__ cts, const bf* __restrict__ gnn,
                const float* __restrict__ w_d1, const float* __restrict__ b_d1,
                const float* __restrict__ w_de, const float* __restrict__ b_de,
                float* __restrict__ out, int N)
{
    __shared__ float sCts[18][19];
    __shared__ float sWd1[144];
    __shared__ float sB1[16];
    __shared__ float sDe[64];

    int tile = blockIdx.x;
    int X0 = (tile & 15) * 16, Y0 = (tile >> 4) * 16;
    int n = blockIdx.y;
    int t = threadIdx.x, tx = t & 15, ty = t >> 4;

    for (int e = t; e < 18 * 18; e += 256) {
        int py = e / 18, px = e % 18;
        int iy = Y0 - 1 + py, ix = X0 - 1 + px;
        sCts[py][px] = ((unsigned)iy < 256u && (unsigned)ix < 256u)
                       ? cts[((size_t)n << 16) + (iy << 8) + ix] : 0.f;
    }
    if (t < 144) sWd1[t] = w_d1[t];
    else if (t < 160) sB1[t - 144] = b_d1[t - 144];
    else if (t >= 192 && t < 256) sDe[t - 192] = w_de[t - 192];
    __syncthreads();

    int pix = ((Y0 + ty) << 8) + X0 + tx;
    float l0 = b_de[0], l1 = b_de[1];

    #pragma unroll
    for (int c = 0; c < 16; ++c) {
        float v = bf2f(gnn[((size_t)(n * 16 + c) << 16) + pix]);
        l0 = fmaf(v, sDe[c * 2 + 0], l0);
        l1 = fmaf(v, sDe[c * 2 + 1], l1);
    }

    float ct[3][3];
    #pragma unroll
    for (int a = 0; a < 3; ++a)
        #pragma unroll
        for (int b = 0; b < 3; ++b)
            ct[a][b] = sCts[ty + a][tx + b];
    #pragma unroll
    for (int c = 0; c < 16; ++c) {
        float a1 = sB1[c];
        #pragma unroll
        for (int t9 = 0; t9 < 9; ++t9)
            a1 = fmaf(ct[t9 / 3][t9 % 3], sWd1[c * 9 + t9], a1);
        float v = fmaxf(a1, 0.f);
        l0 = fmaf(v, sDe[(16 + c) * 2 + 0], l0);
        l1 = fmaf(v, sDe[(16 + c) * 2 + 1], l1);
    }

    float m = fmaxf(l0, l1);
    float e0 = expf(l0 - m), e1 = expf(l1 - m);
    float inv = 1.f / (e0 + e1);
    size_t base = ((size_t)n * 2) << 16;
    out[base + pix] = e0 * inv;
    out[base + 65536 + pix] = e1 * inv;
}

// ===========================================================================

extern "C" void kernel_launch(void* const* d_in, const int* in_sizes, int n_in,
                              void* d_out, int out_size, void* d_ws, size_t ws_size,
                              hipStream_t stream)
{
    const float* cts  = (const float*)d_in[0];
    const int*   prng = (const int*)d_in[1];
    const float* w_d1 = (const float*)d_in[2];  const float* b_d1 = (const float*)d_in[3];
    const float* w_d2 = (const float*)d_in[4];  const float* b_d2 = (const float*)d_in[5];
    const float* w_d3 = (const float*)d_in[6];  const float* b_d3 = (const float*)d_in[7];
    const float* w_d4 = (const float*)d_in[8];  const float* b_d4 = (const float*)d_in[9];
    const float* w_u1 = (const float*)d_in[10]; const float* b_u1 = (const float*)d_in[11];
    const float* w_u2 = (const float*)d_in[12]; const float* b_u2 = (const float*)d_in[13];
    const float* w_u3 = (const float*)d_in[14]; const float* b_u3 = (const float*)d_in[15];
    const float* w_ga = (const float*)d_in[16]; const float* b_ga = (const float*)d_in[17];
    const float* w_gu = (const float*)d_in[18]; const float* b_gu = (const float*)d_in[19];
    const float* w_de = (const float*)d_in[20]; const float* b_de = (const float*)d_in[21];

    const int H = 256, Wd = 256;
    const int N = in_sizes[0] / (H * Wd);   // 32

    // ---- workspace layout (192 MiB total), lifetime reuse ----
    char* wsb = (char*)d_ws;
    bf* u3 = (bf*)(wsb);
    bf* R1 = (bf*)(wsb + 67108864);

    bf* d1 = R1;
    bf* d2 = (bf*)(wsb + 134217728);
    bf* d3 = (bf*)(wsb + 134217728 + 33554432);
    bf* d4 = (bf*)(wsb + 134217728 + 50331648);
    bf* u1 = R1;
    bf* u2 = (bf*)(wsb + 67108864 + 16777216);
    bf* ga = R1;
    bf* gnn = R1;
    bf* agg = (bf*)(wsb + 134217728);
    float* simp = (float*)(wsb + 134217728);
    float* sim  = (float*)(wsb + 134217728 + 16777216);
    int*   idx  = (int*)d_out + (out_size - 96);

    const int KTOT = 16 * H * Wd;
    const int NCH  = KTOT / 256;            // 4096 chunks

    // encoder
    conv32<float><<<dim3(64, N), 256, 0, stream>>>(cts, cts, 1, 1, w_d1, b_d1, d1, N);
    conv_tiled<<<dim3(64, N, 2), 256, 0, stream>>>(
        d1, (const bf*)nullptr, 16, 16, w_d2, b_d2, d2, N, 256, 256, 32, 128, 128, 8);
    conv_tiled<<<dim3(16, N, 4), 256, 0, stream>>>(
        d2, (const bf*)nullptr, 32, 32, w_d3, b_d3, d3, N, 128, 128, 64, 64, 64, 4);
    conv_tiled<<<dim3(4, N, 8), 256, 0, stream>>>(
        d3, (const bf*)nullptr, 64, 64, w_d4, b_d4, d4, N, 64, 64, 128, 32, 32, 2);
    // decoder (all transposed convs via MFMA)
    convt_mfma<128, 128><<<dim3(4, N, 4), 256, 0, stream>>>(
        d4, d4, w_u1, b_u1, u1, N, 32, 32, 64, 64, 64, 2);
    convt_mfma<128, 64><<<dim3(16, N, 2), 256, 0, stream>>>(
        u1, d3, w_u2, b_u2, u2, N, 64, 64, 32, 128, 128, 4);
    convt_mfma<64, 32><<<dim3(64, N, 1), 256, 0, stream>>>(
        u2, d2, w_u3, b_u3, u3, N, 128, 128, 16, 256, 256, 8);
    // cosine similarity + top-3 (Gram via MFMA)
    sim_partial<<<NCH, 256, 0, stream>>>(u3, simp, KTOT);
    sim_reduce<<<dim3(N * N), 256, 0, stream>>>(simp, sim, NCH);
    topk_kernel<<<1, 64, 0, stream>>>(sim, prng, idx, N);
    // per-slice gnn-neighbor conv (MFMA, contiguous A-reads), then gather-mean
    conv_mfma<16, 20, 160><<<dim3(256, N), 256, 0, stream>>>(
        u3, u3, 16, w_ga, b_ga, ga, N);
    gather_mean<<<dim3(512, N), 256, 0, stream>>>(ga, idx, agg);
    // gnn conv (MFMA, 32ch from u3|agg, contiguous A-reads) then light head
    conv_mfma<32, 40, 288><<<dim3(256, N), 256, 0, stream>>>(
        u3, agg, 16, w_gu, b_gu, gnn, N);
    head_tiled<<<dim3(256, N), 256, 0, stream>>>(
        cts, gnn, w_d1, b_d1, w_de, b_de, (float*)d_out, N);
}

// Round 28
// 1049.090 us; speedup vs baseline: 1.7503x; 1.0647x over previous
//
#include <hip/hip_runtime.h>
#include <hip/hip_bf16.h>
#include <math.h>

typedef __hip_bfloat16 bf;
typedef __attribute__((ext_vector_type(8))) short bf8v;   // 8 bf16 = 4 VGPR
typedef __attribute__((ext_vector_type(4))) float f4v;

__device__ __forceinline__ float bf2f(bf v) { return __bfloat162float(v); }
__device__ __forceinline__ bf f2bf(float v) { return __float2bfloat16(v); }
__device__ __forceinline__ unsigned packbf(float a, float b) {
    __hip_bfloat16_raw ra = (__hip_bfloat16_raw)__float2bfloat16(a);
    __hip_bfloat16_raw rb = (__hip_bfloat16_raw)__float2bfloat16(b);
    return (unsigned)ra.x | ((unsigned)rb.x << 16);
}

// ===========================================================================
// Weight prep kernels (one-time per launch): repack conv weights into the
// exact per-block sWt images so the hot kernels stage weights as a
// contiguous uint4 memcpy instead of thousands of scalar gathers per chunk.
// ===========================================================================
__global__ __launch_bounds__(256)
void prep_wt_convt(const float* __restrict__ Wt, bf* __restrict__ outp,
                   int CITOT, int NCH)
{
    int pair = blockIdx.x;                 // cog * NCH + cb
    int cog = pair / NCH, cb = pair % NCH;
    int t = threadIdx.x;
    bf* dst = outp + (size_t)pair * 16 * 328;
    for (int e = t; e < 16 * 288; e += 256) {
        int co = e / 288, rem = e % 288;
        int cic = rem / 9, t9 = rem % 9;
        int ky = t9 / 3, kx = t9 % 3;
        int ry = (ky == 1) ? 0 : 1;
        int rx = (kx == 1) ? 0 : 1;
        int ty = (ky == 1) ? 0 : (ky >> 1);
        int txi = (kx == 1) ? 0 : (kx >> 1);
        int ntx = 1 + rx;
        int ph = ry * 2 + rx;
        const int base4[4] = {0, 40, 112, 184};
        int kl = (ty * ntx + txi) * 32 + cic;     // cic-minor k order
        dst[co * 328 + base4[ph] + kl] =
            f2bf(Wt[(size_t)(cog * 16 + co) * CITOT * 9
                    + (size_t)(cb * 32 + cic) * 9 + t9]);
    }
}

__global__ __launch_bounds__(256)
void prep_wt_conv(const float* __restrict__ Wt, bf* __restrict__ outp,
                  int CI, int KPAD)
{
    int t = threadIdx.x;
    int K = CI * 9;
    for (int e = t; e < 16 * KPAD; e += 256) {
        int co = e / KPAD, k = e % KPAD;
        int tap = k / CI, ci = k % CI;
        outp[co * KPAD + k] = (k < K)
            ? f2bf(Wt[(size_t)co * K + ci * 9 + tap]) : f2bf(0.f);
    }
}

// ===========================================================================
// Tiled direct 3x3 conv, STRIDE 2, bf16 (d2,d3,d4). 16x16 out tile.
// r25 vectorized global staging.
// ===========================================================================
__global__ __launch_bounds__(256)
void conv_tiled(const bf* __restrict__ inA, const bf* __restrict__ inB,
                int CiA, int Ci,
                const float* __restrict__ Wt, const float* __restrict__ Bias,
                bf* __restrict__ out,
                int N, int Hi, int Wi, int Co, int Ho, int Wo, int tilesX)
{
    constexpr int IH = 33;
    constexpr int IWP = 33;
    constexpr int CHUNK = 8;

    __shared__ bf sIn[CHUNK * IH * IWP];
    __shared__ __align__(16) float sW[CHUNK * 144];

    int tile = blockIdx.x;
    int tx0 = (tile % tilesX) * 16, ty0 = (tile / tilesX) * 16;
    int n = blockIdx.y;
    int cog0 = blockIdx.z * 16;
    int t = threadIdx.x;
    int tx = t & 15, ty = t >> 4;
    int CiB = Ci - CiA;

    float acc[16];
    #pragma unroll
    for (int c = 0; c < 16; ++c) acc[c] = Bias[cog0 + c];

    for (int cb = 0; cb < Ci; cb += CHUNK) {
        int cn = (Ci - cb < CHUNK) ? (Ci - cb) : CHUNK;
        for (int e = t; e < cn * 165; e += 256) {
            int ci = e / 165, rem = e % 165;
            int py = rem / 5, seg = rem % 5;
            int gci = cb + ci;
            const bf* src = (gci < CiA)
                ? inA + (size_t)(n * CiA + gci) * Hi * Wi
                : inB + (size_t)(n * CiB + gci - CiA) * Hi * Wi;
            int iy = ty0 * 2 - 1 + py;
            bool rowok = (iy >= 0);
            bf* drow = &sIn[ci * IH * IWP + py * IWP];
            if (seg == 0) {
                int ix = tx0 * 2 - 1;
                drow[0] = (rowok && ix >= 0) ? src[(size_t)iy * Wi + ix]
                                             : f2bf(0.f);
            } else {
                int px0 = 1 + 8 * (seg - 1);
                int ix0 = tx0 * 2 + 8 * (seg - 1);
                if (rowok) {
                    uint4 v = *(const uint4*)&src[(size_t)iy * Wi + ix0];
                    const bf* pv = (const bf*)&v;
                    #pragma unroll
                    for (int j = 0; j < 8; ++j) drow[px0 + j] = pv[j];
                } else {
                    #pragma unroll
                    for (int j = 0; j < 8; ++j) drow[px0 + j] = f2bf(0.f);
                }
            }
        }
        for (int e = t; e < cn * 144; e += 256) {
            int ci = e / 144, rem = e % 144;
            int t9 = rem / 16, co = rem % 16;
            sW[ci * 144 + t9 * 16 + co] =
                Wt[(size_t)(cog0 + co) * Ci * 9 + (cb + ci) * 9 + t9];
        }
        __syncthreads();
        for (int ci = 0; ci < cn; ++ci) {
            #pragma unroll
            for (int t9 = 0; t9 < 9; ++t9) {
                int ky = t9 / 3, kx = t9 % 3;
                float v = bf2f(sIn[ci * IH * IWP + (ty * 2 + ky) * IWP
                                   + (tx * 2 + kx)]);
                const float* wp = &sW[ci * 144 + t9 * 16];
                #pragma unroll
                for (int co = 0; co < 16; ++co)
                    acc[co] = fmaf(v, wp[co], acc[co]);
            }
        }
        __syncthreads();
    }

    int oy = ty0 + ty, ox = tx0 + tx;
    #pragma unroll
    for (int co = 0; co < 16; ++co)
        out[(size_t)(n * Co + cog0 + co) * Ho * Wo + (size_t)oy * Wo + ox]
            = f2bf(fmaxf(acc[co], 0.f));
}

// ===========================================================================
// Stride-1 conv (d1 only, Ci=1). 32x32 tile, 2x2 px/thread.
// ===========================================================================
template <typename TIN>
__global__ __launch_bounds__(256)
void conv32(const TIN* __restrict__ inA, const TIN* __restrict__ inB,
            int CiA, int Ci,
            const float* __restrict__ Wt, const float* __restrict__ Bias,
            bf* __restrict__ out, int N)
{
    constexpr int CHUNK = 4;
    __shared__ float sIn[CHUNK][34][35];
    __shared__ __align__(16) float sW[CHUNK][9][16];

    int tile = blockIdx.x;
    int X0 = (tile & 7) * 32, Y0 = (tile >> 3) * 32;
    int n = blockIdx.y;
    int t = threadIdx.x, tx = t & 15, ty = t >> 4;
    int CiB = Ci - CiA;

    float acc[4][16];
    #pragma unroll
    for (int p = 0; p < 4; ++p)
        #pragma unroll
        for (int c = 0; c < 16; ++c) acc[p][c] = 0.f;

    for (int cb = 0; cb < Ci; cb += CHUNK) {
        int cn = (Ci - cb < CHUNK) ? Ci - cb : CHUNK;
        for (int e = t; e < cn * 1156; e += 256) {
            int ci = e / 1156, rem = e % 1156;
            int py = rem / 34, px = rem % 34;
            int iy = Y0 - 1 + py, ix = X0 - 1 + px;
            int gci = cb + ci;
            const TIN* src = (gci < CiA)
                ? inA + ((size_t)(n * CiA + gci) << 16)
                : inB + ((size_t)(n * CiB + gci - CiA) << 16);
            sIn[ci][py][px] = ((unsigned)iy < 256u && (unsigned)ix < 256u)
                              ? (float)src[(iy << 8) + ix] : 0.f;
        }
        for (int e = t; e < cn * 144; e += 256) {
            int ci = e / 144, rem = e % 144;
            int t9 = rem / 16, co = rem % 16;
            sW[ci][t9][co] = Wt[(size_t)co * Ci * 9 + (cb + ci) * 9 + t9];
        }
        __syncthreads();
        for (int ci = 0; ci < cn; ++ci) {
            float rin[4][4];
            #pragma unroll
            for (int a = 0; a < 4; ++a)
                #pragma unroll
                for (int b = 0; b < 4; ++b)
                    rin[a][b] = sIn[ci][2 * ty + a][2 * tx + b];
            #pragma unroll
            for (int t9 = 0; t9 < 9; ++t9) {
                const int ky = t9 / 3, kx = t9 % 3;
                float w[16];
                #pragma unroll
                for (int q = 0; q < 4; ++q)
                    *(float4*)&w[q * 4] = *(const float4*)&sW[ci][t9][q * 4];
                #pragma unroll
                for (int ry = 0; ry < 2; ++ry)
                    #pragma unroll
                    for (int rx = 0; rx < 2; ++rx) {
                        float v = rin[ry + ky][rx + kx];
                        #pragma unroll
                        for (int co = 0; co < 16; ++co)
                            acc[ry * 2 + rx][co] = fmaf(v, w[co], acc[ry * 2 + rx][co]);
                    }
            }
        }
        __syncthreads();
    }

    #pragma unroll
    for (int co = 0; co < 16; ++co) {
        float bs = Bias[co];
        bf* dst = out + ((size_t)(n * 16 + co) << 16);
        #pragma unroll
        for (int ry = 0; ry < 2; ++ry) {
            unsigned pk = packbf(fmaxf(acc[ry * 2 + 0][co] + bs, 0.f),
                                 fmaxf(acc[ry * 2 + 1][co] + bs, 0.f));
            *(unsigned*)(dst + ((Y0 + 2 * ty + ry) << 8) + X0 + 2 * tx) = pk;
        }
    }
}

// ===========================================================================
// MFMA implicit-GEMM stride-1 conv: contiguous A-reads (r23), vectorized
// input staging (r24), PREPACKED weights (r26: contiguous uint4 copy).
// ===========================================================================
template <int CI, int CIP, int KPAD>
__global__ __launch_bounds__(256)
void conv_mfma(const bf* __restrict__ inA, const bf* __restrict__ inB,
               int CiA, const bf* __restrict__ pW,
               const float* __restrict__ Bias,
               bf* __restrict__ out, int N)
{
    constexpr int NM = KPAD / 32;
    __shared__ __align__(16) bf sIn2[18][19][CIP];
    __shared__ __align__(16) bf sWt[16][KPAD];

    int tile = blockIdx.x;
    int X0 = (tile & 15) * 16, Y0 = (tile >> 4) * 16;
    int n = blockIdx.y;
    int t = threadIdx.x;
    int lane = t & 63, wave = t >> 6;
    int q = lane >> 4, mcol = lane & 15;
    int CiB = CI - CiA;

    // weights: contiguous copy of prepacked image
    for (int e = t; e < 16 * KPAD / 8; e += 256)
        ((uint4*)sWt)[e] = ((const uint4*)pW)[e];
    // input: channel-minor [py][px][ci]; vectorized global reads
    for (int e = t; e < CI * 72; e += 256) {       // 18 rows x 4 slots
        int ci = e / 72, rem = e % 72;
        int py = rem / 4, slot = rem % 4;
        const bf* src = (ci < CiA)
            ? inA + ((size_t)(n * CiA + ci) << 16)
            : inB + ((size_t)(n * CiB + ci - CiA) << 16);
        int iy = Y0 - 1 + py;
        bool rowok = ((unsigned)iy < 256u);
        if (slot == 0) {
            int ix = X0 - 1;
            sIn2[py][0][ci] = (rowok && ix >= 0) ? src[(iy << 8) + ix] : f2bf(0.f);
        } else if (slot == 3) {
            int ix = X0 + 16;
            sIn2[py][17][ci] = (rowok && ix < 256) ? src[(iy << 8) + ix] : f2bf(0.f);
        } else {
            int px0 = (slot == 1) ? 1 : 9;
            if (rowok) {
                uint4 v = *(const uint4*)&src[(iy << 8) + X0 - 1 + px0];
                const bf* pv = (const bf*)&v;
                #pragma unroll
                for (int j = 0; j < 8; ++j) sIn2[py][px0 + j][ci] = pv[j];
            } else {
                #pragma unroll
                for (int j = 0; j < 8; ++j) sIn2[py][px0 + j][ci] = f2bf(0.f);
            }
        }
    }
    __syncthreads();

    f4v acc[4];
    #pragma unroll
    for (int g = 0; g < 4; ++g) acc[g] = (f4v){0.f, 0.f, 0.f, 0.f};

    int prow0 = wave * 4;
    #pragma unroll
    for (int s = 0; s < NM; ++s) {
        bf8v wf = *(const bf8v*)&sWt[mcol][s * 32 + q * 8];
        int tap, ciofs;
        if (CI == 32) { tap = s;               ciofs = q * 8; }
        else          { tap = 2 * s + (q >> 1); if (tap > 8) tap = 8;
                        ciofs = (q & 1) * 8; }
        int ay = tap / 3, ax = tap - ay * 3;
        #pragma unroll
        for (int g = 0; g < 4; ++g) {
            bf8v af = *(const bf8v*)&sIn2[prow0 + g + ay][mcol + ax][ciofs];
            acc[g] = __builtin_amdgcn_mfma_f32_16x16x32_bf16(af, wf, acc[g], 0, 0, 0);
        }
    }

    float bs = Bias[mcol];
    bf* dst = out + ((size_t)(n * 16 + mcol) << 16);
    #pragma unroll
    for (int g = 0; g < 4; ++g) {
        int oy = Y0 + prow0 + g, ox = X0 + q * 4;
        uint2 pk;
        pk.x = packbf(fmaxf(acc[g][0] + bs, 0.f), fmaxf(acc[g][1] + bs, 0.f));
        pk.y = packbf(fmaxf(acc[g][2] + bs, 0.f), fmaxf(acc[g][3] + bs, 0.f));
        *(uint2*)(dst + (oy << 8) + ox) = pk;
    }
}

// ===========================================================================
// MFMA phase-decomposed transposed conv: r23 contiguous A-reads, r24
// vectorized input staging, r26 PREPACKED weights (contiguous uint4 copy).
// ===========================================================================
#define CVT_CHAIN(PH, KOFF, AY, AX)                                           \
    {                                                                          \
        bf8v wf = *(const bf8v*)&sWt[mcol][(KOFF) + q * 8];                    \
        _Pragma("unroll")                                                      \
        for (int g = 0; g < 4; ++g) {                                          \
            bf8v af = *(const bf8v*)&sIn2[prow0 + g + (AY)][mcol + (AX)][q * 8];\
            acc[PH][g] = __builtin_amdgcn_mfma_f32_16x16x32_bf16(af, wf,       \
                                                      acc[PH][g], 0, 0, 0);    \
        }                                                                      \
    }

template <int CITOT, int CIA>
__global__ __launch_bounds__(256)
void convt_mfma(const bf* __restrict__ inA, const bf* __restrict__ inB,
                const bf* __restrict__ pW, const float* __restrict__ Bias,
                bf* __restrict__ out,
                int N, int Hi, int Wi, int Cotot, int Ho, int Wo, int tilesX)
{
    constexpr int NCH = CITOT / 32;
    __shared__ __align__(16) bf sIn2[17][18][40];  // [py][px][ci pad40] 24.5KB
    __shared__ __align__(16) bf sWt[16][328];      // phase bases 0,40,112,184

    int tile = blockIdx.x;
    int J0 = (tile % tilesX) * 16, I0 = (tile / tilesX) * 16;
    int n = blockIdx.y;
    int t = threadIdx.x;
    int lane = t & 63, wave = t >> 6;
    int q = lane >> 4, mcol = lane & 15;
    int prow0 = wave * 4;

    f4v acc[4][4];
    #pragma unroll
    for (int p = 0; p < 4; ++p)
        #pragma unroll
        for (int g = 0; g < 4; ++g) acc[p][g] = (f4v){0.f, 0.f, 0.f, 0.f};

    for (int cb = 0; cb < NCH; ++cb) {
        if (cb) __syncthreads();                  // drain reads before restage
        for (int e = t; e < 32 * 51; e += 256) {  // 51 = 17 rows * 3 segs
            int ci = e / 51, rem = e % 51;
            int py = rem / 3, seg = rem % 3;
            int gci = cb * 32 + ci;
            const bf* src = (gci < CIA)
                ? inA + (size_t)(n * CIA + gci) * Hi * Wi
                : inB + (size_t)(n * (CITOT - CIA) + gci - CIA) * Hi * Wi;
            int iy = I0 + py;
            if (seg < 2) {
                int px0 = seg * 8;
                if (iy < Hi) {
                    uint4 v = *(const uint4*)&src[(size_t)iy * Wi + J0 + px0];
                    const bf* pv = (const bf*)&v;
                    #pragma unroll
                    for (int j = 0; j < 8; ++j) sIn2[py][px0 + j][ci] = pv[j];
                } else {
                    #pragma unroll
                    for (int j = 0; j < 8; ++j) sIn2[py][px0 + j][ci] = f2bf(0.f);
                }
            } else {
                int ix = J0 + 16;
                sIn2[py][16][ci] = (iy < Hi && ix < Wi)
                                   ? src[(size_t)iy * Wi + ix] : f2bf(0.f);
                sIn2[py][17][ci] = f2bf(0.f);
            }
        }
        // weights: contiguous copy of the (cog, cb) prepacked image
        {
            const uint4* wsrc = (const uint4*)(pW
                + ((size_t)blockIdx.z * NCH + cb) * 16 * 328);
            for (int e = t; e < 656; e += 256)     // 16*328/8
                ((uint4*)sWt)[e] = wsrc[e];
        }
        __syncthreads();

        //        PH  KOFF AY AX      (chain = one tap over 32 channels)
        CVT_CHAIN(0,   0, 0, 0)    // phase (ry0,rx0): tap (1,1)
        CVT_CHAIN(1,  40, 0, 0)    // phase (ry0,rx1): tap kx=0
        CVT_CHAIN(1,  72, 0, 1)    //                  tap kx=2
        CVT_CHAIN(2, 112, 0, 0)    // phase (ry1,rx0): tap ky=0
        CVT_CHAIN(2, 144, 1, 0)    //                  tap ky=2
        CVT_CHAIN(3, 184, 0, 0)    // phase (ry1,rx1): tap (0,0)
        CVT_CHAIN(3, 216, 0, 1)    //                  tap (0,2)
        CVT_CHAIN(3, 248, 1, 0)    //                  tap (2,0)
        CVT_CHAIN(3, 280, 1, 1)    //                  tap (2,2)
    }

    float bs = Bias[blockIdx.z * 16 + mcol];
    bf* dst = out + (size_t)(n * Cotot + blockIdx.z * 16 + mcol) * Ho * Wo;
    #pragma unroll
    for (int ph = 0; ph < 4; ++ph) {
        const int ry = ph >> 1, rx = ph & 1;
        #pragma unroll
        for (int g = 0; g < 4; ++g) {
            int oy = 2 * (I0 + prow0 + g) + ry;
            #pragma unroll
            for (int jj = 0; jj < 4; ++jj) {
                int ox = 2 * (J0 + q * 4 + jj) + rx;
                dst[(size_t)oy * Wo + ox] = f2bf(fmaxf(acc[ph][g][jj] + bs, 0.f));
            }
        }
    }
}

// ===========================================================================
// MFMA Gram partials (verified round 20).
// ===========================================================================
__global__ __launch_bounds__(256)
void sim_partial(const bf* __restrict__ f, float* __restrict__ part, int KTOT)
{
    __shared__ __align__(16) bf tile[32][264];
    int c = blockIdx.x;
    int t = threadIdx.x;
    int k0 = c << 8;

    for (int e = t; e < 1024; e += 256) {
        int row = e >> 5, col8 = (e & 31) * 8;
        uint4 v = *(const uint4*)&f[(size_t)row * KTOT + k0 + col8];
        *(uint4*)&tile[row][col8] = v;
    }
    __syncthreads();

    int lane = t & 63, wave = t >> 6;
    int q = lane >> 4, mcol = lane & 15;
    int qr = wave >> 1, qc = wave & 1;

    f4v acc = (f4v){0.f, 0.f, 0.f, 0.f};
    #pragma unroll
    for (int ks = 0; ks < 8; ++ks) {
        bf8v a = *(const bf8v*)&tile[qr * 16 + mcol][ks * 32 + q * 8];
        bf8v b = *(const bf8v*)&tile[qc * 16 + mcol][ks * 32 + q * 8];
        acc = __builtin_amdgcn_mfma_f32_16x16x32_bf16(a, b, acc, 0, 0, 0);
    }

    float* dst = part + (size_t)c * 1024;
    #pragma unroll
    for (int jj = 0; jj < 4; ++jj) {
        int i = qr * 16 + q * 4 + jj;
        int j = qc * 16 + mcol;
        dst[i * 32 + j] = acc[jj];
    }
}

__global__ __launch_bounds__(256)
void sim_reduce(const float* __restrict__ part, float* __restrict__ sim, int nchunks)
{
    __shared__ float red[256];
    int pair = blockIdx.x;
    int t = threadIdx.x;
    float s = 0.f;
    for (int k = t; k < nchunks; k += 256)
        s += part[(size_t)k * 1024 + pair];
    red[t] = s;
    __syncthreads();
    #pragma unroll
    for (int off = 128; off > 0; off >>= 1) {
        if (t < off) red[t] += red[t + off];
        __syncthreads();
    }
    if (t == 0) sim[pair] = red[0];
}

// ===========================================================================
// Cosine sim + group mask + top-3 (strict >, lowest index wins ties).
// ===========================================================================
__global__ void topk_kernel(const float* __restrict__ sim, const int* __restrict__ prange,
                            int* __restrict__ idx, int N)
{
    int i = threadIdx.x;
    if (i >= N) return;
    float nm_i = fmaxf(sqrtf(sim[i * N + i]), 1e-8f);
    int p0 = prange[0], p1 = prange[1];
    int gi = (i >= p0) + (i >= p1);
    float vals[32];
    for (int j = 0; j < N; ++j) {
        int gj = (j >= p0) + (j >= p1);
        if (j == i || gj != gi) { vals[j] = -1e30f; continue; }
        float nm_j = fmaxf(sqrtf(sim[j * N + j]), 1e-8f);
        vals[j] = sim[i * N + j] / (nm_i * nm_j);
    }
    for (int k = 0; k < 3; ++k) {
        float best = -2e30f; int bj = 0;
        for (int j = 0; j < N; ++j)
            if (vals[j] > best) { best = vals[j]; bj = j; }
        idx[i * 3 + k] = bj;
        vals[bj] = -1e30f;
    }
}

// ===========================================================================
// Gather-mean: agg[n] = (ga[i0] + ga[i1] + ga[i2]) / 3.
// ===========================================================================
__global__ __launch_bounds__(256)
void gather_mean(const bf* __restrict__ ga, const int* __restrict__ idx,
                 bf* __restrict__ agg)
{
    int n = blockIdx.y;
    int v = blockIdx.x * 256 + threadIdx.x;
    int i0 = idx[n * 3 + 0], i1 = idx[n * 3 + 1], i2 = idx[n * 3 + 2];
    const size_t stride = (size_t)16 << 16;
    const uint4* p0 = (const uint4*)(ga + stride * i0) + v;
    const uint4* p1 = (const uint4*)(ga + stride * i1) + v;
    const uint4* p2 = (const uint4*)(ga + stride * i2) + v;
    uint4 a = *p0, b = *p1, c = *p2;
    uint4 r;
    unsigned* ap = (unsigned*)&a; unsigned* bp = (unsigned*)&b;
    unsigned* cp = (unsigned*)&c; unsigned* rp = (unsigned*)&r;
    #pragma unroll
    for (int w = 0; w < 4; ++w) {
        float fa0 = __bfloat162float((__hip_bfloat16_raw){(unsigned short)(ap[w] & 0xffff)});
        float fb0 = __bfloat162float((__hip_bfloat16_raw){(unsigned short)(bp[w] & 0xffff)});
        float fc0 = __bfloat162float((__hip_bfloat16_raw){(unsigned short)(cp[w] & 0xffff)});
        float fa1 = __bfloat162float((__hip_bfloat16_raw){(unsigned short)(ap[w] >> 16)});
        float fb1 = __bfloat162float((__hip_bfloat16_raw){(unsigned short)(bp[w] >> 16)});
        float fc1 = __bfloat162float((__hip_bfloat16_raw){(unsigned short)(cp[w] >> 16)});
        rp[w] = packbf((fa0 + fb0 + fc0) * (1.f / 3.f),
                       (fa1 + fb1 + fc1) * (1.f / 3.f));
    }
    *((uint4*)(agg + stride * n) + v) = r;
}

// ===========================================================================
// Light head: gnn (bf16) + d1 recompute + dense 32->2 + softmax.
// ===========================================================================
__global__ __launch_bounds__(256)
void head_tiled(const float* __restrict__ cts, const bf* __restrict__ gnn,
                const float* __restrict__ w_d1, const float* __restrict__ b_d1,
                const float* __restrict__ w_de, const float* __restrict__ b_de,
                float* __restrict__ out, int N)
{
    __shared__ float sCts[18][19];
    __shared__ float sWd1[144];
    __shared__ float sB1[16];
    __shared__ float sDe[64];

    int tile = blockIdx.x;
    int X0 = (tile & 15) * 16, Y0 = (tile >> 4) * 16;
    int n = blockIdx.y;
    int t = threadIdx.x, tx = t & 15, ty = t >> 4;

    for (int e = t; e < 18 * 18; e += 256) {
        int py = e / 18, px = e % 18;
        int iy = Y0 - 1 + py, ix = X0 - 1 + px;
        sCts[py][px] = ((unsigned)iy < 256u && (unsigned)ix < 256u)
                       ? cts[((size_t)n << 16) + (iy << 8) + ix] : 0.f;
    }
    if (t < 144) sWd1[t] = w_d1[t];
    else if (t < 160) sB1[t - 144] = b_d1[t - 144];
    else if (t >= 192 && t < 256) sDe[t - 192] = w_de[t - 192];
    __syncthreads();

    int pix = ((Y0 + ty) << 8) + X0 + tx;
    float l0 = b_de[0], l1 = b_de[1];

    #pragma unroll
    for (int c = 0; c < 16; ++c) {
        float v = bf2f(gnn[((size_t)(n * 16 + c) << 16) + pix]);
        l0 = fmaf(v, sDe[c * 2 + 0], l0);
        l1 = fmaf(v, sDe[c * 2 + 1], l1);
    }

    float ct[3][3];
    #pragma unroll
    for (int a = 0; a < 3; ++a)
        #pragma unroll
        for (int b = 0; b < 3; ++b)
            ct[a][b] = sCts[ty + a][tx + b];
    #pragma unroll
    for (int c = 0; c < 16; ++c) {
        float a1 = sB1[c];
        #pragma unroll
        for (int t9 = 0; t9 < 9; ++t9)
            a1 = fmaf(ct[t9 / 3][t9 % 3], sWd1[c * 9 + t9], a1);
        float v = fmaxf(a1, 0.f);
        l0 = fmaf(v, sDe[(16 + c) * 2 + 0], l0);
        l1 = fmaf(v, sDe[(16 + c) * 2 + 1], l1);
    }

    float m = fmaxf(l0, l1);
    float e0 = expf(l0 - m), e1 = expf(l1 - m);
    float inv = 1.f / (e0 + e1);
    size_t base = ((size_t)n * 2) << 16;
    out[base + pix] = e0 * inv;
    out[base + 65536 + pix] = e1 * inv;
}

// ===========================================================================

extern "C" void kernel_launch(void* const* d_in, const int* in_sizes, int n_in,
                              void* d_out, int out_size, void* d_ws, size_t ws_size,
                              hipStream_t stream)
{
    const float* cts  = (const float*)d_in[0];
    const int*   prng = (const int*)d_in[1];
    const float* w_d1 = (const float*)d_in[2];  const float* b_d1 = (const float*)d_in[3];
    const float* w_d2 = (const float*)d_in[4];  const float* b_d2 = (const float*)d_in[5];
    const float* w_d3 = (const float*)d_in[6];  const float* b_d3 = (const float*)d_in[7];
    const float* w_d4 = (const float*)d_in[8];  const float* b_d4 = (const float*)d_in[9];
    const float* w_u1 = (const float*)d_in[10]; const float* b_u1 = (const float*)d_in[11];
    const float* w_u2 = (const float*)d_in[12]; const float* b_u2 = (const float*)d_in[13];
    const float* w_u3 = (const float*)d_in[14]; const float* b_u3 = (const float*)d_in[15];
    const float* w_ga = (const float*)d_in[16]; const float* b_ga = (const float*)d_in[17];
    const float* w_gu = (const float*)d_in[18]; const float* b_gu = (const float*)d_in[19];
    const float* w_de = (const float*)d_in[20]; const float* b_de = (const float*)d_in[21];

    const int H = 256, Wd = 256;
    const int N = in_sizes[0] / (H * Wd);   // 32

    // ---- workspace layout (192 MiB total), lifetime reuse ----
    // u3 [0,64M); R1 [64M,128M): d1 -> u1/u2 -> ga/gnn (spans the FULL 64MB);
    // R2 [128M,184M): d2/d3/d4 -> simp/sim -> agg.
    // FREE window: [184M,192M) — prepacked weights live here (~287KB).
    char* wsb = (char*)d_ws;
    bf* u3 = (bf*)(wsb);
    bf* R1 = (bf*)(wsb + 67108864);

    bf* d1 = R1;
    bf* d2 = (bf*)(wsb + 134217728);
    bf* d3 = (bf*)(wsb + 134217728 + 33554432);
    bf* d4 = (bf*)(wsb + 134217728 + 50331648);
    bf* u1 = R1;
    bf* u2 = (bf*)(wsb + 67108864 + 16777216);
    bf* ga = R1;
    bf* gnn = R1;
    bf* agg = (bf*)(wsb + 134217728);
    float* simp = (float*)(wsb + 134217728);
    float* sim  = (float*)(wsb + 134217728 + 16777216);
    int*   idx  = (int*)d_out + (out_size - 96);

    // prepacked weight images in the dead window @ 184 MiB
    bf* pwu1 = (bf*)(wsb + 192937984);               // 16 pairs * 10496B
    bf* pwu2 = (bf*)(wsb + 192937984 + 167936);      //  8 pairs
    bf* pwu3 = (bf*)(wsb + 192937984 + 251904);      //  2 pairs
    bf* pwga = (bf*)(wsb + 192937984 + 272896);      // 16x160
    bf* pwgn = (bf*)(wsb + 192937984 + 278016);      // 16x288

    const int KTOT = 16 * H * Wd;
    const int NCH  = KTOT / 256;            // 4096 chunks

    // one-time weight repack (tiny)
    prep_wt_convt<<<16, 256, 0, stream>>>(w_u1, pwu1, 128, 4);
    prep_wt_convt<<<8,  256, 0, stream>>>(w_u2, pwu2, 128, 4);
    prep_wt_convt<<<2,  256, 0, stream>>>(w_u3, pwu3, 64, 2);
    prep_wt_conv<<<1,   256, 0, stream>>>(w_ga, pwga, 16, 160);
    prep_wt_conv<<<1,   256, 0, stream>>>(w_gu, pwgn, 32, 288);

    // encoder
    conv32<float><<<dim3(64, N), 256, 0, stream>>>(cts, cts, 1, 1, w_d1, b_d1, d1, N);
    conv_tiled<<<dim3(64, N, 2), 256, 0, stream>>>(
        d1, (const bf*)nullptr, 16, 16, w_d2, b_d2, d2, N, 256, 256, 32, 128, 128, 8);
    conv_tiled<<<dim3(16, N, 4), 256, 0, stream>>>(
        d2, (const bf*)nullptr, 32, 32, w_d3, b_d3, d3, N, 128, 128, 64, 64, 64, 4);
    conv_tiled<<<dim3(4, N, 8), 256, 0, stream>>>(
        d3, (const bf*)nullptr, 64, 64, w_d4, b_d4, d4, N, 64, 64, 128, 32, 32, 2);
    // decoder (all transposed convs via MFMA, prepacked weights)
    convt_mfma<128, 128><<<dim3(4, N, 4), 256, 0, stream>>>(
        d4, d4, pwu1, b_u1, u1, N, 32, 32, 64, 64, 64, 2);
    convt_mfma<128, 64><<<dim3(16, N, 2), 256, 0, stream>>>(
        u1, d3, pwu2, b_u2, u2, N, 64, 64, 32, 128, 128, 4);
    convt_mfma<64, 32><<<dim3(64, N, 1), 256, 0, stream>>>(
        u2, d2, pwu3, b_u3, u3, N, 128, 128, 16, 256, 256, 8);
    // cosine similarity + top-3 (Gram via MFMA)
    sim_partial<<<NCH, 256, 0, stream>>>(u3, simp, KTOT);
    sim_reduce<<<dim3(N * N), 256, 0, stream>>>(simp, sim, NCH);
    topk_kernel<<<1, 64, 0, stream>>>(sim, prng, idx, N);
    // per-slice gnn-neighbor conv (MFMA), then gather-mean
    conv_mfma<16, 20, 160><<<dim3(256, N), 256, 0, stream>>>(
        u3, u3, 16, pwga, b_ga, ga, N);
    gather_mean<<<dim3(512, N), 256, 0, stream>>>(ga, idx, agg);
    // gnn conv (MFMA, 32ch from u3|agg) then light head
    conv_mfma<32, 40, 288><<<dim3(256, N), 256, 0, stream>>>(
        u3, agg, 16, pwgn, b_gu, gnn, N);
    head_tiled<<<dim3(256, N), 256, 0, stream>>>(
        cts, gnn, w_d1, b_d1, w_de, b_de, (float*)d_out, N);
}

// Round 29
// 913.225 us; speedup vs baseline: 2.0107x; 1.1488x over previous
//
#include <hip/hip_runtime.h>
#include <hip/hip_bf16.h>
#include <math.h>

typedef __hip_bfloat16 bf;
typedef __attribute__((ext_vector_type(8))) short bf8v;   // 8 bf16 = 4 VGPR
typedef __attribute__((ext_vector_type(4))) float f4v;

__device__ __forceinline__ float bf2f(bf v) { return __bfloat162float(v); }
__device__ __forceinline__ bf f2bf(float v) { return __float2bfloat16(v); }
__device__ __forceinline__ unsigned packbf(float a, float b) {
    __hip_bfloat16_raw ra = (__hip_bfloat16_raw)__float2bfloat16(a);
    __hip_bfloat16_raw rb = (__hip_bfloat16_raw)__float2bfloat16(b);
    return (unsigned)ra.x | ((unsigned)rb.x << 16);
}

// XCD-aware bijective work swizzle (requires total % 8 == 0): block with
// linear id L executes work id (L%8)*(total/8) + L/8, so each XCD owns a
// contiguous (tile, n) range -> halo cache lines shared within one L2.
__device__ __forceinline__ int xcd_swizzle_lin()
{
    int total = gridDim.x * gridDim.y * gridDim.z;
    int lin = blockIdx.x + gridDim.x * (blockIdx.y + gridDim.y * blockIdx.z);
    return (lin & 7) * (total >> 3) + (lin >> 3);
}

// ===========================================================================
// Weight prep kernels (one-time per launch): repack conv weights into the
// exact per-block sWt images so the hot kernels stage weights as a
// contiguous uint4 memcpy instead of thousands of scalar gathers per chunk.
// ===========================================================================
__global__ __launch_bounds__(256)
void prep_wt_convt(const float* __restrict__ Wt, bf* __restrict__ outp,
                   int CITOT, int NCH)
{
    int pair = blockIdx.x;                 // cog * NCH + cb
    int cog = pair / NCH, cb = pair % NCH;
    int t = threadIdx.x;
    bf* dst = outp + (size_t)pair * 16 * 328;
    for (int e = t; e < 16 * 288; e += 256) {
        int co = e / 288, rem = e % 288;
        int cic = rem / 9, t9 = rem % 9;
        int ky = t9 / 3, kx = t9 % 3;
        int ry = (ky == 1) ? 0 : 1;
        int rx = (kx == 1) ? 0 : 1;
        int ty = (ky == 1) ? 0 : (ky >> 1);
        int txi = (kx == 1) ? 0 : (kx >> 1);
        int ntx = 1 + rx;
        int ph = ry * 2 + rx;
        const int base4[4] = {0, 40, 112, 184};
        int kl = (ty * ntx + txi) * 32 + cic;     // cic-minor k order
        dst[co * 328 + base4[ph] + kl] =
            f2bf(Wt[(size_t)(cog * 16 + co) * CITOT * 9
                    + (size_t)(cb * 32 + cic) * 9 + t9]);
    }
}

__global__ __launch_bounds__(256)
void prep_wt_conv(const float* __restrict__ Wt, bf* __restrict__ outp,
                  int CI, int KPAD)
{
    int t = threadIdx.x;
    int K = CI * 9;
    for (int e = t; e < 16 * KPAD; e += 256) {
        int co = e / KPAD, k = e % KPAD;
        int tap = k / CI, ci = k % CI;
        outp[co * KPAD + k] = (k < K)
            ? f2bf(Wt[(size_t)co * K + ci * 9 + tap]) : f2bf(0.f);
    }
}

// ===========================================================================
// Tiled direct 3x3 conv, STRIDE 2, bf16 (d2,d3,d4). 16x16 out tile.
// r25 vectorized global staging; r29 XCD swizzle.
// ===========================================================================
__global__ __launch_bounds__(256)
void conv_tiled(const bf* __restrict__ inA, const bf* __restrict__ inB,
                int CiA, int Ci,
                const float* __restrict__ Wt, const float* __restrict__ Bias,
                bf* __restrict__ out,
                int N, int Hi, int Wi, int Co, int Ho, int Wo, int tilesX)
{
    constexpr int IH = 33;
    constexpr int IWP = 33;
    constexpr int CHUNK = 8;

    __shared__ bf sIn[CHUNK * IH * IWP];
    __shared__ __align__(16) float sW[CHUNK * 144];

    int swz = xcd_swizzle_lin();
    int tile = swz % gridDim.x;
    int rest = swz / gridDim.x;
    int n = rest % gridDim.y;
    int cog0 = (rest / gridDim.y) * 16;

    int tx0 = (tile % tilesX) * 16, ty0 = (tile / tilesX) * 16;
    int t = threadIdx.x;
    int tx = t & 15, ty = t >> 4;
    int CiB = Ci - CiA;

    float acc[16];
    #pragma unroll
    for (int c = 0; c < 16; ++c) acc[c] = Bias[cog0 + c];

    for (int cb = 0; cb < Ci; cb += CHUNK) {
        int cn = (Ci - cb < CHUNK) ? (Ci - cb) : CHUNK;
        for (int e = t; e < cn * 165; e += 256) {
            int ci = e / 165, rem = e % 165;
            int py = rem / 5, seg = rem % 5;
            int gci = cb + ci;
            const bf* src = (gci < CiA)
                ? inA + (size_t)(n * CiA + gci) * Hi * Wi
                : inB + (size_t)(n * CiB + gci - CiA) * Hi * Wi;
            int iy = ty0 * 2 - 1 + py;
            bool rowok = (iy >= 0);
            bf* drow = &sIn[ci * IH * IWP + py * IWP];
            if (seg == 0) {
                int ix = tx0 * 2 - 1;
                drow[0] = (rowok && ix >= 0) ? src[(size_t)iy * Wi + ix]
                                             : f2bf(0.f);
            } else {
                int px0 = 1 + 8 * (seg - 1);
                int ix0 = tx0 * 2 + 8 * (seg - 1);
                if (rowok) {
                    uint4 v = *(const uint4*)&src[(size_t)iy * Wi + ix0];
                    const bf* pv = (const bf*)&v;
                    #pragma unroll
                    for (int j = 0; j < 8; ++j) drow[px0 + j] = pv[j];
                } else {
                    #pragma unroll
                    for (int j = 0; j < 8; ++j) drow[px0 + j] = f2bf(0.f);
                }
            }
        }
        for (int e = t; e < cn * 144; e += 256) {
            int ci = e / 144, rem = e % 144;
            int t9 = rem / 16, co = rem % 16;
            sW[ci * 144 + t9 * 16 + co] =
                Wt[(size_t)(cog0 + co) * Ci * 9 + (cb + ci) * 9 + t9];
        }
        __syncthreads();
        for (int ci = 0; ci < cn; ++ci) {
            #pragma unroll
            for (int t9 = 0; t9 < 9; ++t9) {
                int ky = t9 / 3, kx = t9 % 3;
                float v = bf2f(sIn[ci * IH * IWP + (ty * 2 + ky) * IWP
                                   + (tx * 2 + kx)]);
                const float* wp = &sW[ci * 144 + t9 * 16];
                #pragma unroll
                for (int co = 0; co < 16; ++co)
                    acc[co] = fmaf(v, wp[co], acc[co]);
            }
        }
        __syncthreads();
    }

    int oy = ty0 + ty, ox = tx0 + tx;
    #pragma unroll
    for (int co = 0; co < 16; ++co)
        out[(size_t)(n * Co + cog0 + co) * Ho * Wo + (size_t)oy * Wo + ox]
            = f2bf(fmaxf(acc[co], 0.f));
}

// ===========================================================================
// Stride-1 conv (d1 only, Ci=1). 32x32 tile, 2x2 px/thread.
// ===========================================================================
template <typename TIN>
__global__ __launch_bounds__(256)
void conv32(const TIN* __restrict__ inA, const TIN* __restrict__ inB,
            int CiA, int Ci,
            const float* __restrict__ Wt, const float* __restrict__ Bias,
            bf* __restrict__ out, int N)
{
    constexpr int CHUNK = 4;
    __shared__ float sIn[CHUNK][34][35];
    __shared__ __align__(16) float sW[CHUNK][9][16];

    int tile = blockIdx.x;
    int X0 = (tile & 7) * 32, Y0 = (tile >> 3) * 32;
    int n = blockIdx.y;
    int t = threadIdx.x, tx = t & 15, ty = t >> 4;
    int CiB = Ci - CiA;

    float acc[4][16];
    #pragma unroll
    for (int p = 0; p < 4; ++p)
        #pragma unroll
        for (int c = 0; c < 16; ++c) acc[p][c] = 0.f;

    for (int cb = 0; cb < Ci; cb += CHUNK) {
        int cn = (Ci - cb < CHUNK) ? Ci - cb : CHUNK;
        for (int e = t; e < cn * 1156; e += 256) {
            int ci = e / 1156, rem = e % 1156;
            int py = rem / 34, px = rem % 34;
            int iy = Y0 - 1 + py, ix = X0 - 1 + px;
            int gci = cb + ci;
            const TIN* src = (gci < CiA)
                ? inA + ((size_t)(n * CiA + gci) << 16)
                : inB + ((size_t)(n * CiB + gci - CiA) << 16);
            sIn[ci][py][px] = ((unsigned)iy < 256u && (unsigned)ix < 256u)
                              ? (float)src[(iy << 8) + ix] : 0.f;
        }
        for (int e = t; e < cn * 144; e += 256) {
            int ci = e / 144, rem = e % 144;
            int t9 = rem / 16, co = rem % 16;
            sW[ci][t9][co] = Wt[(size_t)co * Ci * 9 + (cb + ci) * 9 + t9];
        }
        __syncthreads();
        for (int ci = 0; ci < cn; ++ci) {
            float rin[4][4];
            #pragma unroll
            for (int a = 0; a < 4; ++a)
                #pragma unroll
                for (int b = 0; b < 4; ++b)
                    rin[a][b] = sIn[ci][2 * ty + a][2 * tx + b];
            #pragma unroll
            for (int t9 = 0; t9 < 9; ++t9) {
                const int ky = t9 / 3, kx = t9 % 3;
                float w[16];
                #pragma unroll
                for (int q = 0; q < 4; ++q)
                    *(float4*)&w[q * 4] = *(const float4*)&sW[ci][t9][q * 4];
                #pragma unroll
                for (int ry = 0; ry < 2; ++ry)
                    #pragma unroll
                    for (int rx = 0; rx < 2; ++rx) {
                        float v = rin[ry + ky][rx + kx];
                        #pragma unroll
                        for (int co = 0; co < 16; ++co)
                            acc[ry * 2 + rx][co] = fmaf(v, w[co], acc[ry * 2 + rx][co]);
                    }
            }
        }
        __syncthreads();
    }

    #pragma unroll
    for (int co = 0; co < 16; ++co) {
        float bs = Bias[co];
        bf* dst = out + ((size_t)(n * 16 + co) << 16);
        #pragma unroll
        for (int ry = 0; ry < 2; ++ry) {
            unsigned pk = packbf(fmaxf(acc[ry * 2 + 0][co] + bs, 0.f),
                                 fmaxf(acc[ry * 2 + 1][co] + bs, 0.f));
            *(unsigned*)(dst + ((Y0 + 2 * ty + ry) << 8) + X0 + 2 * tx) = pk;
        }
    }
}

// ===========================================================================
// MFMA implicit-GEMM stride-1 conv: contiguous A-reads (r23), vectorized
// input staging (r24), prepacked weights (r26), XCD swizzle (r29).
// ===========================================================================
template <int CI, int CIP, int KPAD>
__global__ __launch_bounds__(256)
void conv_mfma(const bf* __restrict__ inA, const bf* __restrict__ inB,
               int CiA, const bf* __restrict__ pW,
               const float* __restrict__ Bias,
               bf* __restrict__ out, int N)
{
    constexpr int NM = KPAD / 32;
    __shared__ __align__(16) bf sIn2[18][19][CIP];
    __shared__ __align__(16) bf sWt[16][KPAD];

    int swz = xcd_swizzle_lin();           // gridDim.x == 256 always
    int tile = swz & 255;
    int n = swz >> 8;

    int X0 = (tile & 15) * 16, Y0 = (tile >> 4) * 16;
    int t = threadIdx.x;
    int lane = t & 63, wave = t >> 6;
    int q = lane >> 4, mcol = lane & 15;
    int CiB = CI - CiA;

    // weights: contiguous copy of prepacked image
    for (int e = t; e < 16 * KPAD / 8; e += 256)
        ((uint4*)sWt)[e] = ((const uint4*)pW)[e];
    // input: channel-minor [py][px][ci]; vectorized global reads
    for (int e = t; e < CI * 72; e += 256) {       // 18 rows x 4 slots
        int ci = e / 72, rem = e % 72;
        int py = rem / 4, slot = rem % 4;
        const bf* src = (ci < CiA)
            ? inA + ((size_t)(n * CiA + ci) << 16)
            : inB + ((size_t)(n * CiB + ci - CiA) << 16);
        int iy = Y0 - 1 + py;
        bool rowok = ((unsigned)iy < 256u);
        if (slot == 0) {
            int ix = X0 - 1;
            sIn2[py][0][ci] = (rowok && ix >= 0) ? src[(iy << 8) + ix] : f2bf(0.f);
        } else if (slot == 3) {
            int ix = X0 + 16;
            sIn2[py][17][ci] = (rowok && ix < 256) ? src[(iy << 8) + ix] : f2bf(0.f);
        } else {
            int px0 = (slot == 1) ? 1 : 9;
            if (rowok) {
                uint4 v = *(const uint4*)&src[(iy << 8) + X0 - 1 + px0];
                const bf* pv = (const bf*)&v;
                #pragma unroll
                for (int j = 0; j < 8; ++j) sIn2[py][px0 + j][ci] = pv[j];
            } else {
                #pragma unroll
                for (int j = 0; j < 8; ++j) sIn2[py][px0 + j][ci] = f2bf(0.f);
            }
        }
    }
    __syncthreads();

    f4v acc[4];
    #pragma unroll
    for (int g = 0; g < 4; ++g) acc[g] = (f4v){0.f, 0.f, 0.f, 0.f};

    int prow0 = wave * 4;
    #pragma unroll
    for (int s = 0; s < NM; ++s) {
        bf8v wf = *(const bf8v*)&sWt[mcol][s * 32 + q * 8];
        int tap, ciofs;
        if (CI == 32) { tap = s;               ciofs = q * 8; }
        else          { tap = 2 * s + (q >> 1); if (tap > 8) tap = 8;
                        ciofs = (q & 1) * 8; }
        int ay = tap / 3, ax = tap - ay * 3;
        #pragma unroll
        for (int g = 0; g < 4; ++g) {
            bf8v af = *(const bf8v*)&sIn2[prow0 + g + ay][mcol + ax][ciofs];
            acc[g] = __builtin_amdgcn_mfma_f32_16x16x32_bf16(af, wf, acc[g], 0, 0, 0);
        }
    }

    float bs = Bias[mcol];
    bf* dst = out + ((size_t)(n * 16 + mcol) << 16);
    #pragma unroll
    for (int g = 0; g < 4; ++g) {
        int oy = Y0 + prow0 + g, ox = X0 + q * 4;
        uint2 pk;
        pk.x = packbf(fmaxf(acc[g][0] + bs, 0.f), fmaxf(acc[g][1] + bs, 0.f));
        pk.y = packbf(fmaxf(acc[g][2] + bs, 0.f), fmaxf(acc[g][3] + bs, 0.f));
        *(uint2*)(dst + (oy << 8) + ox) = pk;
    }
}

// ===========================================================================
// MFMA phase-decomposed transposed conv: r23 contiguous A-reads, r24
// vectorized input staging, r26 prepacked weights, r29 XCD swizzle.
// ===========================================================================
#define CVT_CHAIN(PH, KOFF, AY, AX)                                           \
    {                                                                          \
        bf8v wf = *(const bf8v*)&sWt[mcol][(KOFF) + q * 8];                    \
        _Pragma("unroll")                                                      \
        for (int g = 0; g < 4; ++g) {                                          \
            bf8v af = *(const bf8v*)&sIn2[prow0 + g + (AY)][mcol + (AX)][q * 8];\
            acc[PH][g] = __builtin_amdgcn_mfma_f32_16x16x32_bf16(af, wf,       \
                                                      acc[PH][g], 0, 0, 0);    \
        }                                                                      \
    }

template <int CITOT, int CIA>
__global__ __launch_bounds__(256)
void convt_mfma(const bf* __restrict__ inA, const bf* __restrict__ inB,
                const bf* __restrict__ pW, const float* __restrict__ Bias,
                bf* __restrict__ out,
                int N, int Hi, int Wi, int Cotot, int Ho, int Wo, int tilesX)
{
    constexpr int NCH = CITOT / 32;
    __shared__ __align__(16) bf sIn2[17][18][40];  // [py][px][ci pad40] 24.5KB
    __shared__ __align__(16) bf sWt[16][328];      // phase bases 0,40,112,184

    int swz = xcd_swizzle_lin();
    int tile = swz % gridDim.x;
    int rest = swz / gridDim.x;
    int n = rest % gridDim.y;
    int cog = rest / gridDim.y;

    int J0 = (tile % tilesX) * 16, I0 = (tile / tilesX) * 16;
    int t = threadIdx.x;
    int lane = t & 63, wave = t >> 6;
    int q = lane >> 4, mcol = lane & 15;
    int prow0 = wave * 4;

    f4v acc[4][4];
    #pragma unroll
    for (int p = 0; p < 4; ++p)
        #pragma unroll
        for (int g = 0; g < 4; ++g) acc[p][g] = (f4v){0.f, 0.f, 0.f, 0.f};

    for (int cb = 0; cb < NCH; ++cb) {
        if (cb) __syncthreads();                  // drain reads before restage
        for (int e = t; e < 32 * 51; e += 256) {  // 51 = 17 rows * 3 segs
            int ci = e / 51, rem = e % 51;
            int py = rem / 3, seg = rem % 3;
            int gci = cb * 32 + ci;
            const bf* src = (gci < CIA)
                ? inA + (size_t)(n * CIA + gci) * Hi * Wi
                : inB + (size_t)(n * (CITOT - CIA) + gci - CIA) * Hi * Wi;
            int iy = I0 + py;
            if (seg < 2) {
                int px0 = seg * 8;
                if (iy < Hi) {
                    uint4 v = *(const uint4*)&src[(size_t)iy * Wi + J0 + px0];
                    const bf* pv = (const bf*)&v;
                    #pragma unroll
                    for (int j = 0; j < 8; ++j) sIn2[py][px0 + j][ci] = pv[j];
                } else {
                    #pragma unroll
                    for (int j = 0; j < 8; ++j) sIn2[py][px0 + j][ci] = f2bf(0.f);
                }
            } else {
                int ix = J0 + 16;
                sIn2[py][16][ci] = (iy < Hi && ix < Wi)
                                   ? src[(size_t)iy * Wi + ix] : f2bf(0.f);
                sIn2[py][17][ci] = f2bf(0.f);
            }
        }
        // weights: contiguous copy of the (cog, cb) prepacked image
        {
            const uint4* wsrc = (const uint4*)(pW
                + ((size_t)cog * NCH + cb) * 16 * 328);
            for (int e = t; e < 656; e += 256)     // 16*328/8
                ((uint4*)sWt)[e] = wsrc[e];
        }
        __syncthreads();

        //        PH  KOFF AY AX      (chain = one tap over 32 channels)
        CVT_CHAIN(0,   0, 0, 0)    // phase (ry0,rx0): tap (1,1)
        CVT_CHAIN(1,  40, 0, 0)    // phase (ry0,rx1): tap kx=0
        CVT_CHAIN(1,  72, 0, 1)    //                  tap kx=2
        CVT_CHAIN(2, 112, 0, 0)    // phase (ry1,rx0): tap ky=0
        CVT_CHAIN(2, 144, 1, 0)    //                  tap ky=2
        CVT_CHAIN(3, 184, 0, 0)    // phase (ry1,rx1): tap (0,0)
        CVT_CHAIN(3, 216, 0, 1)    //                  tap (0,2)
        CVT_CHAIN(3, 248, 1, 0)    //                  tap (2,0)
        CVT_CHAIN(3, 280, 1, 1)    //                  tap (2,2)
    }

    float bs = Bias[cog * 16 + mcol];
    bf* dst = out + (size_t)(n * Cotot + cog * 16 + mcol) * Ho * Wo;
    #pragma unroll
    for (int ph = 0; ph < 4; ++ph) {
        const int ry = ph >> 1, rx = ph & 1;
        #pragma unroll
        for (int g = 0; g < 4; ++g) {
            int oy = 2 * (I0 + prow0 + g) + ry;
            #pragma unroll
            for (int jj = 0; jj < 4; ++jj) {
                int ox = 2 * (J0 + q * 4 + jj) + rx;
                dst[(size_t)oy * Wo + ox] = f2bf(fmaxf(acc[ph][g][jj] + bs, 0.f));
            }
        }
    }
}

// ===========================================================================
// MFMA Gram partials (verified round 20).
// ===========================================================================
__global__ __launch_bounds__(256)
void sim_partial(const bf* __restrict__ f, float* __restrict__ part, int KTOT)
{
    __shared__ __align__(16) bf tile[32][264];
    int c = blockIdx.x;
    int t = threadIdx.x;
    int k0 = c << 8;

    for (int e = t; e < 1024; e += 256) {
        int row = e >> 5, col8 = (e & 31) * 8;
        uint4 v = *(const uint4*)&f[(size_t)row * KTOT + k0 + col8];
        *(uint4*)&tile[row][col8] = v;
    }
    __syncthreads();

    int lane = t & 63, wave = t >> 6;
    int q = lane >> 4, mcol = lane & 15;
    int qr = wave >> 1, qc = wave & 1;

    f4v acc = (f4v){0.f, 0.f, 0.f, 0.f};
    #pragma unroll
    for (int ks = 0; ks < 8; ++ks) {
        bf8v a = *(const bf8v*)&tile[qr * 16 + mcol][ks * 32 + q * 8];
        bf8v b = *(const bf8v*)&tile[qc * 16 + mcol][ks * 32 + q * 8];
        acc = __builtin_amdgcn_mfma_f32_16x16x32_bf16(a, b, acc, 0, 0, 0);
    }

    float* dst = part + (size_t)c * 1024;
    #pragma unroll
    for (int jj = 0; jj < 4; ++jj) {
        int i = qr * 16 + q * 4 + jj;
        int j = qc * 16 + mcol;
        dst[i * 32 + j] = acc[jj];
    }
}

__global__ __launch_bounds__(256)
void sim_reduce(const float* __restrict__ part, float* __restrict__ sim, int nchunks)
{
    __shared__ float red[256];
    int pair = blockIdx.x;
    int t = threadIdx.x;
    float s = 0.f;
    for (int k = t; k < nchunks; k += 256)
        s += part[(size_t)k * 1024 + pair];
    red[t] = s;
    __syncthreads();
    #pragma unroll
    for (int off = 128; off > 0; off >>= 1) {
        if (t < off) red[t] += red[t + off];
        __syncthreads();
    }
    if (t == 0) sim[pair] = red[0];
}

// ===========================================================================
// Cosine sim + group mask + top-3 (strict >, lowest index wins ties).
// ===========================================================================
__global__ void topk_kernel(const float* __restrict__ sim, const int* __restrict__ prange,
                            int* __restrict__ idx, int N)
{
    int i = threadIdx.x;
    if (i >= N) return;
    float nm_i = fmaxf(sqrtf(sim[i * N + i]), 1e-8f);
    int p0 = prange[0], p1 = prange[1];
    int gi = (i >= p0) + (i >= p1);
    float vals[32];
    for (int j = 0; j < N; ++j) {
        int gj = (j >= p0) + (j >= p1);
        if (j == i || gj != gi) { vals[j] = -1e30f; continue; }
        float nm_j = fmaxf(sqrtf(sim[j * N + j]), 1e-8f);
        vals[j] = sim[i * N + j] / (nm_i * nm_j);
    }
    for (int k = 0; k < 3; ++k) {
        float best = -2e30f; int bj = 0;
        for (int j = 0; j < N; ++j)
            if (vals[j] > best) { best = vals[j]; bj = j; }
        idx[i * 3 + k] = bj;
        vals[bj] = -1e30f;
    }
}

// ===========================================================================
// Gather-mean: agg[n] = (ga[i0] + ga[i1] + ga[i2]) / 3.
// ===========================================================================
__global__ __launch_bounds__(256)
void gather_mean(const bf* __restrict__ ga, const int* __restrict__ idx,
                 bf* __restrict__ agg)
{
    int n = blockIdx.y;
    int v = blockIdx.x * 256 + threadIdx.x;
    int i0 = idx[n * 3 + 0], i1 = idx[n * 3 + 1], i2 = idx[n * 3 + 2];
    const size_t stride = (size_t)16 << 16;
    const uint4* p0 = (const uint4*)(ga + stride * i0) + v;
    const uint4* p1 = (const uint4*)(ga + stride * i1) + v;
    const uint4* p2 = (const uint4*)(ga + stride * i2) + v;
    uint4 a = *p0, b = *p1, c = *p2;
    uint4 r;
    unsigned* ap = (unsigned*)&a; unsigned* bp = (unsigned*)&b;
    unsigned* cp = (unsigned*)&c; unsigned* rp = (unsigned*)&r;
    #pragma unroll
    for (int w = 0; w < 4; ++w) {
        float fa0 = __bfloat162float((__hip_bfloat16_raw){(unsigned short)(ap[w] & 0xffff)});
        float fb0 = __bfloat162float((__hip_bfloat16_raw){(unsigned short)(bp[w] & 0xffff)});
        float fc0 = __bfloat162float((__hip_bfloat16_raw){(unsigned short)(cp[w] & 0xffff)});
        float fa1 = __bfloat162float((__hip_bfloat16_raw){(unsigned short)(ap[w] >> 16)});
        float fb1 = __bfloat162float((__hip_bfloat16_raw){(unsigned short)(bp[w] >> 16)});
        float fc1 = __bfloat162float((__hip_bfloat16_raw){(unsigned short)(cp[w] >> 16)});
        rp[w] = packbf((fa0 + fb0 + fc0) * (1.f / 3.f),
                       (fa1 + fb1 + fc1) * (1.f / 3.f));
    }
    *((uint4*)(agg + stride * n) + v) = r;
}

// ===========================================================================
// Light head: gnn (bf16) + d1 recompute + dense 32->2 + softmax.
// ===========================================================================
__global__ __launch_bounds__(256)
void head_tiled(const float* __restrict__ cts, const bf* __restrict__ gnn,
                const float* __restrict__ w_d1, const float* __restrict__ b_d1,
                const float* __restrict__ w_de, const float* __restrict__ b_de,
                float* __restrict__ out, int N)
{
    __shared__ float sCts[18][19];
    __shared__ float sWd1[144];
    __shared__ float sB1[16];
    __shared__ float sDe[64];

    int tile = blockIdx.x;
    int X0 = (tile & 15) * 16, Y0 = (tile >> 4) * 16;
    int n = blockIdx.y;
    int t = threadIdx.x, tx = t & 15, ty = t >> 4;

    for (int e = t; e < 18 * 18; e += 256) {
        int py = e / 18, px = e % 18;
        int iy = Y0 - 1 + py, ix = X0 - 1 + px;
        sCts[py][px] = ((unsigned)iy < 256u && (unsigned)ix < 256u)
                       ? cts[((size_t)n << 16) + (iy << 8) + ix] : 0.f;
    }
    if (t < 144) sWd1[t] = w_d1[t];
    else if (t < 160) sB1[t - 144] = b_d1[t - 144];
    else if (t >= 192 && t < 256) sDe[t - 192] = w_de[t - 192];
    __syncthreads();

    int pix = ((Y0 + ty) << 8) + X0 + tx;
    float l0 = b_de[0], l1 = b_de[1];

    #pragma unroll
    for (int c = 0; c < 16; ++c) {
        float v = bf2f(gnn[((size_t)(n * 16 + c) << 16) + pix]);
        l0 = fmaf(v, sDe[c * 2 + 0], l0);
        l1 = fmaf(v, sDe[c * 2 + 1], l1);
    }

    float ct[3][3];
    #pragma unroll
    for (int a = 0; a < 3; ++a)
        #pragma unroll
        for (int b = 0; b < 3; ++b)
            ct[a][b] = sCts[ty + a][tx + b];
    #pragma unroll
    for (int c = 0; c < 16; ++c) {
        float a1 = sB1[c];
        #pragma unroll
        for (int t9 = 0; t9 < 9; ++t9)
            a1 = fmaf(ct[t9 / 3][t9 % 3], sWd1[c * 9 + t9], a1);
        float v = fmaxf(a1, 0.f);
        l0 = fmaf(v, sDe[(16 + c) * 2 + 0], l0);
        l1 = fmaf(v, sDe[(16 + c) * 2 + 1], l1);
    }

    float m = fmaxf(l0, l1);
    float e0 = expf(l0 - m), e1 = expf(l1 - m);
    float inv = 1.f / (e0 + e1);
    size_t base = ((size_t)n * 2) << 16;
    out[base + pix] = e0 * inv;
    out[base + 65536 + pix] = e1 * inv;
}

// ===========================================================================

extern "C" void kernel_launch(void* const* d_in, const int* in_sizes, int n_in,
                              void* d_out, int out_size, void* d_ws, size_t ws_size,
                              hipStream_t stream)
{
    const float* cts  = (const float*)d_in[0];
    const int*   prng = (const int*)d_in[1];
    const float* w_d1 = (const float*)d_in[2];  const float* b_d1 = (const float*)d_in[3];
    const float* w_d2 = (const float*)d_in[4];  const float* b_d2 = (const float*)d_in[5];
    const float* w_d3 = (const float*)d_in[6];  const float* b_d3 = (const float*)d_in[7];
    const float* w_d4 = (const float*)d_in[8];  const float* b_d4 = (const float*)d_in[9];
    const float* w_u1 = (const float*)d_in[10]; const float* b_u1 = (const float*)d_in[11];
    const float* w_u2 = (const float*)d_in[12]; const float* b_u2 = (const float*)d_in[13];
    const float* w_u3 = (const float*)d_in[14]; const float* b_u3 = (const float*)d_in[15];
    const float* w_ga = (const float*)d_in[16]; const float* b_ga = (const float*)d_in[17];
    const float* w_gu = (const float*)d_in[18]; const float* b_gu = (const float*)d_in[19];
    const float* w_de = (const float*)d_in[20]; const float* b_de = (const float*)d_in[21];

    const int H = 256, Wd = 256;
    const int N = in_sizes[0] / (H * Wd);   // 32

    // ---- workspace layout (192 MiB total), lifetime reuse ----
    // u3 [0,64M); R1 [64M,128M): d1 -> u1/u2 -> ga/gnn (spans the FULL 64MB);
    // R2 [128M,184M): d2/d3/d4 -> simp/sim -> agg.
    // FREE window: [184M,192M) — prepacked weights live here (~287KB).
    char* wsb = (char*)d_ws;
    bf* u3 = (bf*)(wsb);
    bf* R1 = (bf*)(wsb + 67108864);

    bf* d1 = R1;
    bf* d2 = (bf*)(wsb + 134217728);
    bf* d3 = (bf*)(wsb + 134217728 + 33554432);
    bf* d4 = (bf*)(wsb + 134217728 + 50331648);
    bf* u1 = R1;
    bf* u2 = (bf*)(wsb + 67108864 + 16777216);
    bf* ga = R1;
    bf* gnn = R1;
    bf* agg = (bf*)(wsb + 134217728);
    float* simp = (float*)(wsb + 134217728);
    float* sim  = (float*)(wsb + 134217728 + 16777216);
    int*   idx  = (int*)d_out + (out_size - 96);

    // prepacked weight images in the dead window @ 184 MiB
    bf* pwu1 = (bf*)(wsb + 192937984);               // 16 pairs * 10496B
    bf* pwu2 = (bf*)(wsb + 192937984 + 167936);      //  8 pairs
    bf* pwu3 = (bf*)(wsb + 192937984 + 251904);      //  2 pairs
    bf* pwga = (bf*)(wsb + 192937984 + 272896);      // 16x160
    bf* pwgn = (bf*)(wsb + 192937984 + 278016);      // 16x288

    const int KTOT = 16 * H * Wd;
    const int NCH  = KTOT / 256;            // 4096 chunks

    // one-time weight repack (tiny)
    prep_wt_convt<<<16, 256, 0, stream>>>(w_u1, pwu1, 128, 4);
    prep_wt_convt<<<8,  256, 0, stream>>>(w_u2, pwu2, 128, 4);
    prep_wt_convt<<<2,  256, 0, stream>>>(w_u3, pwu3, 64, 2);
    prep_wt_conv<<<1,   256, 0, stream>>>(w_ga, pwga, 16, 160);
    prep_wt_conv<<<1,   256, 0, stream>>>(w_gu, pwgn, 32, 288);

    // encoder
    conv32<float><<<dim3(64, N), 256, 0, stream>>>(cts, cts, 1, 1, w_d1, b_d1, d1, N);
    conv_tiled<<<dim3(64, N, 2), 256, 0, stream>>>(
        d1, (const bf*)nullptr, 16, 16, w_d2, b_d2, d2, N, 256, 256, 32, 128, 128, 8);
    conv_tiled<<<dim3(16, N, 4), 256, 0, stream>>>(
        d2, (const bf*)nullptr, 32, 32, w_d3, b_d3, d3, N, 128, 128, 64, 64, 64, 4);
    conv_tiled<<<dim3(4, N, 8), 256, 0, stream>>>(
        d3, (const bf*)nullptr, 64, 64, w_d4, b_d4, d4, N, 64, 64, 128, 32, 32, 2);
    // decoder (all transposed convs via MFMA, prepacked weights)
    convt_mfma<128, 128><<<dim3(4, N, 4), 256, 0, stream>>>(
        d4, d4, pwu1, b_u1, u1, N, 32, 32, 64, 64, 64, 2);
    convt_mfma<128, 64><<<dim3(16, N, 2), 256, 0, stream>>>(
        u1, d3, pwu2, b_u2, u2, N, 64, 64, 32, 128, 128, 4);
    convt_mfma<64, 32><<<dim3(64, N, 1), 256, 0, stream>>>(
        u2, d2, pwu3, b_u3, u3, N, 128, 128, 16, 256, 256, 8);
    // cosine similarity + top-3 (Gram via MFMA)
    sim_partial<<<NCH, 256, 0, stream>>>(u3, simp, KTOT);
    sim_reduce<<<dim3(N * N), 256, 0, stream>>>(simp, sim, NCH);
    topk_kernel<<<1, 64, 0, stream>>>(sim, prng, idx, N);
    // per-slice gnn-neighbor conv (MFMA), then gather-mean
    conv_mfma<16, 20, 160><<<dim3(256, N), 256, 0, stream>>>(
        u3, u3, 16, pwga, b_ga, ga, N);
    gather_mean<<<dim3(512, N), 256, 0, stream>>>(ga, idx, agg);
    // gnn conv (MFMA, 32ch from u3|agg) then light head
    conv_mfma<32, 40, 288><<<dim3(256, N), 256, 0, stream>>>(
        u3, agg, 16, pwgn, b_gu, gnn, N);
    head_tiled<<<dim3(256, N), 256, 0, stream>>>(
        cts, gnn, w_d1, b_d1, w_de, b_de, (float*)d_out, N);
}

// Round 30
// 748.058 us; speedup vs baseline: 2.4546x; 1.2208x over previous
//
#include <hip/hip_runtime.h>
#include <hip/hip_bf16.h>
#include <math.h>

typedef __hip_bfloat16 bf;
typedef __attribute__((ext_vector_type(8))) short bf8v;   // 8 bf16 = 4 VGPR
typedef __attribute__((ext_vector_type(4))) float f4v;

__device__ __forceinline__ float bf2f(bf v) { return __bfloat162float(v); }
__device__ __forceinline__ bf f2bf(float v) { return __float2bfloat16(v); }
__device__ __forceinline__ unsigned packbf(float a, float b) {
    __hip_bfloat16_raw ra = (__hip_bfloat16_raw)__float2bfloat16(a);
    __hip_bfloat16_raw rb = (__hip_bfloat16_raw)__float2bfloat16(b);
    return (unsigned)ra.x | ((unsigned)rb.x << 16);
}

// XCD-aware bijective work swizzle (requires total % 8 == 0).
__device__ __forceinline__ int xcd_swizzle_lin()
{
    int total = gridDim.x * gridDim.y * gridDim.z;
    int lin = blockIdx.x + gridDim.x * (blockIdx.y + gridDim.y * blockIdx.z);
    return (lin & 7) * (total >> 3) + (lin >> 3);
}

// ===========================================================================
// Weight prep kernels (one-time per launch).
// ===========================================================================
__global__ __launch_bounds__(256)
void prep_wt_convt(const float* __restrict__ Wt, bf* __restrict__ outp,
                   int CITOT, int NCH)
{
    int pair = blockIdx.x;                 // cog * NCH + cb
    int cog = pair / NCH, cb = pair % NCH;
    int t = threadIdx.x;
    bf* dst = outp + (size_t)pair * 16 * 328;
    for (int e = t; e < 16 * 288; e += 256) {
        int co = e / 288, rem = e % 288;
        int cic = rem / 9, t9 = rem % 9;
        int ky = t9 / 3, kx = t9 % 3;
        int ry = (ky == 1) ? 0 : 1;
        int rx = (kx == 1) ? 0 : 1;
        int ty = (ky == 1) ? 0 : (ky >> 1);
        int txi = (kx == 1) ? 0 : (kx >> 1);
        int ntx = 1 + rx;
        int ph = ry * 2 + rx;
        const int base4[4] = {0, 40, 112, 184};
        int kl = (ty * ntx + txi) * 32 + cic;     // cic-minor k order
        dst[co * 328 + base4[ph] + kl] =
            f2bf(Wt[(size_t)(cog * 16 + co) * CITOT * 9
                    + (size_t)(cb * 32 + cic) * 9 + t9]);
    }
}

__global__ __launch_bounds__(256)
void prep_wt_conv(const float* __restrict__ Wt, bf* __restrict__ outp,
                  int CI, int KPAD)
{
    int t = threadIdx.x;
    int K = CI * 9;
    for (int e = t; e < 16 * KPAD; e += 256) {
        int co = e / KPAD, k = e % KPAD;
        int tap = k / CI, ci = k % CI;
        outp[co * KPAD + k] = (k < K)
            ? f2bf(Wt[(size_t)co * K + ci * 9 + tap]) : f2bf(0.f);
    }
}

// stride-2 conv weights: per-(cog, cb16) 16x160 images, kl = tap*16 + ci.
__global__ __launch_bounds__(256)
void prep_wt_conv2s(const float* __restrict__ Wt, bf* __restrict__ outp,
                    int CITOT, int NCH)
{
    int pair = blockIdx.x;                 // cog * NCH + cb
    int cog = pair / NCH, cb = pair % NCH;
    int t = threadIdx.x;
    bf* dst = outp + (size_t)pair * 16 * 160;
    for (int e = t; e < 16 * 160; e += 256) {
        int co = e / 160, k = e % 160;
        int tap = k / 16, ci = k % 16;
        dst[e] = (k < 144)
            ? f2bf(Wt[(size_t)(cog * 16 + co) * CITOT * 9
                      + (size_t)(cb * 16 + ci) * 9 + tap])
            : f2bf(0.f);
    }
}

// ===========================================================================
// MFMA stride-2 conv (d2,d3,d4). 16x16 out tile per block; ci chunked by 16
// (K=144 pad 160, ga-path chain mapping verified r24); A-fragment reads at
// input stride 2: sIn2[2*(prow0+g)+ay][2*mcol+ax][ciofs]. r25 vectorized
// staging (33x33 tile), r26 prepacked weights, r29 XCD swizzle.
// ===========================================================================
template <int CITOT>
__global__ __launch_bounds__(256)
void conv2s_mfma(const bf* __restrict__ in, const bf* __restrict__ pW,
                 const float* __restrict__ Bias, bf* __restrict__ out,
                 int N, int Hi, int Wi, int Cotot, int Ho, int Wo, int tilesX)
{
    constexpr int NCH = CITOT / 16;
    __shared__ __align__(16) bf sIn2[33][33][18];  // [py][px][ci pad18] 39.2KB
    __shared__ __align__(16) bf sWt[16][160];      // 5KB

    int swz = xcd_swizzle_lin();
    int tile = swz % gridDim.x;
    int rest = swz / gridDim.x;
    int n = rest % gridDim.y;
    int cog = rest / gridDim.y;

    int X0 = (tile % tilesX) * 16, Y0 = (tile / tilesX) * 16;  // output coords
    int t = threadIdx.x;
    int lane = t & 63, wave = t >> 6;
    int q = lane >> 4, mcol = lane & 15;
    int prow0 = wave * 4;

    f4v acc[4];
    #pragma unroll
    for (int g = 0; g < 4; ++g) acc[g] = (f4v){0.f, 0.f, 0.f, 0.f};

    for (int cb = 0; cb < NCH; ++cb) {
        if (cb) __syncthreads();                  // drain reads before restage
        // input: 16 ci x 33 rows x {1 scalar + 4 vec8} segments
        for (int e = t; e < 16 * 165; e += 256) {
            int ci = e / 165, rem = e % 165;
            int py = rem / 5, seg = rem % 5;
            const bf* src = in + (size_t)(n * CITOT + cb * 16 + ci) * Hi * Wi;
            int iy = 2 * Y0 - 1 + py;
            bool rowok = (iy >= 0);               // iy < Hi always holds
            if (seg == 0) {
                int ix = 2 * X0 - 1;
                sIn2[py][0][ci] = (rowok && ix >= 0)
                                  ? src[(size_t)iy * Wi + ix] : f2bf(0.f);
            } else {
                int px0 = 1 + 8 * (seg - 1);       // 1, 9, 17, 25
                int ix0 = 2 * X0 + 8 * (seg - 1);  // in-bounds, 16B-aligned
                if (rowok) {
                    uint4 v = *(const uint4*)&src[(size_t)iy * Wi + ix0];
                    const bf* pv = (const bf*)&v;
                    #pragma unroll
                    for (int j = 0; j < 8; ++j) sIn2[py][px0 + j][ci] = pv[j];
                } else {
                    #pragma unroll
                    for (int j = 0; j < 8; ++j) sIn2[py][px0 + j][ci] = f2bf(0.f);
                }
            }
        }
        // weights: contiguous copy of the (cog, cb) prepacked 16x160 image
        {
            const uint4* wsrc = (const uint4*)(pW
                + ((size_t)cog * NCH + cb) * 16 * 160);
            for (int e = t; e < 320; e += 256)     // 16*160/8
                ((uint4*)sWt)[e] = wsrc[e];
        }
        __syncthreads();

        #pragma unroll
        for (int s = 0; s < 5; ++s) {
            bf8v wf = *(const bf8v*)&sWt[mcol][s * 32 + q * 8];
            int tap = 2 * s + (q >> 1); if (tap > 8) tap = 8;  // pad weights=0
            int ciofs = (q & 1) * 8;
            int ay = tap / 3, ax = tap - ay * 3;
            #pragma unroll
            for (int g = 0; g < 4; ++g) {
                bf8v af = *(const bf8v*)
                    &sIn2[2 * (prow0 + g) + ay][2 * mcol + ax][ciofs];
                acc[g] = __builtin_amdgcn_mfma_f32_16x16x32_bf16(af, wf,
                                                                 acc[g], 0, 0, 0);
            }
        }
    }

    float bs = Bias[cog * 16 + mcol];
    bf* dst = out + (size_t)(n * Cotot + cog * 16 + mcol) * Ho * Wo;
    #pragma unroll
    for (int g = 0; g < 4; ++g) {
        int oy = Y0 + prow0 + g, ox = X0 + q * 4;
        uint2 pk;
        pk.x = packbf(fmaxf(acc[g][0] + bs, 0.f), fmaxf(acc[g][1] + bs, 0.f));
        pk.y = packbf(fmaxf(acc[g][2] + bs, 0.f), fmaxf(acc[g][3] + bs, 0.f));
        *(uint2*)(dst + (size_t)oy * Wo + ox) = pk;
    }
}

// ===========================================================================
// Stride-1 conv (d1 only, Ci=1). 32x32 tile, 2x2 px/thread.
// ===========================================================================
template <typename TIN>
__global__ __launch_bounds__(256)
void conv32(const TIN* __restrict__ inA, const TIN* __restrict__ inB,
            int CiA, int Ci,
            const float* __restrict__ Wt, const float* __restrict__ Bias,
            bf* __restrict__ out, int N)
{
    constexpr int CHUNK = 4;
    __shared__ float sIn[CHUNK][34][35];
    __shared__ __align__(16) float sW[CHUNK][9][16];

    int tile = blockIdx.x;
    int X0 = (tile & 7) * 32, Y0 = (tile >> 3) * 32;
    int n = blockIdx.y;
    int t = threadIdx.x, tx = t & 15, ty = t >> 4;
    int CiB = Ci - CiA;

    float acc[4][16];
    #pragma unroll
    for (int p = 0; p < 4; ++p)
        #pragma unroll
        for (int c = 0; c < 16; ++c) acc[p][c] = 0.f;

    for (int cb = 0; cb < Ci; cb += CHUNK) {
        int cn = (Ci - cb < CHUNK) ? Ci - cb : CHUNK;
        for (int e = t; e < cn * 1156; e += 256) {
            int ci = e / 1156, rem = e % 1156;
            int py = rem / 34, px = rem % 34;
            int iy = Y0 - 1 + py, ix = X0 - 1 + px;
            int gci = cb + ci;
            const TIN* src = (gci < CiA)
                ? inA + ((size_t)(n * CiA + gci) << 16)
                : inB + ((size_t)(n * CiB + gci - CiA) << 16);
            sIn[ci][py][px] = ((unsigned)iy < 256u && (unsigned)ix < 256u)
                              ? (float)src[(iy << 8) + ix] : 0.f;
        }
        for (int e = t; e < cn * 144; e += 256) {
            int ci = e / 144, rem = e % 144;
            int t9 = rem / 16, co = rem % 16;
            sW[ci][t9][co] = Wt[(size_t)co * Ci * 9 + (cb + ci) * 9 + t9];
        }
        __syncthreads();
        for (int ci = 0; ci < cn; ++ci) {
            float rin[4][4];
            #pragma unroll
            for (int a = 0; a < 4; ++a)
                #pragma unroll
                for (int b = 0; b < 4; ++b)
                    rin[a][b] = sIn[ci][2 * ty + a][2 * tx + b];
            #pragma unroll
            for (int t9 = 0; t9 < 9; ++t9) {
                const int ky = t9 / 3, kx = t9 % 3;
                float w[16];
                #pragma unroll
                for (int q = 0; q < 4; ++q)
                    *(float4*)&w[q * 4] = *(const float4*)&sW[ci][t9][q * 4];
                #pragma unroll
                for (int ry = 0; ry < 2; ++ry)
                    #pragma unroll
                    for (int rx = 0; rx < 2; ++rx) {
                        float v = rin[ry + ky][rx + kx];
                        #pragma unroll
                        for (int co = 0; co < 16; ++co)
                            acc[ry * 2 + rx][co] = fmaf(v, w[co], acc[ry * 2 + rx][co]);
                    }
            }
        }
        __syncthreads();
    }

    #pragma unroll
    for (int co = 0; co < 16; ++co) {
        float bs = Bias[co];
        bf* dst = out + ((size_t)(n * 16 + co) << 16);
        #pragma unroll
        for (int ry = 0; ry < 2; ++ry) {
            unsigned pk = packbf(fmaxf(acc[ry * 2 + 0][co] + bs, 0.f),
                                 fmaxf(acc[ry * 2 + 1][co] + bs, 0.f));
            *(unsigned*)(dst + ((Y0 + 2 * ty + ry) << 8) + X0 + 2 * tx) = pk;
        }
    }
}

// ===========================================================================
// MFMA implicit-GEMM stride-1 conv (ga, gnn).
// ===========================================================================
template <int CI, int CIP, int KPAD>
__global__ __launch_bounds__(256)
void conv_mfma(const bf* __restrict__ inA, const bf* __restrict__ inB,
               int CiA, const bf* __restrict__ pW,
               const float* __restrict__ Bias,
               bf* __restrict__ out, int N)
{
    constexpr int NM = KPAD / 32;
    __shared__ __align__(16) bf sIn2[18][19][CIP];
    __shared__ __align__(16) bf sWt[16][KPAD];

    int swz = xcd_swizzle_lin();           // gridDim.x == 256 always
    int tile = swz & 255;
    int n = swz >> 8;

    int X0 = (tile & 15) * 16, Y0 = (tile >> 4) * 16;
    int t = threadIdx.x;
    int lane = t & 63, wave = t >> 6;
    int q = lane >> 4, mcol = lane & 15;
    int CiB = CI - CiA;

    // weights: contiguous copy of prepacked image
    for (int e = t; e < 16 * KPAD / 8; e += 256)
        ((uint4*)sWt)[e] = ((const uint4*)pW)[e];
    // input: channel-minor [py][px][ci]; vectorized global reads
    for (int e = t; e < CI * 72; e += 256) {       // 18 rows x 4 slots
        int ci = e / 72, rem = e % 72;
        int py = rem / 4, slot = rem % 4;
        const bf* src = (ci < CiA)
            ? inA + ((size_t)(n * CiA + ci) << 16)
            : inB + ((size_t)(n * CiB + ci - CiA) << 16);
        int iy = Y0 - 1 + py;
        bool rowok = ((unsigned)iy < 256u);
        if (slot == 0) {
            int ix = X0 - 1;
            sIn2[py][0][ci] = (rowok && ix >= 0) ? src[(iy << 8) + ix] : f2bf(0.f);
        } else if (slot == 3) {
            int ix = X0 + 16;
            sIn2[py][17][ci] = (rowok && ix < 256) ? src[(iy << 8) + ix] : f2bf(0.f);
        } else {
            int px0 = (slot == 1) ? 1 : 9;
            if (rowok) {
                uint4 v = *(const uint4*)&src[(iy << 8) + X0 - 1 + px0];
                const bf* pv = (const bf*)&v;
                #pragma unroll
                for (int j = 0; j < 8; ++j) sIn2[py][px0 + j][ci] = pv[j];
            } else {
                #pragma unroll
                for (int j = 0; j < 8; ++j) sIn2[py][px0 + j][ci] = f2bf(0.f);
            }
        }
    }
    __syncthreads();

    f4v acc[4];
    #pragma unroll
    for (int g = 0; g < 4; ++g) acc[g] = (f4v){0.f, 0.f, 0.f, 0.f};

    int prow0 = wave * 4;
    #pragma unroll
    for (int s = 0; s < NM; ++s) {
        bf8v wf = *(const bf8v*)&sWt[mcol][s * 32 + q * 8];
        int tap, ciofs;
        if (CI == 32) { tap = s;               ciofs = q * 8; }
        else          { tap = 2 * s + (q >> 1); if (tap > 8) tap = 8;
                        ciofs = (q & 1) * 8; }
        int ay = tap / 3, ax = tap - ay * 3;
        #pragma unroll
        for (int g = 0; g < 4; ++g) {
            bf8v af = *(const bf8v*)&sIn2[prow0 + g + ay][mcol + ax][ciofs];
            acc[g] = __builtin_amdgcn_mfma_f32_16x16x32_bf16(af, wf, acc[g], 0, 0, 0);
        }
    }

    float bs = Bias[mcol];
    bf* dst = out + ((size_t)(n * 16 + mcol) << 16);
    #pragma unroll
    for (int g = 0; g < 4; ++g) {
        int oy = Y0 + prow0 + g, ox = X0 + q * 4;
        uint2 pk;
        pk.x = packbf(fmaxf(acc[g][0] + bs, 0.f), fmaxf(acc[g][1] + bs, 0.f));
        pk.y = packbf(fmaxf(acc[g][2] + bs, 0.f), fmaxf(acc[g][3] + bs, 0.f));
        *(uint2*)(dst + (oy << 8) + ox) = pk;
    }
}

// ===========================================================================
// MFMA phase-decomposed transposed conv (u1,u2,u3).
// ===========================================================================
#define CVT_CHAIN(PH, KOFF, AY, AX)                                           \
    {                                                                          \
        bf8v wf = *(const bf8v*)&sWt[mcol][(KOFF) + q * 8];                    \
        _Pragma("unroll")                                                      \
        for (int g = 0; g < 4; ++g) {                                          \
            bf8v af = *(const bf8v*)&sIn2[prow0 + g + (AY)][mcol + (AX)][q * 8];\
            acc[PH][g] = __builtin_amdgcn_mfma_f32_16x16x32_bf16(af, wf,       \
                                                      acc[PH][g], 0, 0, 0);    \
        }                                                                      \
    }

template <int CITOT, int CIA>
__global__ __launch_bounds__(256)
void convt_mfma(const bf* __restrict__ inA, const bf* __restrict__ inB,
                const bf* __restrict__ pW, const float* __restrict__ Bias,
                bf* __restrict__ out,
                int N, int Hi, int Wi, int Cotot, int Ho, int Wo, int tilesX)
{
    constexpr int NCH = CITOT / 32;
    __shared__ __align__(16) bf sIn2[17][18][40];  // [py][px][ci pad40] 24.5KB
    __shared__ __align__(16) bf sWt[16][328];      // phase bases 0,40,112,184

    int swz = xcd_swizzle_lin();
    int tile = swz % gridDim.x;
    int rest = swz / gridDim.x;
    int n = rest % gridDim.y;
    int cog = rest / gridDim.y;

    int J0 = (tile % tilesX) * 16, I0 = (tile / tilesX) * 16;
    int t = threadIdx.x;
    int lane = t & 63, wave = t >> 6;
    int q = lane >> 4, mcol = lane & 15;
    int prow0 = wave * 4;

    f4v acc[4][4];
    #pragma unroll
    for (int p = 0; p < 4; ++p)
        #pragma unroll
        for (int g = 0; g < 4; ++g) acc[p][g] = (f4v){0.f, 0.f, 0.f, 0.f};

    for (int cb = 0; cb < NCH; ++cb) {
        if (cb) __syncthreads();                  // drain reads before restage
        for (int e = t; e < 32 * 51; e += 256) {  // 51 = 17 rows * 3 segs
            int ci = e / 51, rem = e % 51;
            int py = rem / 3, seg = rem % 3;
            int gci = cb * 32 + ci;
            const bf* src = (gci < CIA)
                ? inA + (size_t)(n * CIA + gci) * Hi * Wi
                : inB + (size_t)(n * (CITOT - CIA) + gci - CIA) * Hi * Wi;
            int iy = I0 + py;
            if (seg < 2) {
                int px0 = seg * 8;
                if (iy < Hi) {
                    uint4 v = *(const uint4*)&src[(size_t)iy * Wi + J0 + px0];
                    const bf* pv = (const bf*)&v;
                    #pragma unroll
                    for (int j = 0; j < 8; ++j) sIn2[py][px0 + j][ci] = pv[j];
                } else {
                    #pragma unroll
                    for (int j = 0; j < 8; ++j) sIn2[py][px0 + j][ci] = f2bf(0.f);
                }
            } else {
                int ix = J0 + 16;
                sIn2[py][16][ci] = (iy < Hi && ix < Wi)
                                   ? src[(size_t)iy * Wi + ix] : f2bf(0.f);
                sIn2[py][17][ci] = f2bf(0.f);
            }
        }
        // weights: contiguous copy of the (cog, cb) prepacked image
        {
            const uint4* wsrc = (const uint4*)(pW
                + ((size_t)cog * NCH + cb) * 16 * 328);
            for (int e = t; e < 656; e += 256)     // 16*328/8
                ((uint4*)sWt)[e] = wsrc[e];
        }
        __syncthreads();

        //        PH  KOFF AY AX      (chain = one tap over 32 channels)
        CVT_CHAIN(0,   0, 0, 0)    // phase (ry0,rx0): tap (1,1)
        CVT_CHAIN(1,  40, 0, 0)    // phase (ry0,rx1): tap kx=0
        CVT_CHAIN(1,  72, 0, 1)    //                  tap kx=2
        CVT_CHAIN(2, 112, 0, 0)    // phase (ry1,rx0): tap ky=0
        CVT_CHAIN(2, 144, 1, 0)    //                  tap ky=2
        CVT_CHAIN(3, 184, 0, 0)    // phase (ry1,rx1): tap (0,0)
        CVT_CHAIN(3, 216, 0, 1)    //                  tap (0,2)
        CVT_CHAIN(3, 248, 1, 0)    //                  tap (2,0)
        CVT_CHAIN(3, 280, 1, 1)    //                  tap (2,2)
    }

    float bs = Bias[cog * 16 + mcol];
    bf* dst = out + (size_t)(n * Cotot + cog * 16 + mcol) * Ho * Wo;
    #pragma unroll
    for (int ph = 0; ph < 4; ++ph) {
        const int ry = ph >> 1, rx = ph & 1;
        #pragma unroll
        for (int g = 0; g < 4; ++g) {
            int oy = 2 * (I0 + prow0 + g) + ry;
            #pragma unroll
            for (int jj = 0; jj < 4; ++jj) {
                int ox = 2 * (J0 + q * 4 + jj) + rx;
                dst[(size_t)oy * Wo + ox] = f2bf(fmaxf(acc[ph][g][jj] + bs, 0.f));
            }
        }
    }
}

// ===========================================================================
// MFMA Gram partials (verified round 20).
// ===========================================================================
__global__ __launch_bounds__(256)
void sim_partial(const bf* __restrict__ f, float* __restrict__ part, int KTOT)
{
    __shared__ __align__(16) bf tile[32][264];
    int c = blockIdx.x;
    int t = threadIdx.x;
    int k0 = c << 8;

    for (int e = t; e < 1024; e += 256) {
        int row = e >> 5, col8 = (e & 31) * 8;
        uint4 v = *(const uint4*)&f[(size_t)row * KTOT + k0 + col8];
        *(uint4*)&tile[row][col8] = v;
    }
    __syncthreads();

    int lane = t & 63, wave = t >> 6;
    int q = lane >> 4, mcol = lane & 15;
    int qr = wave >> 1, qc = wave & 1;

    f4v acc = (f4v){0.f, 0.f, 0.f, 0.f};
    #pragma unroll
    for (int ks = 0; ks < 8; ++ks) {
        bf8v a = *(const bf8v*)&tile[qr * 16 + mcol][ks * 32 + q * 8];
        bf8v b = *(const bf8v*)&tile[qc * 16 + mcol][ks * 32 + q * 8];
        acc = __builtin_amdgcn_mfma_f32_16x16x32_bf16(a, b, acc, 0, 0, 0);
    }

    float* dst = part + (size_t)c * 1024;
    #pragma unroll
    for (int jj = 0; jj < 4; ++jj) {
        int i = qr * 16 + q * 4 + jj;
        int j = qc * 16 + mcol;
        dst[i * 32 + j] = acc[jj];
    }
}

__global__ __launch_bounds__(256)
void sim_reduce(const float* __restrict__ part, float* __restrict__ sim, int nchunks)
{
    __shared__ float red[256];
    int pair = blockIdx.x;
    int t = threadIdx.x;
    float s = 0.f;
    for (int k = t; k < nchunks; k += 256)
        s += part[(size_t)k * 1024 + pair];
    red[t] = s;
    __syncthreads();
    #pragma unroll
    for (int off = 128; off > 0; off >>= 1) {
        if (t < off) red[t] += red[t + off];
        __syncthreads();
    }
    if (t == 0) sim[pair] = red[0];
}

// ===========================================================================
// Cosine sim + group mask + top-3 (strict >, lowest index wins ties).
// ===========================================================================
__global__ void topk_kernel(const float* __restrict__ sim, const int* __restrict__ prange,
                            int* __restrict__ idx, int N)
{
    int i = threadIdx.x;
    if (i >= N) return;
    float nm_i = fmaxf(sqrtf(sim[i * N + i]), 1e-8f);
    int p0 = prange[0], p1 = prange[1];
    int gi = (i >= p0) + (i >= p1);
    float vals[32];
    for (int j = 0; j < N; ++j) {
        int gj = (j >= p0) + (j >= p1);
        if (j == i || gj != gi) { vals[j] = -1e30f; continue; }
        float nm_j = fmaxf(sqrtf(sim[j * N + j]), 1e-8f);
        vals[j] = sim[i * N + j] / (nm_i * nm_j);
    }
    for (int k = 0; k < 3; ++k) {
        float best = -2e30f; int bj = 0;
        for (int j = 0; j < N; ++j)
            if (vals[j] > best) { best = vals[j]; bj = j; }
        idx[i * 3 + k] = bj;
        vals[bj] = -1e30f;
    }
}

// ===========================================================================
// Gather-mean: agg[n] = (ga[i0] + ga[i1] + ga[i2]) / 3.
// ===========================================================================
__global__ __launch_bounds__(256)
void gather_mean(const bf* __restrict__ ga, const int* __restrict__ idx,
                 bf* __restrict__ agg)
{
    int n = blockIdx.y;
    int v = blockIdx.x * 256 + threadIdx.x;
    int i0 = idx[n * 3 + 0], i1 = idx[n * 3 + 1], i2 = idx[n * 3 + 2];
    const size_t stride = (size_t)16 << 16;
    const uint4* p0 = (const uint4*)(ga + stride * i0) + v;
    const uint4* p1 = (const uint4*)(ga + stride * i1) + v;
    const uint4* p2 = (const uint4*)(ga + stride * i2) + v;
    uint4 a = *p0, b = *p1, c = *p2;
    uint4 r;
    unsigned* ap = (unsigned*)&a; unsigned* bp = (unsigned*)&b;
    unsigned* cp = (unsigned*)&c; unsigned* rp = (unsigned*)&r;
    #pragma unroll
    for (int w = 0; w < 4; ++w) {
        float fa0 = __bfloat162float((__hip_bfloat16_raw){(unsigned short)(ap[w] & 0xffff)});
        float fb0 = __bfloat162float((__hip_bfloat16_raw){(unsigned short)(bp[w] & 0xffff)});
        float fc0 = __bfloat162float((__hip_bfloat16_raw){(unsigned short)(cp[w] & 0xffff)});
        float fa1 = __bfloat162float((__hip_bfloat16_raw){(unsigned short)(ap[w] >> 16)});
        float fb1 = __bfloat162float((__hip_bfloat16_raw){(unsigned short)(bp[w] >> 16)});
        float fc1 = __bfloat162float((__hip_bfloat16_raw){(unsigned short)(cp[w] >> 16)});
        rp[w] = packbf((fa0 + fb0 + fc0) * (1.f / 3.f),
                       (fa1 + fb1 + fc1) * (1.f / 3.f));
    }
    *((uint4*)(agg + stride * n) + v) = r;
}

// ===========================================================================
// Light head: gnn (bf16) + d1 recompute + dense 32->2 + softmax.
// ===========================================================================
__global__ __launch_bounds__(256)
void head_tiled(const float* __restrict__ cts, const bf* __restrict__ gnn,
                const float* __restrict__ w_d1, const float* __restrict__ b_d1,
                const float* __restrict__ w_de, const float* __restrict__ b_de,
                float* __restrict__ out, int N)
{
    __shared__ float sCts[18][19];
    __shared__ float sWd1[144];
    __shared__ float sB1[16];
    __shared__ float sDe[64];

    int tile = blockIdx.x;
    int X0 = (tile & 15) * 16, Y0 = (tile >> 4) * 16;
    int n = blockIdx.y;
    int t = threadIdx.x, tx = t & 15, ty = t >> 4;

    for (int e = t; e < 18 * 18; e += 256) {
        int py = e / 18, px = e % 18;
        int iy = Y0 - 1 + py, ix = X0 - 1 + px;
        sCts[py][px] = ((unsigned)iy < 256u && (unsigned)ix < 256u)
                       ? cts[((size_t)n << 16) + (iy << 8) + ix] : 0.f;
    }
    if (t < 144) sWd1[t] = w_d1[t];
    else if (t < 160) sB1[t - 144] = b_d1[t - 144];
    else if (t >= 192 && t < 256) sDe[t - 192] = w_de[t - 192];
    __syncthreads();

    int pix = ((Y0 + ty) << 8) + X0 + tx;
    float l0 = b_de[0], l1 = b_de[1];

    #pragma unroll
    for (int c = 0; c < 16; ++c) {
        float v = bf2f(gnn[((size_t)(n * 16 + c) << 16) + pix]);
        l0 = fmaf(v, sDe[c * 2 + 0], l0);
        l1 = fmaf(v, sDe[c * 2 + 1], l1);
    }

    float ct[3][3];
    #pragma unroll
    for (int a = 0; a < 3; ++a)
        #pragma unroll
        for (int b = 0; b < 3; ++b)
            ct[a][b] = sCts[ty + a][tx + b];
    #pragma unroll
    for (int c = 0; c < 16; ++c) {
        float a1 = sB1[c];
        #pragma unroll
        for (int t9 = 0; t9 < 9; ++t9)
            a1 = fmaf(ct[t9 / 3][t9 % 3], sWd1[c * 9 + t9], a1);
        float v = fmaxf(a1, 0.f);
        l0 = fmaf(v, sDe[(16 + c) * 2 + 0], l0);
        l1 = fmaf(v, sDe[(16 + c) * 2 + 1], l1);
    }

    float m = fmaxf(l0, l1);
    float e0 = expf(l0 - m), e1 = expf(l1 - m);
    float inv = 1.f / (e0 + e1);
    size_t base = ((size_t)n * 2) << 16;
    out[base + pix] = e0 * inv;
    out[base + 65536 + pix] = e1 * inv;
}

// ===========================================================================

extern "C" void kernel_launch(void* const* d_in, const int* in_sizes, int n_in,
                              void* d_out, int out_size, void* d_ws, size_t ws_size,
                              hipStream_t stream)
{
    const float* cts  = (const float*)d_in[0];
    const int*   prng = (const int*)d_in[1];
    const float* w_d1 = (const float*)d_in[2];  const float* b_d1 = (const float*)d_in[3];
    const float* w_d2 = (const float*)d_in[4];  const float* b_d2 = (const float*)d_in[5];
    const float* w_d3 = (const float*)d_in[6];  const float* b_d3 = (const float*)d_in[7];
    const float* w_d4 = (const float*)d_in[8];  const float* b_d4 = (const float*)d_in[9];
    const float* w_u1 = (const float*)d_in[10]; const float* b_u1 = (const float*)d_in[11];
    const float* w_u2 = (const float*)d_in[12]; const float* b_u2 = (const float*)d_in[13];
    const float* w_u3 = (const float*)d_in[14]; const float* b_u3 = (const float*)d_in[15];
    const float* w_ga = (const float*)d_in[16]; const float* b_ga = (const float*)d_in[17];
    const float* w_gu = (const float*)d_in[18]; const float* b_gu = (const float*)d_in[19];
    const float* w_de = (const float*)d_in[20]; const float* b_de = (const float*)d_in[21];

    const int H = 256, Wd = 256;
    const int N = in_sizes[0] / (H * Wd);   // 32

    // ---- workspace layout (192 MiB total), lifetime reuse ----
    // u3 [0,64M); R1 [64M,128M): d1 -> u1/u2 -> ga/gnn (spans the FULL 64MB);
    // R2 [128M,184M): d2/d3/d4 -> simp/sim -> agg.
    // FREE window: [184M,192M) — prepacked weights live here (~503KB).
    char* wsb = (char*)d_ws;
    bf* u3 = (bf*)(wsb);
    bf* R1 = (bf*)(wsb + 67108864);

    bf* d1 = R1;
    bf* d2 = (bf*)(wsb + 134217728);
    bf* d3 = (bf*)(wsb + 134217728 + 33554432);
    bf* d4 = (bf*)(wsb + 134217728 + 50331648);
    bf* u1 = R1;
    bf* u2 = (bf*)(wsb + 67108864 + 16777216);
    bf* ga = R1;
    bf* gnn = R1;
    bf* agg = (bf*)(wsb + 134217728);
    float* simp = (float*)(wsb + 134217728);
    float* sim  = (float*)(wsb + 134217728 + 16777216);
    int*   idx  = (int*)d_out + (out_size - 96);

    // prepacked weight images in the dead window @ 184 MiB
    bf* pwu1 = (bf*)(wsb + 192937984);               // 16 pairs * 10496B
    bf* pwu2 = (bf*)(wsb + 192937984 + 167936);      //  8 pairs
    bf* pwu3 = (bf*)(wsb + 192937984 + 251904);      //  2 pairs
    bf* pwga = (bf*)(wsb + 192937984 + 272896);      // 16x160
    bf* pwgn = (bf*)(wsb + 192937984 + 278016);      // 16x288
    bf* pwd2 = (bf*)(wsb + 192937984 + 287232);      //  2 pairs * 5120B
    bf* pwd3 = (bf*)(wsb + 192937984 + 297472);      //  8 pairs
    bf* pwd4 = (bf*)(wsb + 192937984 + 338432);      // 32 pairs -> ends 502272

    const int KTOT = 16 * H * Wd;
    const int NCH  = KTOT / 256;            // 4096 chunks

    // one-time weight repack (tiny)
    prep_wt_convt<<<16, 256, 0, stream>>>(w_u1, pwu1, 128, 4);
    prep_wt_convt<<<8,  256, 0, stream>>>(w_u2, pwu2, 128, 4);
    prep_wt_convt<<<2,  256, 0, stream>>>(w_u3, pwu3, 64, 2);
    prep_wt_conv<<<1,   256, 0, stream>>>(w_ga, pwga, 16, 160);
    prep_wt_conv<<<1,   256, 0, stream>>>(w_gu, pwgn, 32, 288);
    prep_wt_conv2s<<<2,  256, 0, stream>>>(w_d2, pwd2, 16, 1);
    prep_wt_conv2s<<<8,  256, 0, stream>>>(w_d3, pwd3, 32, 2);
    prep_wt_conv2s<<<32, 256, 0, stream>>>(w_d4, pwd4, 64, 4);

    // encoder (stride-2 convs via MFMA, prepacked weights)
    conv32<float><<<dim3(64, N), 256, 0, stream>>>(cts, cts, 1, 1, w_d1, b_d1, d1, N);
    conv2s_mfma<16><<<dim3(64, N, 2), 256, 0, stream>>>(
        d1, pwd2, b_d2, d2, N, 256, 256, 32, 128, 128, 8);
    conv2s_mfma<32><<<dim3(16, N, 4), 256, 0, stream>>>(
        d2, pwd3, b_d3, d3, N, 128, 128, 64, 64, 64, 4);
    conv2s_mfma<64><<<dim3(4, N, 8), 256, 0, stream>>>(
        d3, pwd4, b_d4, d4, N, 64, 64, 128, 32, 32, 2);
    // decoder (all transposed convs via MFMA, prepacked weights)
    convt_mfma<128, 128><<<dim3(4, N, 4), 256, 0, stream>>>(
        d4, d4, pwu1, b_u1, u1, N, 32, 32, 64, 64, 64, 2);
    convt_mfma<128, 64><<<dim3(16, N, 2), 256, 0, stream>>>(
        u1, d3, pwu2, b_u2, u2, N, 64, 64, 32, 128, 128, 4);
    convt_mfma<64, 32><<<dim3(64, N, 1), 256, 0, stream>>>(
        u2, d2, pwu3, b_u3, u3, N, 128, 128, 16, 256, 256, 8);
    // cosine similarity + top-3 (Gram via MFMA)
    sim_partial<<<NCH, 256, 0, stream>>>(u3, simp, KTOT);
    sim_reduce<<<dim3(N * N), 256, 0, stream>>>(simp, sim, NCH);
    topk_kernel<<<1, 64, 0, stream>>>(sim, prng, idx, N);
    // per-slice gnn-neighbor conv (MFMA), then gather-mean
    conv_mfma<16, 20, 160><<<dim3(256, N), 256, 0, stream>>>(
        u3, u3, 16, pwga, b_ga, ga, N);
    gather_mean<<<dim3(512, N), 256, 0, stream>>>(ga, idx, agg);
    // gnn conv (MFMA, 32ch from u3|agg) then light head
    conv_mfma<32, 40, 288><<<dim3(256, N), 256, 0, stream>>>(
        u3, agg, 16, pwgn, b_gu, gnn, N);
    head_tiled<<<dim3(256, N), 256, 0, stream>>>(
        cts, gnn, w_d1, b_d1, w_de, b_de, (float*)d_out, N);
}

// Round 31
// 658.994 us; speedup vs baseline: 2.7864x; 1.1352x over previous
//
#include <hip/hip_runtime.h>
#include <hip/hip_bf16.h>
#include <math.h>

typedef __hip_bfloat16 bf;
typedef __attribute__((ext_vector_type(8))) short bf8v;   // 8 bf16 = 4 VGPR
typedef __attribute__((ext_vector_type(4))) float f4v;

__device__ __forceinline__ float bf2f(bf v) { return __bfloat162float(v); }
__device__ __forceinline__ bf f2bf(float v) { return __float2bfloat16(v); }
__device__ __forceinline__ unsigned packbf(float a, float b) {
    __hip_bfloat16_raw ra = (__hip_bfloat16_raw)__float2bfloat16(a);
    __hip_bfloat16_raw rb = (__hip_bfloat16_raw)__float2bfloat16(b);
    return (unsigned)ra.x | ((unsigned)rb.x << 16);
}

// XCD-aware bijective work swizzle (requires total % 8 == 0).
__device__ __forceinline__ int xcd_swizzle_lin()
{
    int total = gridDim.x * gridDim.y * gridDim.z;
    int lin = blockIdx.x + gridDim.x * (blockIdx.y + gridDim.y * blockIdx.z);
    return (lin & 7) * (total >> 3) + (lin >> 3);
}

// ===========================================================================
// Weight prep kernels (one-time per launch).
// ===========================================================================
__global__ __launch_bounds__(256)
void prep_wt_convt(const float* __restrict__ Wt, bf* __restrict__ outp,
                   int CITOT, int NCH)
{
    int pair = blockIdx.x;                 // cog * NCH + cb
    int cog = pair / NCH, cb = pair % NCH;
    int t = threadIdx.x;
    bf* dst = outp + (size_t)pair * 16 * 328;
    for (int e = t; e < 16 * 288; e += 256) {
        int co = e / 288, rem = e % 288;
        int cic = rem / 9, t9 = rem % 9;
        int ky = t9 / 3, kx = t9 % 3;
        int ry = (ky == 1) ? 0 : 1;
        int rx = (kx == 1) ? 0 : 1;
        int ty = (ky == 1) ? 0 : (ky >> 1);
        int txi = (kx == 1) ? 0 : (kx >> 1);
        int ntx = 1 + rx;
        int ph = ry * 2 + rx;
        const int base4[4] = {0, 40, 112, 184};
        int kl = (ty * ntx + txi) * 32 + cic;     // cic-minor k order
        dst[co * 328 + base4[ph] + kl] =
            f2bf(Wt[(size_t)(cog * 16 + co) * CITOT * 9
                    + (size_t)(cb * 32 + cic) * 9 + t9]);
    }
}

__global__ __launch_bounds__(256)
void prep_wt_conv(const float* __restrict__ Wt, bf* __restrict__ outp,
                  int CI, int KPAD)
{
    int t = threadIdx.x;
    int K = CI * 9;
    for (int e = t; e < 16 * KPAD; e += 256) {
        int co = e / KPAD, k = e % KPAD;
        int tap = k / CI, ci = k % CI;
        outp[co * KPAD + k] = (k < K)
            ? f2bf(Wt[(size_t)co * K + ci * 9 + tap]) : f2bf(0.f);
    }
}

// stride-2 conv weights: per-(cog, cb16) 16x160 images, kl = tap*16 + ci.
__global__ __launch_bounds__(256)
void prep_wt_conv2s(const float* __restrict__ Wt, bf* __restrict__ outp,
                    int CITOT, int NCH)
{
    int pair = blockIdx.x;                 // cog * NCH + cb
    int cog = pair / NCH, cb = pair % NCH;
    int t = threadIdx.x;
    bf* dst = outp + (size_t)pair * 16 * 160;
    for (int e = t; e < 16 * 160; e += 256) {
        int co = e / 160, k = e % 160;
        int tap = k / 16, ci = k % 16;
        dst[e] = (k < 144)
            ? f2bf(Wt[(size_t)(cog * 16 + co) * CITOT * 9
                      + (size_t)(cb * 16 + ci) * 9 + tap])
            : f2bf(0.f);
    }
}

// ===========================================================================
// MFMA stride-2 conv (d2,d3,d4). (verified r30)
// ===========================================================================
template <int CITOT>
__global__ __launch_bounds__(256)
void conv2s_mfma(const bf* __restrict__ in, const bf* __restrict__ pW,
                 const float* __restrict__ Bias, bf* __restrict__ out,
                 int N, int Hi, int Wi, int Cotot, int Ho, int Wo, int tilesX)
{
    constexpr int NCH = CITOT / 16;
    __shared__ __align__(16) bf sIn2[33][33][18];  // [py][px][ci pad18] 39.2KB
    __shared__ __align__(16) bf sWt[16][160];      // 5KB

    int swz = xcd_swizzle_lin();
    int tile = swz % gridDim.x;
    int rest = swz / gridDim.x;
    int n = rest % gridDim.y;
    int cog = rest / gridDim.y;

    int X0 = (tile % tilesX) * 16, Y0 = (tile / tilesX) * 16;  // output coords
    int t = threadIdx.x;
    int lane = t & 63, wave = t >> 6;
    int q = lane >> 4, mcol = lane & 15;
    int prow0 = wave * 4;

    f4v acc[4];
    #pragma unroll
    for (int g = 0; g < 4; ++g) acc[g] = (f4v){0.f, 0.f, 0.f, 0.f};

    for (int cb = 0; cb < NCH; ++cb) {
        if (cb) __syncthreads();                  // drain reads before restage
        // input: 16 ci x 33 rows x {1 scalar + 4 vec8} segments
        for (int e = t; e < 16 * 165; e += 256) {
            int ci = e / 165, rem = e % 165;
            int py = rem / 5, seg = rem % 5;
            const bf* src = in + (size_t)(n * CITOT + cb * 16 + ci) * Hi * Wi;
            int iy = 2 * Y0 - 1 + py;
            bool rowok = (iy >= 0);               // iy < Hi always holds
            if (seg == 0) {
                int ix = 2 * X0 - 1;
                sIn2[py][0][ci] = (rowok && ix >= 0)
                                  ? src[(size_t)iy * Wi + ix] : f2bf(0.f);
            } else {
                int px0 = 1 + 8 * (seg - 1);       // 1, 9, 17, 25
                int ix0 = 2 * X0 + 8 * (seg - 1);  // in-bounds, 16B-aligned
                if (rowok) {
                    uint4 v = *(const uint4*)&src[(size_t)iy * Wi + ix0];
                    const bf* pv = (const bf*)&v;
                    #pragma unroll
                    for (int j = 0; j < 8; ++j) sIn2[py][px0 + j][ci] = pv[j];
                } else {
                    #pragma unroll
                    for (int j = 0; j < 8; ++j) sIn2[py][px0 + j][ci] = f2bf(0.f);
                }
            }
        }
        // weights: contiguous copy of the (cog, cb) prepacked 16x160 image
        {
            const uint4* wsrc = (const uint4*)(pW
                + ((size_t)cog * NCH + cb) * 16 * 160);
            for (int e = t; e < 320; e += 256)     // 16*160/8
                ((uint4*)sWt)[e] = wsrc[e];
        }
        __syncthreads();

        #pragma unroll
        for (int s = 0; s < 5; ++s) {
            bf8v wf = *(const bf8v*)&sWt[mcol][s * 32 + q * 8];
            int tap = 2 * s + (q >> 1); if (tap > 8) tap = 8;  // pad weights=0
            int ciofs = (q & 1) * 8;
            int ay = tap / 3, ax = tap - ay * 3;
            #pragma unroll
            for (int g = 0; g < 4; ++g) {
                bf8v af = *(const bf8v*)
                    &sIn2[2 * (prow0 + g) + ay][2 * mcol + ax][ciofs];
                acc[g] = __builtin_amdgcn_mfma_f32_16x16x32_bf16(af, wf,
                                                                 acc[g], 0, 0, 0);
            }
        }
    }

    float bs = Bias[cog * 16 + mcol];
    bf* dst = out + (size_t)(n * Cotot + cog * 16 + mcol) * Ho * Wo;
    #pragma unroll
    for (int g = 0; g < 4; ++g) {
        int oy = Y0 + prow0 + g, ox = X0 + q * 4;
        uint2 pk;
        pk.x = packbf(fmaxf(acc[g][0] + bs, 0.f), fmaxf(acc[g][1] + bs, 0.f));
        pk.y = packbf(fmaxf(acc[g][2] + bs, 0.f), fmaxf(acc[g][3] + bs, 0.f));
        *(uint2*)(dst + (size_t)oy * Wo + ox) = pk;
    }
}

// ===========================================================================
// Stride-1 conv (d1 only, Ci=1). 32x32 tile, 2x2 px/thread.
// ===========================================================================
template <typename TIN>
__global__ __launch_bounds__(256)
void conv32(const TIN* __restrict__ inA, const TIN* __restrict__ inB,
            int CiA, int Ci,
            const float* __restrict__ Wt, const float* __restrict__ Bias,
            bf* __restrict__ out, int N)
{
    constexpr int CHUNK = 4;
    __shared__ float sIn[CHUNK][34][35];
    __shared__ __align__(16) float sW[CHUNK][9][16];

    int tile = blockIdx.x;
    int X0 = (tile & 7) * 32, Y0 = (tile >> 3) * 32;
    int n = blockIdx.y;
    int t = threadIdx.x, tx = t & 15, ty = t >> 4;
    int CiB = Ci - CiA;

    float acc[4][16];
    #pragma unroll
    for (int p = 0; p < 4; ++p)
        #pragma unroll
        for (int c = 0; c < 16; ++c) acc[p][c] = 0.f;

    for (int cb = 0; cb < Ci; cb += CHUNK) {
        int cn = (Ci - cb < CHUNK) ? Ci - cb : CHUNK;
        for (int e = t; e < cn * 1156; e += 256) {
            int ci = e / 1156, rem = e % 1156;
            int py = rem / 34, px = rem % 34;
            int iy = Y0 - 1 + py, ix = X0 - 1 + px;
            int gci = cb + ci;
            const TIN* src = (gci < CiA)
                ? inA + ((size_t)(n * CiA + gci) << 16)
                : inB + ((size_t)(n * CiB + gci - CiA) << 16);
            sIn[ci][py][px] = ((unsigned)iy < 256u && (unsigned)ix < 256u)
                              ? (float)src[(iy << 8) + ix] : 0.f;
        }
        for (int e = t; e < cn * 144; e += 256) {
            int ci = e / 144, rem = e % 144;
            int t9 = rem / 16, co = rem % 16;
            sW[ci][t9][co] = Wt[(size_t)co * Ci * 9 + (cb + ci) * 9 + t9];
        }
        __syncthreads();
        for (int ci = 0; ci < cn; ++ci) {
            float rin[4][4];
            #pragma unroll
            for (int a = 0; a < 4; ++a)
                #pragma unroll
                for (int b = 0; b < 4; ++b)
                    rin[a][b] = sIn[ci][2 * ty + a][2 * tx + b];
            #pragma unroll
            for (int t9 = 0; t9 < 9; ++t9) {
                const int ky = t9 / 3, kx = t9 % 3;
                float w[16];
                #pragma unroll
                for (int q = 0; q < 4; ++q)
                    *(float4*)&w[q * 4] = *(const float4*)&sW[ci][t9][q * 4];
                #pragma unroll
                for (int ry = 0; ry < 2; ++ry)
                    #pragma unroll
                    for (int rx = 0; rx < 2; ++rx) {
                        float v = rin[ry + ky][rx + kx];
                        #pragma unroll
                        for (int co = 0; co < 16; ++co)
                            acc[ry * 2 + rx][co] = fmaf(v, w[co], acc[ry * 2 + rx][co]);
                    }
            }
        }
        __syncthreads();
    }

    #pragma unroll
    for (int co = 0; co < 16; ++co) {
        float bs = Bias[co];
        bf* dst = out + ((size_t)(n * 16 + co) << 16);
        #pragma unroll
        for (int ry = 0; ry < 2; ++ry) {
            unsigned pk = packbf(fmaxf(acc[ry * 2 + 0][co] + bs, 0.f),
                                 fmaxf(acc[ry * 2 + 1][co] + bs, 0.f));
            *(unsigned*)(dst + ((Y0 + 2 * ty + ry) << 8) + X0 + 2 * tx) = pk;
        }
    }
}

// ===========================================================================
// MFMA implicit-GEMM stride-1 conv (ga, gnn).
// ===========================================================================
template <int CI, int CIP, int KPAD>
__global__ __launch_bounds__(256)
void conv_mfma(const bf* __restrict__ inA, const bf* __restrict__ inB,
               int CiA, const bf* __restrict__ pW,
               const float* __restrict__ Bias,
               bf* __restrict__ out, int N)
{
    constexpr int NM = KPAD / 32;
    __shared__ __align__(16) bf sIn2[18][19][CIP];
    __shared__ __align__(16) bf sWt[16][KPAD];

    int swz = xcd_swizzle_lin();           // gridDim.x == 256 always
    int tile = swz & 255;
    int n = swz >> 8;

    int X0 = (tile & 15) * 16, Y0 = (tile >> 4) * 16;
    int t = threadIdx.x;
    int lane = t & 63, wave = t >> 6;
    int q = lane >> 4, mcol = lane & 15;
    int CiB = CI - CiA;

    // weights: contiguous copy of prepacked image
    for (int e = t; e < 16 * KPAD / 8; e += 256)
        ((uint4*)sWt)[e] = ((const uint4*)pW)[e];
    // input: channel-minor [py][px][ci]; vectorized global reads
    for (int e = t; e < CI * 72; e += 256) {       // 18 rows x 4 slots
        int ci = e / 72, rem = e % 72;
        int py = rem / 4, slot = rem % 4;
        const bf* src = (ci < CiA)
            ? inA + ((size_t)(n * CiA + ci) << 16)
            : inB + ((size_t)(n * CiB + ci - CiA) << 16);
        int iy = Y0 - 1 + py;
        bool rowok = ((unsigned)iy < 256u);
        if (slot == 0) {
            int ix = X0 - 1;
            sIn2[py][0][ci] = (rowok && ix >= 0) ? src[(iy << 8) + ix] : f2bf(0.f);
        } else if (slot == 3) {
            int ix = X0 + 16;
            sIn2[py][17][ci] = (rowok && ix < 256) ? src[(iy << 8) + ix] : f2bf(0.f);
        } else {
            int px0 = (slot == 1) ? 1 : 9;
            if (rowok) {
                uint4 v = *(const uint4*)&src[(iy << 8) + X0 - 1 + px0];
                const bf* pv = (const bf*)&v;
                #pragma unroll
                for (int j = 0; j < 8; ++j) sIn2[py][px0 + j][ci] = pv[j];
            } else {
                #pragma unroll
                for (int j = 0; j < 8; ++j) sIn2[py][px0 + j][ci] = f2bf(0.f);
            }
        }
    }
    __syncthreads();

    f4v acc[4];
    #pragma unroll
    for (int g = 0; g < 4; ++g) acc[g] = (f4v){0.f, 0.f, 0.f, 0.f};

    int prow0 = wave * 4;
    #pragma unroll
    for (int s = 0; s < NM; ++s) {
        bf8v wf = *(const bf8v*)&sWt[mcol][s * 32 + q * 8];
        int tap, ciofs;
        if (CI == 32) { tap = s;               ciofs = q * 8; }
        else          { tap = 2 * s + (q >> 1); if (tap > 8) tap = 8;
                        ciofs = (q & 1) * 8; }
        int ay = tap / 3, ax = tap - ay * 3;
        #pragma unroll
        for (int g = 0; g < 4; ++g) {
            bf8v af = *(const bf8v*)&sIn2[prow0 + g + ay][mcol + ax][ciofs];
            acc[g] = __builtin_amdgcn_mfma_f32_16x16x32_bf16(af, wf, acc[g], 0, 0, 0);
        }
    }

    float bs = Bias[mcol];
    bf* dst = out + ((size_t)(n * 16 + mcol) << 16);
    #pragma unroll
    for (int g = 0; g < 4; ++g) {
        int oy = Y0 + prow0 + g, ox = X0 + q * 4;
        uint2 pk;
        pk.x = packbf(fmaxf(acc[g][0] + bs, 0.f), fmaxf(acc[g][1] + bs, 0.f));
        pk.y = packbf(fmaxf(acc[g][2] + bs, 0.f), fmaxf(acc[g][3] + bs, 0.f));
        *(uint2*)(dst + (oy << 8) + ox) = pk;
    }
}

// ===========================================================================
// MFMA phase-decomposed transposed conv (u1,u2,u3).
// r31: [17][19][40] staging pad (write-conflict spread) + phase-paired
// uint4 epilogue (8 x 16B coalesced stores instead of 64 scalar stores).
// ===========================================================================
#define CVT_CHAIN(PH, KOFF, AY, AX)                                           \
    {                                                                          \
        bf8v wf = *(const bf8v*)&sWt[mcol][(KOFF) + q * 8];                    \
        _Pragma("unroll")                                                      \
        for (int g = 0; g < 4; ++g) {                                          \
            bf8v af = *(const bf8v*)&sIn2[prow0 + g + (AY)][mcol + (AX)][q * 8];\
            acc[PH][g] = __builtin_amdgcn_mfma_f32_16x16x32_bf16(af, wf,       \
                                                      acc[PH][g], 0, 0, 0);    \
        }                                                                      \
    }

template <int CITOT, int CIA>
__global__ __launch_bounds__(256)
void convt_mfma(const bf* __restrict__ inA, const bf* __restrict__ inB,
                const bf* __restrict__ pW, const float* __restrict__ Bias,
                bf* __restrict__ out,
                int N, int Hi, int Wi, int Cotot, int Ho, int Wo, int tilesX)
{
    constexpr int NCH = CITOT / 32;
    __shared__ __align__(16) bf sIn2[17][19][40];  // [py][px pad19][ci pad40]
    __shared__ __align__(16) bf sWt[16][328];      // phase bases 0,40,112,184

    int swz = xcd_swizzle_lin();
    int tile = swz % gridDim.x;
    int rest = swz / gridDim.x;
    int n = rest % gridDim.y;
    int cog = rest / gridDim.y;

    int J0 = (tile % tilesX) * 16, I0 = (tile / tilesX) * 16;
    int t = threadIdx.x;
    int lane = t & 63, wave = t >> 6;
    int q = lane >> 4, mcol = lane & 15;
    int prow0 = wave * 4;

    f4v acc[4][4];
    #pragma unroll
    for (int p = 0; p < 4; ++p)
        #pragma unroll
        for (int g = 0; g < 4; ++g) acc[p][g] = (f4v){0.f, 0.f, 0.f, 0.f};

    for (int cb = 0; cb < NCH; ++cb) {
        if (cb) __syncthreads();                  // drain reads before restage
        for (int e = t; e < 32 * 51; e += 256) {  // 51 = 17 rows * 3 segs
            int ci = e / 51, rem = e % 51;
            int py = rem / 3, seg = rem % 3;
            int gci = cb * 32 + ci;
            const bf* src = (gci < CIA)
                ? inA + (size_t)(n * CIA + gci) * Hi * Wi
                : inB + (size_t)(n * (CITOT - CIA) + gci - CIA) * Hi * Wi;
            int iy = I0 + py;
            if (seg < 2) {
                int px0 = seg * 8;
                if (iy < Hi) {
                    uint4 v = *(const uint4*)&src[(size_t)iy * Wi + J0 + px0];
                    const bf* pv = (const bf*)&v;
                    #pragma unroll
                    for (int j = 0; j < 8; ++j) sIn2[py][px0 + j][ci] = pv[j];
                } else {
                    #pragma unroll
                    for (int j = 0; j < 8; ++j) sIn2[py][px0 + j][ci] = f2bf(0.f);
                }
            } else {
                int ix = J0 + 16;
                sIn2[py][16][ci] = (iy < Hi && ix < Wi)
                                   ? src[(size_t)iy * Wi + ix] : f2bf(0.f);
                sIn2[py][17][ci] = f2bf(0.f);
            }
        }
        // weights: contiguous copy of the (cog, cb) prepacked image
        {
            const uint4* wsrc = (const uint4*)(pW
                + ((size_t)cog * NCH + cb) * 16 * 328);
            for (int e = t; e < 656; e += 256)     // 16*328/8
                ((uint4*)sWt)[e] = wsrc[e];
        }
        __syncthreads();

        //        PH  KOFF AY AX      (chain = one tap over 32 channels)
        CVT_CHAIN(0,   0, 0, 0)    // phase (ry0,rx0): tap (1,1)
        CVT_CHAIN(1,  40, 0, 0)    // phase (ry0,rx1): tap kx=0
        CVT_CHAIN(1,  72, 0, 1)    //                  tap kx=2
        CVT_CHAIN(2, 112, 0, 0)    // phase (ry1,rx0): tap ky=0
        CVT_CHAIN(2, 144, 1, 0)    //                  tap ky=2
        CVT_CHAIN(3, 184, 0, 0)    // phase (ry1,rx1): tap (0,0)
        CVT_CHAIN(3, 216, 0, 1)    //                  tap (0,2)
        CVT_CHAIN(3, 248, 1, 0)    //                  tap (2,0)
        CVT_CHAIN(3, 280, 1, 1)    //                  tap (2,2)
    }

    // phase-paired uint4 epilogue: phases (ry,0)/(ry,1) fill even/odd x of
    // the same output row; jj spans 8 consecutive elements -> one 16B store
    // at dst[oy*Wo + 2*J0 + q*8] (16B-aligned: J0 mult-16).
    float bs = Bias[cog * 16 + mcol];
    bf* dst = out + (size_t)(n * Cotot + cog * 16 + mcol) * Ho * Wo;
    #pragma unroll
    for (int ry = 0; ry < 2; ++ry) {
        #pragma unroll
        for (int g = 0; g < 4; ++g) {
            int oy = 2 * (I0 + prow0 + g) + ry;
            uint4 pk;
            unsigned* pw = (unsigned*)&pk;
            #pragma unroll
            for (int jj = 0; jj < 4; ++jj)
                pw[jj] = packbf(fmaxf(acc[2 * ry + 0][g][jj] + bs, 0.f),
                                fmaxf(acc[2 * ry + 1][g][jj] + bs, 0.f));
            *(uint4*)(dst + (size_t)oy * Wo + 2 * J0 + q * 8) = pk;
        }
    }
}

// ===========================================================================
// MFMA Gram partials (verified round 20).
// ===========================================================================
__global__ __launch_bounds__(256)
void sim_partial(const bf* __restrict__ f, float* __restrict__ part, int KTOT)
{
    __shared__ __align__(16) bf tile[32][264];
    int c = blockIdx.x;
    int t = threadIdx.x;
    int k0 = c << 8;

    for (int e = t; e < 1024; e += 256) {
        int row = e >> 5, col8 = (e & 31) * 8;
        uint4 v = *(const uint4*)&f[(size_t)row * KTOT + k0 + col8];
        *(uint4*)&tile[row][col8] = v;
    }
    __syncthreads();

    int lane = t & 63, wave = t >> 6;
    int q = lane >> 4, mcol = lane & 15;
    int qr = wave >> 1, qc = wave & 1;

    f4v acc = (f4v){0.f, 0.f, 0.f, 0.f};
    #pragma unroll
    for (int ks = 0; ks < 8; ++ks) {
        bf8v a = *(const bf8v*)&tile[qr * 16 + mcol][ks * 32 + q * 8];
        bf8v b = *(const bf8v*)&tile[qc * 16 + mcol][ks * 32 + q * 8];
        acc = __builtin_amdgcn_mfma_f32_16x16x32_bf16(a, b, acc, 0, 0, 0);
    }

    float* dst = part + (size_t)c * 1024;
    #pragma unroll
    for (int jj = 0; jj < 4; ++jj) {
        int i = qr * 16 + q * 4 + jj;
        int j = qc * 16 + mcol;
        dst[i * 32 + j] = acc[jj];
    }
}

__global__ __launch_bounds__(256)
void sim_reduce(const float* __restrict__ part, float* __restrict__ sim, int nchunks)
{
    __shared__ float red[256];
    int pair = blockIdx.x;
    int t = threadIdx.x;
    float s = 0.f;
    for (int k = t; k < nchunks; k += 256)
        s += part[(size_t)k * 1024 + pair];
    red[t] = s;
    __syncthreads();
    #pragma unroll
    for (int off = 128; off > 0; off >>= 1) {
        if (t < off) red[t] += red[t + off];
        __syncthreads();
    }
    if (t == 0) sim[pair] = red[0];
}

// ===========================================================================
// Cosine sim + group mask + top-3 (strict >, lowest index wins ties).
// ===========================================================================
__global__ void topk_kernel(const float* __restrict__ sim, const int* __restrict__ prange,
                            int* __restrict__ idx, int N)
{
    int i = threadIdx.x;
    if (i >= N) return;
    float nm_i = fmaxf(sqrtf(sim[i * N + i]), 1e-8f);
    int p0 = prange[0], p1 = prange[1];
    int gi = (i >= p0) + (i >= p1);
    float vals[32];
    for (int j = 0; j < N; ++j) {
        int gj = (j >= p0) + (j >= p1);
        if (j == i || gj != gi) { vals[j] = -1e30f; continue; }
        float nm_j = fmaxf(sqrtf(sim[j * N + j]), 1e-8f);
        vals[j] = sim[i * N + j] / (nm_i * nm_j);
    }
    for (int k = 0; k < 3; ++k) {
        float best = -2e30f; int bj = 0;
        for (int j = 0; j < N; ++j)
            if (vals[j] > best) { best = vals[j]; bj = j; }
        idx[i * 3 + k] = bj;
        vals[bj] = -1e30f;
    }
}

// ===========================================================================
// Gather-mean: agg[n] = (ga[i0] + ga[i1] + ga[i2]) / 3.
// ===========================================================================
__global__ __launch_bounds__(256)
void gather_mean(const bf* __restrict__ ga, const int* __restrict__ idx,
                 bf* __restrict__ agg)
{
    int n = blockIdx.y;
    int v = blockIdx.x * 256 + threadIdx.x;
    int i0 = idx[n * 3 + 0], i1 = idx[n * 3 + 1], i2 = idx[n * 3 + 2];
    const size_t stride = (size_t)16 << 16;
    const uint4* p0 = (const uint4*)(ga + stride * i0) + v;
    const uint4* p1 = (const uint4*)(ga + stride * i1) + v;
    const uint4* p2 = (const uint4*)(ga + stride * i2) + v;
    uint4 a = *p0, b = *p1, c = *p2;
    uint4 r;
    unsigned* ap = (unsigned*)&a; unsigned* bp = (unsigned*)&b;
    unsigned* cp = (unsigned*)&c; unsigned* rp = (unsigned*)&r;
    #pragma unroll
    for (int w = 0; w < 4; ++w) {
        float fa0 = __bfloat162float((__hip_bfloat16_raw){(unsigned short)(ap[w] & 0xffff)});
        float fb0 = __bfloat162float((__hip_bfloat16_raw){(unsigned short)(bp[w] & 0xffff)});
        float fc0 = __bfloat162float((__hip_bfloat16_raw){(unsigned short)(cp[w] & 0xffff)});
        float fa1 = __bfloat162float((__hip_bfloat16_raw){(unsigned short)(ap[w] >> 16)});
        float fb1 = __bfloat162float((__hip_bfloat16_raw){(unsigned short)(bp[w] >> 16)});
        float fc1 = __bfloat162float((__hip_bfloat16_raw){(unsigned short)(cp[w] >> 16)});
        rp[w] = packbf((fa0 + fb0 + fc0) * (1.f / 3.f),
                       (fa1 + fb1 + fc1) * (1.f / 3.f));
    }
    *((uint4*)(agg + stride * n) + v) = r;
}

// ===========================================================================
// Light head: gnn (bf16) + d1 recompute + dense 32->2 + softmax.
// ===========================================================================
__global__ __launch_bounds__(256)
void head_tiled(const float* __restrict__ cts, const bf* __restrict__ gnn,
                const float* __restrict__ w_d1, const float* __restrict__ b_d1,
                const float* __restrict__ w_de, const float* __restrict__ b_de,
                float* __restrict__ out, int N)
{
    __shared__ float sCts[18][19];
    __shared__ float sWd1[144];
    __shared__ float sB1[16];
    __shared__ float sDe[64];

    int tile = blockIdx.x;
    int X0 = (tile & 15) * 16, Y0 = (tile >> 4) * 16;
    int n = blockIdx.y;
    int t = threadIdx.x, tx = t & 15, ty = t >> 4;

    for (int e = t; e < 18 * 18; e += 256) {
        int py = e / 18, px = e % 18;
        int iy = Y0 - 1 + py, ix = X0 - 1 + px;
        sCts[py][px] = ((unsigned)iy < 256u && (unsigned)ix < 256u)
                       ? cts[((size_t)n << 16) + (iy << 8) + ix] : 0.f;
    }
    if (t < 144) sWd1[t] = w_d1[t];
    else if (t < 160) sB1[t - 144] = b_d1[t - 144];
    else if (t >= 192 && t < 256) sDe[t - 192] = w_de[t - 192];
    __syncthreads();

    int pix = ((Y0 + ty) << 8) + X0 + tx;
    float l0 = b_de[0], l1 = b_de[1];

    #pragma unroll
    for (int c = 0; c < 16; ++c) {
        float v = bf2f(gnn[((size_t)(n * 16 + c) << 16) + pix]);
        l0 = fmaf(v, sDe[c * 2 + 0], l0);
        l1 = fmaf(v, sDe[c * 2 + 1], l1);
    }

    float ct[3][3];
    #pragma unroll
    for (int a = 0; a < 3; ++a)
        #pragma unroll
        for (int b = 0; b < 3; ++b)
            ct[a][b] = sCts[ty + a][tx + b];
    #pragma unroll
    for (int c = 0; c < 16; ++c) {
        float a1 = sB1[c];
        #pragma unroll
        for (int t9 = 0; t9 < 9; ++t9)
            a1 = fmaf(ct[t9 / 3][t9 % 3], sWd1[c * 9 + t9], a1);
        float v = fmaxf(a1, 0.f);
        l0 = fmaf(v, sDe[(16 + c) * 2 + 0], l0);
        l1 = fmaf(v, sDe[(16 + c) * 2 + 1], l1);
    }

    float m = fmaxf(l0, l1);
    float e0 = expf(l0 - m), e1 = expf(l1 - m);
    float inv = 1.f / (e0 + e1);
    size_t base = ((size_t)n * 2) << 16;
    out[base + pix] = e0 * inv;
    out[base + 65536 + pix] = e1 * inv;
}

// ===========================================================================

extern "C" void kernel_launch(void* const* d_in, const int* in_sizes, int n_in,
                              void* d_out, int out_size, void* d_ws, size_t ws_size,
                              hipStream_t stream)
{
    const float* cts  = (const float*)d_in[0];
    const int*   prng = (const int*)d_in[1];
    const float* w_d1 = (const float*)d_in[2];  const float* b_d1 = (const float*)d_in[3];
    const float* w_d2 = (const float*)d_in[4];  const float* b_d2 = (const float*)d_in[5];
    const float* w_d3 = (const float*)d_in[6];  const float* b_d3 = (const float*)d_in[7];
    const float* w_d4 = (const float*)d_in[8];  const float* b_d4 = (const float*)d_in[9];
    const float* w_u1 = (const float*)d_in[10]; const float* b_u1 = (const float*)d_in[11];
    const float* w_u2 = (const float*)d_in[12]; const float* b_u2 = (const float*)d_in[13];
    const float* w_u3 = (const float*)d_in[14]; const float* b_u3 = (const float*)d_in[15];
    const float* w_ga = (const float*)d_in[16]; const float* b_ga = (const float*)d_in[17];
    const float* w_gu = (const float*)d_in[18]; const float* b_gu = (const float*)d_in[19];
    const float* w_de = (const float*)d_in[20]; const float* b_de = (const float*)d_in[21];

    const int H = 256, Wd = 256;
    const int N = in_sizes[0] / (H * Wd);   // 32

    // ---- workspace layout (192 MiB total), lifetime reuse ----
    // u3 [0,64M); R1 [64M,128M): d1 -> u1/u2 -> ga/gnn (spans the FULL 64MB);
    // R2 [128M,184M): d2/d3/d4 -> simp/sim -> agg.
    // FREE window: [184M,192M) — prepacked weights live here (~503KB).
    char* wsb = (char*)d_ws;
    bf* u3 = (bf*)(wsb);
    bf* R1 = (bf*)(wsb + 67108864);

    bf* d1 = R1;
    bf* d2 = (bf*)(wsb + 134217728);
    bf* d3 = (bf*)(wsb + 134217728 + 33554432);
    bf* d4 = (bf*)(wsb + 134217728 + 50331648);
    bf* u1 = R1;
    bf* u2 = (bf*)(wsb + 67108864 + 16777216);
    bf* ga = R1;
    bf* gnn = R1;
    bf* agg = (bf*)(wsb + 134217728);
    float* simp = (float*)(wsb + 134217728);
    float* sim  = (float*)(wsb + 134217728 + 16777216);
    int*   idx  = (int*)d_out + (out_size - 96);

    // prepacked weight images in the dead window @ 184 MiB
    bf* pwu1 = (bf*)(wsb + 192937984);               // 16 pairs * 10496B
    bf* pwu2 = (bf*)(wsb + 192937984 + 167936);      //  8 pairs
    bf* pwu3 = (bf*)(wsb + 192937984 + 251904);      //  2 pairs
    bf* pwga = (bf*)(wsb + 192937984 + 272896);      // 16x160
    bf* pwgn = (bf*)(wsb + 192937984 + 278016);      // 16x288
    bf* pwd2 = (bf*)(wsb + 192937984 + 287232);      //  2 pairs * 5120B
    bf* pwd3 = (bf*)(wsb + 192937984 + 297472);      //  8 pairs
    bf* pwd4 = (bf*)(wsb + 192937984 + 338432);      // 32 pairs -> ends 502272

    const int KTOT = 16 * H * Wd;
    const int NCH  = KTOT / 256;            // 4096 chunks

    // one-time weight repack (tiny)
    prep_wt_convt<<<16, 256, 0, stream>>>(w_u1, pwu1, 128, 4);
    prep_wt_convt<<<8,  256, 0, stream>>>(w_u2, pwu2, 128, 4);
    prep_wt_convt<<<2,  256, 0, stream>>>(w_u3, pwu3, 64, 2);
    prep_wt_conv<<<1,   256, 0, stream>>>(w_ga, pwga, 16, 160);
    prep_wt_conv<<<1,   256, 0, stream>>>(w_gu, pwgn, 32, 288);
    prep_wt_conv2s<<<2,  256, 0, stream>>>(w_d2, pwd2, 16, 1);
    prep_wt_conv2s<<<8,  256, 0, stream>>>(w_d3, pwd3, 32, 2);
    prep_wt_conv2s<<<32, 256, 0, stream>>>(w_d4, pwd4, 64, 4);

    // encoder (stride-2 convs via MFMA, prepacked weights)
    conv32<float><<<dim3(64, N), 256, 0, stream>>>(cts, cts, 1, 1, w_d1, b_d1, d1, N);
    conv2s_mfma<16><<<dim3(64, N, 2), 256, 0, stream>>>(
        d1, pwd2, b_d2, d2, N, 256, 256, 32, 128, 128, 8);
    conv2s_mfma<32><<<dim3(16, N, 4), 256, 0, stream>>>(
        d2, pwd3, b_d3, d3, N, 128, 128, 64, 64, 64, 4);
    conv2s_mfma<64><<<dim3(4, N, 8), 256, 0, stream>>>(
        d3, pwd4, b_d4, d4, N, 64, 64, 128, 32, 32, 2);
    // decoder (all transposed convs via MFMA, prepacked weights)
    convt_mfma<128, 128><<<dim3(4, N, 4), 256, 0, stream>>>(
        d4, d4, pwu1, b_u1, u1, N, 32, 32, 64, 64, 64, 2);
    convt_mfma<128, 64><<<dim3(16, N, 2), 256, 0, stream>>>(
        u1, d3, pwu2, b_u2, u2, N, 64, 64, 32, 128, 128, 4);
    convt_mfma<64, 32><<<dim3(64, N, 1), 256, 0, stream>>>(
        u2, d2, pwu3, b_u3, u3, N, 128, 128, 16, 256, 256, 8);
    // cosine similarity + top-3 (Gram via MFMA)
    sim_partial<<<NCH, 256, 0, stream>>>(u3, simp, KTOT);
    sim_reduce<<<dim3(N * N), 256, 0, stream>>>(simp, sim, NCH);
    topk_kernel<<<1, 64, 0, stream>>>(sim, prng, idx, N);
    // per-slice gnn-neighbor conv (MFMA), then gather-mean
    conv_mfma<16, 20, 160><<<dim3(256, N), 256, 0, stream>>>(
        u3, u3, 16, pwga, b_ga, ga, N);
    gather_mean<<<dim3(512, N), 256, 0, stream>>>(ga, idx, agg);
    // gnn conv (MFMA, 32ch from u3|agg) then light head
    conv_mfma<32, 40, 288><<<dim3(256, N), 256, 0, stream>>>(
        u3, agg, 16, pwgn, b_gu, gnn, N);
    head_tiled<<<dim3(256, N), 256, 0, stream>>>(
        cts, gnn, w_d1, b_d1, w_de, b_de, (float*)d_out, N);
}